// Round 10
// baseline (270.331 us; speedup 1.0000x reference)
//
#include <hip/hip_runtime.h>
#include <math.h>

#define N_NODES 10000
#define B_BATCH 4
#define F_IN_C 128
#define HID_C 64
#define HEADS_C 4
#define E_EDGES 160000
#define E_TOT (E_EDGES + N_NODES)
#define E_PAD 200000   // E_TOT + 3*N_NODES upper bound, static stride for alpha
#define NEG_SLOPE 0.2f

// ---------------- CSR construction (padded to quad granularity) ----------------

__global__ void k_deg_init(int* __restrict__ deg) {
    int i = blockIdx.x * 256 + threadIdx.x;
    if (i < N_NODES) deg[i] = 1;  // self loop
}

__global__ void k_deg_count(const int* __restrict__ ei, int* __restrict__ deg) {
    int e = blockIdx.x * 256 + threadIdx.x;
    if (e < E_EDGES) atomicAdd(&deg[ei[E_EDGES + e]], 1);
}

// 1024 threads, 10 serial elems/thread, single LDS scan. Offsets use PADDED degrees
// ((deg+3)&~3) so every dst segment is 16B-aligned with quad-multiple length.
__global__ void k_scan(const int* __restrict__ deg, int* __restrict__ offs, int* __restrict__ cursor) {
    __shared__ int lds[1024];
    int t = threadIdx.x;
    int local[10];
    int tot = 0;
#pragma unroll
    for (int j = 0; j < 10; j++) {
        int i = t * 10 + j;
        int v = (i < N_NODES) ? ((deg[i] + 3) & ~3) : 0;
        tot += v;
        local[j] = tot;  // inclusive within chunk
    }
    lds[t] = tot;
    __syncthreads();
    for (int ofs = 1; ofs < 1024; ofs <<= 1) {
        int v = (t >= ofs) ? lds[t - ofs] : 0;
        __syncthreads();
        lds[t] += v;
        __syncthreads();
    }
    int base = lds[t] - tot;  // exclusive prefix of this chunk
#pragma unroll
    for (int j = 0; j < 10; j++) {
        int i = t * 10 + j;
        if (i < N_NODES) {
            offs[i + 1] = base + local[j];
            cursor[i] = (j == 0) ? base : base + local[j - 1];
        }
    }
    if (t == 0) offs[0] = 0;
}

// csr_b holds BYTE offsets (src*256) for the h-row gather; csr_dst the destination.
__global__ void k_scatter(const int* __restrict__ ei, int* __restrict__ cursor,
                          int* __restrict__ csr_b, int* __restrict__ csr_dst) {
    int e = blockIdx.x * 256 + threadIdx.x;
    if (e < E_TOT) {
        int s, d;
        if (e < E_EDGES) { s = ei[e]; d = ei[E_EDGES + e]; }
        else { s = d = e - E_EDGES; }
        int pos = atomicAdd(&cursor[d], 1);
        csr_b[pos] = s << 8;     // src * 256 bytes (64 floats)
        csr_dst[pos] = d;
    }
}

// Fill pad slots (cursor[d] is the real end after scatter): csr_b=0, csr_dst=-1.
__global__ void k_pad(const int* __restrict__ cursor, const int* __restrict__ offs,
                      int* __restrict__ csr_b, int* __restrict__ csr_dst) {
    int tid = blockIdx.x * 256 + threadIdx.x;
    if (tid >= N_NODES * 4) return;
    int d = tid >> 2, ps = tid & 3;
    int pos = cursor[d] + ps;
    if (pos < offs[d + 1]) { csr_b[pos] = 0; csr_dst[pos] = -1; }
}

// ---------------- Fused GEMM: h = x@W (head-major store), al_src/al_dst via group reduce --------
// SINGLE-WAVE 64-thread blocks, 16 nodes/wave -> 2500 waves total: W re-read traffic
// halves vs r9 (each wave reads W once: 2500 x 128KB = 320 MB for K=128), zero barriers.
// Lane owns cols 4l..4l+3; manual 1-ahead W prefetch; unroll 1 guards VGPR (round-6 lesson).

template <int K>
__launch_bounds__(64)
__global__ void k_gemm(const float* __restrict__ x, const float* __restrict__ W,
                       const float* __restrict__ a_src, const float* __restrict__ a_dst,
                       float* __restrict__ h2, float* __restrict__ alsrc, float* __restrict__ aldst) {
    __shared__ float xs[16][K];
    int lane = threadIdx.x;
    int b = blockIdx.y;
    int node0 = blockIdx.x * 16;   // 625*16 == 10000 exactly, no masking needed
    const float* xb = x + (size_t)b * N_NODES * K;

    for (int idx = lane; idx < 16 * (K / 4); idx += 64) {
        int r = idx / (K / 4), c4 = idx % (K / 4);
        *(float4*)&xs[r][c4 * 4] = *(const float4*)(xb + (size_t)(node0 + r) * K + c4 * 4);
    }
    __syncthreads();

    float4 acc[16];
#pragma unroll
    for (int i = 0; i < 16; i++) acc[i] = make_float4(0.f, 0.f, 0.f, 0.f);

    const float* Wl = W + lane * 4;
    float4 w0 = *(const float4*)(Wl + 0 * 256);
    float4 w1 = *(const float4*)(Wl + 1 * 256);
    float4 w2 = *(const float4*)(Wl + 2 * 256);
    float4 w3 = *(const float4*)(Wl + 3 * 256);

#pragma unroll 1
    for (int k0 = 0; k0 < K; k0 += 4) {
        float4 n0, n1, n2, n3;
        if (k0 + 4 < K) {
            n0 = *(const float4*)(Wl + (size_t)(k0 + 4) * 256);
            n1 = *(const float4*)(Wl + (size_t)(k0 + 5) * 256);
            n2 = *(const float4*)(Wl + (size_t)(k0 + 6) * 256);
            n3 = *(const float4*)(Wl + (size_t)(k0 + 7) * 256);
        }
#pragma unroll
        for (int i = 0; i < 16; i++) {
            float4 xv = *(float4*)&xs[i][k0];
            acc[i].x += xv.x * w0.x + xv.y * w1.x + xv.z * w2.x + xv.w * w3.x;
            acc[i].y += xv.x * w0.y + xv.y * w1.y + xv.z * w2.y + xv.w * w3.y;
            acc[i].z += xv.x * w0.z + xv.y * w1.z + xv.z * w2.z + xv.w * w3.z;
            acc[i].w += xv.x * w0.w + xv.y * w1.w + xv.z * w2.w + xv.w * w3.w;
        }
        w0 = n0; w1 = n1; w2 = n2; w3 = n3;
    }

    float4 as4 = *(const float4*)(a_src + lane * 4);
    float4 ad4 = *(const float4*)(a_dst + lane * 4);
    int hd = lane >> 4, cl = lane & 15;
    size_t nb = (size_t)b * N_NODES;
#pragma unroll
    for (int i = 0; i < 16; i++) {
        int n = node0 + i;
        // head-major store: h2[((b*4+hd)*N + n)*64 + cl*4]
        *(float4*)(h2 + ((size_t)(b * 4 + hd) * N_NODES + n) * 64 + cl * 4) = acc[i];
        float vs = acc[i].x * as4.x + acc[i].y * as4.y + acc[i].z * as4.z + acc[i].w * as4.w;
        float vd = acc[i].x * ad4.x + acc[i].y * ad4.y + acc[i].z * ad4.z + acc[i].w * ad4.w;
#pragma unroll
        for (int o = 1; o < 16; o <<= 1) {
            vs += __shfl_xor(vs, o);
            vd += __shfl_xor(vd, o);
        }
        if (cl == 0) {
            alsrc[(nb + n) * 4 + hd] = vs;
            aldst[(nb + n) * 4 + hd] = vd;
        }
    }
}

// ---------------- Edge-parallel unnormalized attention: e = exp(leaky(al_src+al_dst)) ----------
// Softmax shift-invariance: logits O(1), no max-subtraction (validated absmax 2.4e-4).
// Pad slots (csr_dst<0) write 0 -> contribute nothing downstream. [b][hd][E_PAD] layout.

__launch_bounds__(256)
__global__ void k_alpha(const float* __restrict__ alsrc, const float* __restrict__ aldst,
                        const int* __restrict__ csr_b, const int* __restrict__ csr_dst,
                        const int* __restrict__ offs, float* __restrict__ alpha) {
    int j = blockIdx.x * 256 + threadIdx.x;
    int e_act = offs[N_NODES];
    if (j >= e_act) return;
    int b = blockIdx.y;
    size_t base = (size_t)b * 4 * E_PAD + j;
    int dst = csr_dst[j];
    if (dst < 0) {
        alpha[base] = 0.f;
        alpha[base + E_PAD] = 0.f;
        alpha[base + (size_t)2 * E_PAD] = 0.f;
        alpha[base + (size_t)3 * E_PAD] = 0.f;
        return;
    }
    int src4 = csr_b[j] >> 6;  // src*4
    const float* als = alsrc + (size_t)b * N_NODES * 4;
    float4 s4 = *(const float4*)(als + src4);
    float4 d4 = *(const float4*)(aldst + ((size_t)b * N_NODES + dst) * 4);
    float a;
    a = s4.x + d4.x; a = a > 0.f ? a : NEG_SLOPE * a; float e0 = __expf(a);
    a = s4.y + d4.y; a = a > 0.f ? a : NEG_SLOPE * a; float e1 = __expf(a);
    a = s4.z + d4.z; a = a > 0.f ? a : NEG_SLOPE * a; float e2 = __expf(a);
    a = s4.w + d4.w; a = a > 0.f ? a : NEG_SLOPE * a; float e3 = __expf(a);
    alpha[base] = e0;
    alpha[base + E_PAD] = e1;
    alpha[base + (size_t)2 * E_PAD] = e2;
    alpha[base + (size_t)3 * E_PAD] = e3;
}

// ---------------- Gather-aggregate: 16-lane group owns one dst, 2-quad unrolled ----------------
// 16 combos (batch, head) x 625 blocks (16 dsts each), XCD-swizzled -> per-XCD set 2.56 MB.
// Per iteration: 2 quads = 2x(int4+float4) + 8 independent 256 B gathers in flight
// (r9 post-mortem: VALUBusy 18%, chain-latency-bound -> double the outstanding loads).
// Every lane holds the full channel sum -> no cross-lane fold.

__launch_bounds__(256)
__global__ void k_agg(const float* __restrict__ h2, const float* __restrict__ alpha,
                      const int* __restrict__ offs, const int* __restrict__ csr_b,
                      float* __restrict__ oh) {
    int t = threadIdx.x;
    int bid = blockIdx.x;
    int combo = (bid & 7) + 8 * (bid / 5000);
    int local = (bid >> 3) % 625;
    int b = combo & 3, hd = combo >> 2;
    int wv = t >> 6, lane = t & 63;
    int grp = lane >> 4, cl = lane & 15;
    int dst = local * 16 + wv * 4 + grp;

    const char* hcb = (const char*)(h2 + (size_t)(b * 4 + hd) * N_NODES * 64);
    const float* ec = alpha + (size_t)(b * 4 + hd) * E_PAD;
    int s0 = offs[dst], s1 = offs[dst + 1];
    int cl16 = cl * 16;

    float4 acc = make_float4(0.f, 0.f, 0.f, 0.f);
    float sacc = 0.f;
    int j = s0;
    for (; j + 4 < s1; j += 8) {
        int4 ca = *(const int4*)(csr_b + j);
        int4 cb = *(const int4*)(csr_b + j + 4);
        float4 pa = *(const float4*)(ec + j);
        float4 pb = *(const float4*)(ec + j + 4);
        float4 a0 = *(const float4*)(hcb + (unsigned)(ca.x + cl16));
        float4 a1 = *(const float4*)(hcb + (unsigned)(ca.y + cl16));
        float4 a2 = *(const float4*)(hcb + (unsigned)(ca.z + cl16));
        float4 a3 = *(const float4*)(hcb + (unsigned)(ca.w + cl16));
        float4 b0 = *(const float4*)(hcb + (unsigned)(cb.x + cl16));
        float4 b1 = *(const float4*)(hcb + (unsigned)(cb.y + cl16));
        float4 b2 = *(const float4*)(hcb + (unsigned)(cb.z + cl16));
        float4 b3 = *(const float4*)(hcb + (unsigned)(cb.w + cl16));
        acc.x += pa.x * a0.x; acc.y += pa.x * a0.y; acc.z += pa.x * a0.z; acc.w += pa.x * a0.w;
        acc.x += pa.y * a1.x; acc.y += pa.y * a1.y; acc.z += pa.y * a1.z; acc.w += pa.y * a1.w;
        acc.x += pa.z * a2.x; acc.y += pa.z * a2.y; acc.z += pa.z * a2.z; acc.w += pa.z * a2.w;
        acc.x += pa.w * a3.x; acc.y += pa.w * a3.y; acc.z += pa.w * a3.z; acc.w += pa.w * a3.w;
        acc.x += pb.x * b0.x; acc.y += pb.x * b0.y; acc.z += pb.x * b0.z; acc.w += pb.x * b0.w;
        acc.x += pb.y * b1.x; acc.y += pb.y * b1.y; acc.z += pb.y * b1.z; acc.w += pb.y * b1.w;
        acc.x += pb.z * b2.x; acc.y += pb.z * b2.y; acc.z += pb.z * b2.z; acc.w += pb.z * b2.w;
        acc.x += pb.w * b3.x; acc.y += pb.w * b3.y; acc.z += pb.w * b3.z; acc.w += pb.w * b3.w;
        sacc += pa.x + pa.y + pa.z + pa.w + pb.x + pb.y + pb.z + pb.w;
    }
    if (j < s1) {  // one remaining quad
        int4 ca = *(const int4*)(csr_b + j);
        float4 pa = *(const float4*)(ec + j);
        float4 a0 = *(const float4*)(hcb + (unsigned)(ca.x + cl16));
        float4 a1 = *(const float4*)(hcb + (unsigned)(ca.y + cl16));
        float4 a2 = *(const float4*)(hcb + (unsigned)(ca.z + cl16));
        float4 a3 = *(const float4*)(hcb + (unsigned)(ca.w + cl16));
        acc.x += pa.x * a0.x; acc.y += pa.x * a0.y; acc.z += pa.x * a0.z; acc.w += pa.x * a0.w;
        acc.x += pa.y * a1.x; acc.y += pa.y * a1.y; acc.z += pa.y * a1.z; acc.w += pa.y * a1.w;
        acc.x += pa.z * a2.x; acc.y += pa.z * a2.y; acc.z += pa.z * a2.z; acc.w += pa.z * a2.w;
        acc.x += pa.w * a3.x; acc.y += pa.w * a3.y; acc.z += pa.w * a3.z; acc.w += pa.w * a3.w;
        sacc += pa.x + pa.y + pa.z + pa.w;
    }
    float inv = 1.f / (sacc + 1e-16f);
    float4 r = make_float4(acc.x * inv, acc.y * inv, acc.z * inv, acc.w * inv);
    *(float4*)(oh + ((size_t)(b * 4 + hd) * N_NODES + dst) * 64 + cl * 4) = r;
}

// ---------------- Head mean + bias (+ELU for layer 1): pure streaming ----------------

template <bool LAYER1>
__launch_bounds__(256)
__global__ void k_reduce(const float* __restrict__ oh, const float* __restrict__ bias,
                         float* __restrict__ out) {
    int tid = blockIdx.x * 256 + threadIdx.x;  // B*N*16 threads, one float4 each
    int c4 = (tid & 15) * 4;
    int n = (tid >> 4) % N_NODES;
    int b = tid / (N_NODES * 16);
    size_t base = ((size_t)(b * 4) * N_NODES + n) * 64 + c4;
    float4 s = make_float4(0.f, 0.f, 0.f, 0.f);
#pragma unroll
    for (int hd = 0; hd < 4; hd++) {
        float4 v = *(const float4*)(oh + base + (size_t)hd * N_NODES * 64);
        s.x += v.x; s.y += v.y; s.z += v.z; s.w += v.w;
    }
    float4 b4 = *(const float4*)(bias + c4);
    float ox = s.x * 0.25f + b4.x;
    float oy = s.y * 0.25f + b4.y;
    float oz = s.z * 0.25f + b4.z;
    float ow = s.w * 0.25f + b4.w;
    if (LAYER1) {
        ox = ox > 0.f ? ox : expm1f(ox);
        oy = oy > 0.f ? oy : expm1f(oy);
        oz = oz > 0.f ? oz : expm1f(oz);
        ow = ow > 0.f ? ow : expm1f(ow);
    }
    *(float4*)(out + ((size_t)b * N_NODES + n) * 64 + c4) = make_float4(ox, oy, oz, ow);
}

// ---------------- Launch ----------------

extern "C" void kernel_launch(void* const* d_in, const int* in_sizes, int n_in,
                              void* d_out, int out_size, void* d_ws, size_t ws_size,
                              hipStream_t stream) {
    const float* x = (const float*)d_in[0];
    const int* ei = (const int*)d_in[1];
    const float* W1 = (const float*)d_in[2];
    const float* as1 = (const float*)d_in[3];
    const float* ad1 = (const float*)d_in[4];
    const float* b1 = (const float*)d_in[5];
    const float* W2 = (const float*)d_in[6];
    const float* as2 = (const float*)d_in[7];
    const float* ad2 = (const float*)d_in[8];
    const float* b2 = (const float*)d_in[9];
    float* out = (float*)d_out;

    // workspace layout
    char* p = (char*)d_ws;
    int* deg = (int*)p;            p += sizeof(int) * N_NODES;
    int* offs = (int*)p;           p += sizeof(int) * (N_NODES + 4);
    int* cursor = (int*)p;         p += sizeof(int) * N_NODES;
    int* csr_b = (int*)p;          p += sizeof(int) * E_PAD;
    int* csr_dst = (int*)p;        p += sizeof(int) * E_PAD;
    float* alsrc = (float*)p;      p += sizeof(float) * B_BATCH * N_NODES * 4;
    float* aldst = (float*)p;      p += sizeof(float) * B_BATCH * N_NODES * 4;
    float* h2 = (float*)p;         p += sizeof(float) * (size_t)B_BATCH * N_NODES * 256;
    float* oh = (float*)p;         p += sizeof(float) * (size_t)B_BATCH * N_NODES * 256;
    // alpha and x2 share one region (disjoint liveness), sized max(alpha, x2) = alpha.
    float* alpha = (float*)p;
    float* x2 = (float*)p;         p += sizeof(float) * (size_t)B_BATCH * 4 * E_PAD;

    // CSR build (padded)
    k_deg_init<<<(N_NODES + 255) / 256, 256, 0, stream>>>(deg);
    k_deg_count<<<(E_EDGES + 255) / 256, 256, 0, stream>>>(ei, deg);
    k_scan<<<1, 1024, 0, stream>>>(deg, offs, cursor);
    k_scatter<<<(E_TOT + 255) / 256, 256, 0, stream>>>(ei, cursor, csr_b, csr_dst);
    k_pad<<<(N_NODES * 4 + 255) / 256, 256, 0, stream>>>(cursor, offs, csr_b, csr_dst);

    dim3 gGemm(N_NODES / 16, B_BATCH);
    dim3 gAlpha((E_PAD + 255) / 256, B_BATCH);
    int gAgg = 16 * 625;   // (batch, head) combos x 625 blocks (16 dsts each), XCD-swizzled
    int gRed = B_BATCH * N_NODES * 16 / 256;

    // Layer 1
    k_gemm<F_IN_C><<<gGemm, 64, 0, stream>>>(x, W1, as1, ad1, h2, alsrc, aldst);
    k_alpha<<<gAlpha, 256, 0, stream>>>(alsrc, aldst, csr_b, csr_dst, offs, alpha);
    k_agg<<<gAgg, 256, 0, stream>>>(h2, alpha, offs, csr_b, oh);
    k_reduce<true><<<gRed, 256, 0, stream>>>(oh, b1, x2);

    // Layer 2
    k_gemm<HID_C><<<gGemm, 64, 0, stream>>>(x2, W2, as2, ad2, h2, alsrc, aldst);
    k_alpha<<<gAlpha, 256, 0, stream>>>(alsrc, aldst, csr_b, csr_dst, offs, alpha);
    k_agg<<<gAgg, 256, 0, stream>>>(h2, alpha, offs, csr_b, oh);
    k_reduce<false><<<gRed, 256, 0, stream>>>(oh, b2, out);
}

// Round 11
// 263.296 us; speedup vs baseline: 1.0267x; 1.0267x over previous
//
#include <hip/hip_runtime.h>
#include <math.h>

#define N_NODES 10000
#define B_BATCH 4
#define F_IN_C 128
#define HID_C 64
#define HEADS_C 4
#define E_EDGES 160000
#define E_TOT (E_EDGES + N_NODES)
#define E_PAD 200000   // E_TOT + 3*N_NODES upper bound, static stride for alpha
#define NEG_SLOPE 0.2f

// ---------------- CSR construction (padded to quad granularity) ----------------

__global__ void k_deg_init(int* __restrict__ deg) {
    int i = blockIdx.x * 256 + threadIdx.x;
    if (i < N_NODES) deg[i] = 1;  // self loop
}

__global__ void k_deg_count(const int* __restrict__ ei, int* __restrict__ deg) {
    int e = blockIdx.x * 256 + threadIdx.x;
    if (e < E_EDGES) atomicAdd(&deg[ei[E_EDGES + e]], 1);
}

// 1024 threads, 10 serial elems/thread, single LDS scan. Offsets use PADDED degrees
// ((deg+3)&~3) so every dst segment is 16B-aligned with quad-multiple length.
__global__ void k_scan(const int* __restrict__ deg, int* __restrict__ offs, int* __restrict__ cursor) {
    __shared__ int lds[1024];
    int t = threadIdx.x;
    int local[10];
    int tot = 0;
#pragma unroll
    for (int j = 0; j < 10; j++) {
        int i = t * 10 + j;
        int v = (i < N_NODES) ? ((deg[i] + 3) & ~3) : 0;
        tot += v;
        local[j] = tot;  // inclusive within chunk
    }
    lds[t] = tot;
    __syncthreads();
    for (int ofs = 1; ofs < 1024; ofs <<= 1) {
        int v = (t >= ofs) ? lds[t - ofs] : 0;
        __syncthreads();
        lds[t] += v;
        __syncthreads();
    }
    int base = lds[t] - tot;  // exclusive prefix of this chunk
#pragma unroll
    for (int j = 0; j < 10; j++) {
        int i = t * 10 + j;
        if (i < N_NODES) {
            offs[i + 1] = base + local[j];
            cursor[i] = (j == 0) ? base : base + local[j - 1];
        }
    }
    if (t == 0) offs[0] = 0;
}

// csr_b holds BYTE offsets (src*256) for the h-row gather; csr_dst the destination.
__global__ void k_scatter(const int* __restrict__ ei, int* __restrict__ cursor,
                          int* __restrict__ csr_b, int* __restrict__ csr_dst) {
    int e = blockIdx.x * 256 + threadIdx.x;
    if (e < E_TOT) {
        int s, d;
        if (e < E_EDGES) { s = ei[e]; d = ei[E_EDGES + e]; }
        else { s = d = e - E_EDGES; }
        int pos = atomicAdd(&cursor[d], 1);
        csr_b[pos] = s << 8;     // src * 256 bytes (64 floats)
        csr_dst[pos] = d;
    }
}

// Fill pad slots (cursor[d] is the real end after scatter): csr_b=0, csr_dst=-1.
__global__ void k_pad(const int* __restrict__ cursor, const int* __restrict__ offs,
                      int* __restrict__ csr_b, int* __restrict__ csr_dst) {
    int tid = blockIdx.x * 256 + threadIdx.x;
    if (tid >= N_NODES * 4) return;
    int d = tid >> 2, ps = tid & 3;
    int pos = cursor[d] + ps;
    if (pos < offs[d + 1]) { csr_b[pos] = 0; csr_dst[pos] = -1; }
}

// ---------------- Fused GEMM (round-5 structure, empirical best of 6 variants) ----------------
// 256 threads = 4 waves; wave owns 8 nodes (32 nodes/block); lane owns cols 4l..4l+3.
// W rows straight from L1/L2 (block-wide lockstep k); register-pipelined 1-ahead W quad.
// r5 measured: 55 us @ K=128, VGPR 44, occupancy ~38%, VALUBusy 52%.

template <int K>
__launch_bounds__(256)
__global__ void k_gemm(const float* __restrict__ x, const float* __restrict__ W,
                       const float* __restrict__ a_src, const float* __restrict__ a_dst,
                       float* __restrict__ h2, float* __restrict__ alsrc, float* __restrict__ aldst) {
    __shared__ float xs[32][K];
    int t = threadIdx.x;
    int wv = t >> 6, lane = t & 63;
    int b = blockIdx.y;
    int node0 = blockIdx.x * 32;
    const float* xb = x + (size_t)b * N_NODES * K;

    // stage 32 node rows (clamp OOB; stores masked in epilogue)
    for (int idx = t; idx < 32 * (K / 4); idx += 256) {
        int r = idx / (K / 4), c4 = idx % (K / 4);
        int n = node0 + r;
        if (n > N_NODES - 1) n = N_NODES - 1;
        *(float4*)&xs[r][c4 * 4] = *(const float4*)(xb + (size_t)n * K + c4 * 4);
    }
    __syncthreads();

    float4 acc[8];
#pragma unroll
    for (int i = 0; i < 8; i++) acc[i] = make_float4(0.f, 0.f, 0.f, 0.f);

    const float* Wl = W + lane * 4;
    float4 w0 = *(const float4*)(Wl + 0 * 256);
    float4 w1 = *(const float4*)(Wl + 1 * 256);
    float4 w2 = *(const float4*)(Wl + 2 * 256);
    float4 w3 = *(const float4*)(Wl + 3 * 256);

    for (int k0 = 0; k0 < K; k0 += 4) {
        float4 n0, n1, n2, n3;
        if (k0 + 4 < K) {
            n0 = *(const float4*)(Wl + (size_t)(k0 + 4) * 256);
            n1 = *(const float4*)(Wl + (size_t)(k0 + 5) * 256);
            n2 = *(const float4*)(Wl + (size_t)(k0 + 6) * 256);
            n3 = *(const float4*)(Wl + (size_t)(k0 + 7) * 256);
        }
#pragma unroll
        for (int i = 0; i < 8; i++) {
            float4 xv = *(float4*)&xs[wv * 8 + i][k0];
            acc[i].x += xv.x * w0.x + xv.y * w1.x + xv.z * w2.x + xv.w * w3.x;
            acc[i].y += xv.x * w0.y + xv.y * w1.y + xv.z * w2.y + xv.w * w3.y;
            acc[i].z += xv.x * w0.z + xv.y * w1.z + xv.z * w2.z + xv.w * w3.z;
            acc[i].w += xv.x * w0.w + xv.y * w1.w + xv.z * w2.w + xv.w * w3.w;
        }
        w0 = n0; w1 = n1; w2 = n2; w3 = n3;
    }

    float4 as4 = *(const float4*)(a_src + lane * 4);
    float4 ad4 = *(const float4*)(a_dst + lane * 4);
    int hd = lane >> 4, cl = lane & 15;
    size_t nb = (size_t)b * N_NODES;
#pragma unroll
    for (int i = 0; i < 8; i++) {
        int n = node0 + wv * 8 + i;
        if (n >= N_NODES) break;
        // head-major store: h2[((b*4+hd)*N + n)*64 + cl*4]
        *(float4*)(h2 + ((size_t)(b * 4 + hd) * N_NODES + n) * 64 + cl * 4) = acc[i];
        float vs = acc[i].x * as4.x + acc[i].y * as4.y + acc[i].z * as4.z + acc[i].w * as4.w;
        float vd = acc[i].x * ad4.x + acc[i].y * ad4.y + acc[i].z * ad4.z + acc[i].w * ad4.w;
#pragma unroll
        for (int o = 1; o < 16; o <<= 1) {
            vs += __shfl_xor(vs, o);
            vd += __shfl_xor(vd, o);
        }
        if (cl == 0) {
            alsrc[(nb + n) * 4 + hd] = vs;
            aldst[(nb + n) * 4 + hd] = vd;
        }
    }
}

// ---------------- Edge-parallel unnormalized attention: e = exp(leaky(al_src+al_dst)) ----------
// Softmax shift-invariance: logits O(1), no max-subtraction (validated absmax 2.4e-4).
// Pad slots (csr_dst<0) write 0 -> contribute nothing downstream. [b][hd][E_PAD] layout.

__launch_bounds__(256)
__global__ void k_alpha(const float* __restrict__ alsrc, const float* __restrict__ aldst,
                        const int* __restrict__ csr_b, const int* __restrict__ csr_dst,
                        const int* __restrict__ offs, float* __restrict__ alpha) {
    int j = blockIdx.x * 256 + threadIdx.x;
    int e_act = offs[N_NODES];
    if (j >= e_act) return;
    int b = blockIdx.y;
    size_t base = (size_t)b * 4 * E_PAD + j;
    int dst = csr_dst[j];
    if (dst < 0) {
        alpha[base] = 0.f;
        alpha[base + E_PAD] = 0.f;
        alpha[base + (size_t)2 * E_PAD] = 0.f;
        alpha[base + (size_t)3 * E_PAD] = 0.f;
        return;
    }
    int src4 = csr_b[j] >> 6;  // src*4
    const float* als = alsrc + (size_t)b * N_NODES * 4;
    float4 s4 = *(const float4*)(als + src4);
    float4 d4 = *(const float4*)(aldst + ((size_t)b * N_NODES + dst) * 4);
    float a;
    a = s4.x + d4.x; a = a > 0.f ? a : NEG_SLOPE * a; float e0 = __expf(a);
    a = s4.y + d4.y; a = a > 0.f ? a : NEG_SLOPE * a; float e1 = __expf(a);
    a = s4.z + d4.z; a = a > 0.f ? a : NEG_SLOPE * a; float e2 = __expf(a);
    a = s4.w + d4.w; a = a > 0.f ? a : NEG_SLOPE * a; float e3 = __expf(a);
    alpha[base] = e0;
    alpha[base + E_PAD] = e1;
    alpha[base + (size_t)2 * E_PAD] = e2;
    alpha[base + (size_t)3 * E_PAD] = e3;
}

// ---------------- Gather-aggregate: 16-lane group owns one dst, 4-quad deep MLP ----------------
// 16 combos (batch, head) x 625 blocks (16 dsts each), XCD-swizzled -> per-XCD set 2.56 MB.
// r10 post-mortem: latency/request-rate bound with VALU 18% idle -> widen to 16 independent
// 256 B gathers in flight (4 quads), with 2-quad and 1-quad tails (segments are quad-multiple).
// Every lane holds the full channel sum -> no cross-lane fold.

#define QUAD_FMA(p4, g0, g1, g2, g3)                                                   \
    acc.x += p4.x * g0.x; acc.y += p4.x * g0.y; acc.z += p4.x * g0.z; acc.w += p4.x * g0.w; \
    acc.x += p4.y * g1.x; acc.y += p4.y * g1.y; acc.z += p4.y * g1.z; acc.w += p4.y * g1.w; \
    acc.x += p4.z * g2.x; acc.y += p4.z * g2.y; acc.z += p4.z * g2.z; acc.w += p4.z * g2.w; \
    acc.x += p4.w * g3.x; acc.y += p4.w * g3.y; acc.z += p4.w * g3.z; acc.w += p4.w * g3.w; \
    sacc += p4.x + p4.y + p4.z + p4.w;

__launch_bounds__(256)
__global__ void k_agg(const float* __restrict__ h2, const float* __restrict__ alpha,
                      const int* __restrict__ offs, const int* __restrict__ csr_b,
                      float* __restrict__ oh) {
    int t = threadIdx.x;
    int bid = blockIdx.x;
    int combo = (bid & 7) + 8 * (bid / 5000);
    int local = (bid >> 3) % 625;
    int b = combo & 3, hd = combo >> 2;
    int wv = t >> 6, lane = t & 63;
    int grp = lane >> 4, cl = lane & 15;
    int dst = local * 16 + wv * 4 + grp;

    const char* hcb = (const char*)(h2 + (size_t)(b * 4 + hd) * N_NODES * 64);
    const float* ec = alpha + (size_t)(b * 4 + hd) * E_PAD;
    int s0 = offs[dst], s1 = offs[dst + 1];
    int cl16 = cl * 16;

    float4 acc = make_float4(0.f, 0.f, 0.f, 0.f);
    float sacc = 0.f;
    int j = s0;
    // 4-quad main loop: 16 independent gathers in flight
    for (; j + 12 < s1; j += 16) {
        int4 c0 = *(const int4*)(csr_b + j);
        int4 c1 = *(const int4*)(csr_b + j + 4);
        int4 c2 = *(const int4*)(csr_b + j + 8);
        int4 c3 = *(const int4*)(csr_b + j + 12);
        float4 p0 = *(const float4*)(ec + j);
        float4 p1 = *(const float4*)(ec + j + 4);
        float4 p2 = *(const float4*)(ec + j + 8);
        float4 p3 = *(const float4*)(ec + j + 12);
        float4 a0 = *(const float4*)(hcb + (unsigned)(c0.x + cl16));
        float4 a1 = *(const float4*)(hcb + (unsigned)(c0.y + cl16));
        float4 a2 = *(const float4*)(hcb + (unsigned)(c0.z + cl16));
        float4 a3 = *(const float4*)(hcb + (unsigned)(c0.w + cl16));
        float4 b0 = *(const float4*)(hcb + (unsigned)(c1.x + cl16));
        float4 b1 = *(const float4*)(hcb + (unsigned)(c1.y + cl16));
        float4 b2 = *(const float4*)(hcb + (unsigned)(c1.z + cl16));
        float4 b3 = *(const float4*)(hcb + (unsigned)(c1.w + cl16));
        float4 d0 = *(const float4*)(hcb + (unsigned)(c2.x + cl16));
        float4 d1 = *(const float4*)(hcb + (unsigned)(c2.y + cl16));
        float4 d2 = *(const float4*)(hcb + (unsigned)(c2.z + cl16));
        float4 d3 = *(const float4*)(hcb + (unsigned)(c2.w + cl16));
        float4 e0 = *(const float4*)(hcb + (unsigned)(c3.x + cl16));
        float4 e1 = *(const float4*)(hcb + (unsigned)(c3.y + cl16));
        float4 e2 = *(const float4*)(hcb + (unsigned)(c3.z + cl16));
        float4 e3 = *(const float4*)(hcb + (unsigned)(c3.w + cl16));
        QUAD_FMA(p0, a0, a1, a2, a3)
        QUAD_FMA(p1, b0, b1, b2, b3)
        QUAD_FMA(p2, d0, d1, d2, d3)
        QUAD_FMA(p3, e0, e1, e2, e3)
    }
    // 2-quad tail
    for (; j + 4 < s1; j += 8) {
        int4 c0 = *(const int4*)(csr_b + j);
        int4 c1 = *(const int4*)(csr_b + j + 4);
        float4 p0 = *(const float4*)(ec + j);
        float4 p1 = *(const float4*)(ec + j + 4);
        float4 a0 = *(const float4*)(hcb + (unsigned)(c0.x + cl16));
        float4 a1 = *(const float4*)(hcb + (unsigned)(c0.y + cl16));
        float4 a2 = *(const float4*)(hcb + (unsigned)(c0.z + cl16));
        float4 a3 = *(const float4*)(hcb + (unsigned)(c0.w + cl16));
        float4 b0 = *(const float4*)(hcb + (unsigned)(c1.x + cl16));
        float4 b1 = *(const float4*)(hcb + (unsigned)(c1.y + cl16));
        float4 b2 = *(const float4*)(hcb + (unsigned)(c1.z + cl16));
        float4 b3 = *(const float4*)(hcb + (unsigned)(c1.w + cl16));
        QUAD_FMA(p0, a0, a1, a2, a3)
        QUAD_FMA(p1, b0, b1, b2, b3)
    }
    // 1-quad tail
    if (j < s1) {
        int4 c0 = *(const int4*)(csr_b + j);
        float4 p0 = *(const float4*)(ec + j);
        float4 a0 = *(const float4*)(hcb + (unsigned)(c0.x + cl16));
        float4 a1 = *(const float4*)(hcb + (unsigned)(c0.y + cl16));
        float4 a2 = *(const float4*)(hcb + (unsigned)(c0.z + cl16));
        float4 a3 = *(const float4*)(hcb + (unsigned)(c0.w + cl16));
        QUAD_FMA(p0, a0, a1, a2, a3)
    }
    float inv = 1.f / (sacc + 1e-16f);
    float4 r = make_float4(acc.x * inv, acc.y * inv, acc.z * inv, acc.w * inv);
    *(float4*)(oh + ((size_t)(b * 4 + hd) * N_NODES + dst) * 64 + cl * 4) = r;
}

// ---------------- Head mean + bias (+ELU for layer 1): pure streaming ----------------

template <bool LAYER1>
__launch_bounds__(256)
__global__ void k_reduce(const float* __restrict__ oh, const float* __restrict__ bias,
                         float* __restrict__ out) {
    int tid = blockIdx.x * 256 + threadIdx.x;  // B*N*16 threads, one float4 each
    int c4 = (tid & 15) * 4;
    int n = (tid >> 4) % N_NODES;
    int b = tid / (N_NODES * 16);
    size_t base = ((size_t)(b * 4) * N_NODES + n) * 64 + c4;
    float4 s = make_float4(0.f, 0.f, 0.f, 0.f);
#pragma unroll
    for (int hd = 0; hd < 4; hd++) {
        float4 v = *(const float4*)(oh + base + (size_t)hd * N_NODES * 64);
        s.x += v.x; s.y += v.y; s.z += v.z; s.w += v.w;
    }
    float4 b4 = *(const float4*)(bias + c4);
    float ox = s.x * 0.25f + b4.x;
    float oy = s.y * 0.25f + b4.y;
    float oz = s.z * 0.25f + b4.z;
    float ow = s.w * 0.25f + b4.w;
    if (LAYER1) {
        ox = ox > 0.f ? ox : expm1f(ox);
        oy = oy > 0.f ? oy : expm1f(oy);
        oz = oz > 0.f ? oz : expm1f(oz);
        ow = ow > 0.f ? ow : expm1f(ow);
    }
    *(float4*)(out + ((size_t)b * N_NODES + n) * 64 + c4) = make_float4(ox, oy, oz, ow);
}

// ---------------- Launch ----------------

extern "C" void kernel_launch(void* const* d_in, const int* in_sizes, int n_in,
                              void* d_out, int out_size, void* d_ws, size_t ws_size,
                              hipStream_t stream) {
    const float* x = (const float*)d_in[0];
    const int* ei = (const int*)d_in[1];
    const float* W1 = (const float*)d_in[2];
    const float* as1 = (const float*)d_in[3];
    const float* ad1 = (const float*)d_in[4];
    const float* b1 = (const float*)d_in[5];
    const float* W2 = (const float*)d_in[6];
    const float* as2 = (const float*)d_in[7];
    const float* ad2 = (const float*)d_in[8];
    const float* b2 = (const float*)d_in[9];
    float* out = (float*)d_out;

    // workspace layout
    char* p = (char*)d_ws;
    int* deg = (int*)p;            p += sizeof(int) * N_NODES;
    int* offs = (int*)p;           p += sizeof(int) * (N_NODES + 4);
    int* cursor = (int*)p;         p += sizeof(int) * N_NODES;
    int* csr_b = (int*)p;          p += sizeof(int) * E_PAD;
    int* csr_dst = (int*)p;        p += sizeof(int) * E_PAD;
    float* alsrc = (float*)p;      p += sizeof(float) * B_BATCH * N_NODES * 4;
    float* aldst = (float*)p;      p += sizeof(float) * B_BATCH * N_NODES * 4;
    float* h2 = (float*)p;         p += sizeof(float) * (size_t)B_BATCH * N_NODES * 256;
    float* oh = (float*)p;         p += sizeof(float) * (size_t)B_BATCH * N_NODES * 256;
    // alpha and x2 share one region (disjoint liveness), sized max(alpha, x2) = alpha.
    float* alpha = (float*)p;
    float* x2 = (float*)p;         p += sizeof(float) * (size_t)B_BATCH * 4 * E_PAD;

    // CSR build (padded)
    k_deg_init<<<(N_NODES + 255) / 256, 256, 0, stream>>>(deg);
    k_deg_count<<<(E_EDGES + 255) / 256, 256, 0, stream>>>(ei, deg);
    k_scan<<<1, 1024, 0, stream>>>(deg, offs, cursor);
    k_scatter<<<(E_TOT + 255) / 256, 256, 0, stream>>>(ei, cursor, csr_b, csr_dst);
    k_pad<<<(N_NODES * 4 + 255) / 256, 256, 0, stream>>>(cursor, offs, csr_b, csr_dst);

    dim3 gGemm((N_NODES + 31) / 32, B_BATCH);
    dim3 gAlpha((E_PAD + 255) / 256, B_BATCH);
    int gAgg = 16 * 625;   // (batch, head) combos x 625 blocks (16 dsts each), XCD-swizzled
    int gRed = B_BATCH * N_NODES * 16 / 256;

    // Layer 1
    k_gemm<F_IN_C><<<gGemm, 256, 0, stream>>>(x, W1, as1, ad1, h2, alsrc, aldst);
    k_alpha<<<gAlpha, 256, 0, stream>>>(alsrc, aldst, csr_b, csr_dst, offs, alpha);
    k_agg<<<gAgg, 256, 0, stream>>>(h2, alpha, offs, csr_b, oh);
    k_reduce<true><<<gRed, 256, 0, stream>>>(oh, b1, x2);

    // Layer 2
    k_gemm<HID_C><<<gGemm, 256, 0, stream>>>(x2, W2, as2, ad2, h2, alsrc, aldst);
    k_alpha<<<gAlpha, 256, 0, stream>>>(alsrc, aldst, csr_b, csr_dst, offs, alpha);
    k_agg<<<gAgg, 256, 0, stream>>>(h2, alpha, offs, csr_b, oh);
    k_reduce<false><<<gRed, 256, 0, stream>>>(oh, b2, out);
}

// Round 12
// 248.752 us; speedup vs baseline: 1.0867x; 1.0585x over previous
//
#include <hip/hip_runtime.h>
#include <hip/hip_fp16.h>
#include <math.h>

#define N_NODES 10000
#define B_BATCH 4
#define F_IN_C 128
#define HID_C 64
#define HEADS_C 4
#define E_EDGES 160000
#define E_TOT (E_EDGES + N_NODES)
#define E_PAD 200000   // E_TOT + 3*N_NODES upper bound, static stride for alpha
#define NEG_SLOPE 0.2f

// ---------------- CSR construction (padded to quad granularity) ----------------

__global__ void k_deg_init(int* __restrict__ deg) {
    int i = blockIdx.x * 256 + threadIdx.x;
    if (i < N_NODES) deg[i] = 1;  // self loop
}

__global__ void k_deg_count(const int* __restrict__ ei, int* __restrict__ deg) {
    int e = blockIdx.x * 256 + threadIdx.x;
    if (e < E_EDGES) atomicAdd(&deg[ei[E_EDGES + e]], 1);
}

// 1024 threads, 10 serial elems/thread, single LDS scan. Offsets use PADDED degrees
// ((deg+3)&~3) so every dst segment is 16B-aligned with quad-multiple length.
__global__ void k_scan(const int* __restrict__ deg, int* __restrict__ offs, int* __restrict__ cursor) {
    __shared__ int lds[1024];
    int t = threadIdx.x;
    int local[10];
    int tot = 0;
#pragma unroll
    for (int j = 0; j < 10; j++) {
        int i = t * 10 + j;
        int v = (i < N_NODES) ? ((deg[i] + 3) & ~3) : 0;
        tot += v;
        local[j] = tot;  // inclusive within chunk
    }
    lds[t] = tot;
    __syncthreads();
    for (int ofs = 1; ofs < 1024; ofs <<= 1) {
        int v = (t >= ofs) ? lds[t - ofs] : 0;
        __syncthreads();
        lds[t] += v;
        __syncthreads();
    }
    int base = lds[t] - tot;  // exclusive prefix of this chunk
#pragma unroll
    for (int j = 0; j < 10; j++) {
        int i = t * 10 + j;
        if (i < N_NODES) {
            offs[i + 1] = base + local[j];
            cursor[i] = (j == 0) ? base : base + local[j - 1];
        }
    }
    if (t == 0) offs[0] = 0;
}

// csr_b holds BYTE offsets (src*128, fp16 rows) for the h-row gather; csr_dst the destination.
__global__ void k_scatter(const int* __restrict__ ei, int* __restrict__ cursor,
                          int* __restrict__ csr_b, int* __restrict__ csr_dst) {
    int e = blockIdx.x * 256 + threadIdx.x;
    if (e < E_TOT) {
        int s, d;
        if (e < E_EDGES) { s = ei[e]; d = ei[E_EDGES + e]; }
        else { s = d = e - E_EDGES; }
        int pos = atomicAdd(&cursor[d], 1);
        csr_b[pos] = s << 7;     // src * 128 bytes (64 halves)
        csr_dst[pos] = d;
    }
}

// Fill pad slots (cursor[d] is the real end after scatter): csr_b=0, csr_dst=-1.
__global__ void k_pad(const int* __restrict__ cursor, const int* __restrict__ offs,
                      int* __restrict__ csr_b, int* __restrict__ csr_dst) {
    int tid = blockIdx.x * 256 + threadIdx.x;
    if (tid >= N_NODES * 4) return;
    int d = tid >> 2, ps = tid & 3;
    int pos = cursor[d] + ps;
    if (pos < offs[d + 1]) { csr_b[pos] = 0; csr_dst[pos] = -1; }
}

// ---------------- Fused GEMM (round-5 structure, empirical best of 6 variants) ----------------
// 256 threads = 4 waves; wave owns 8 nodes (32 nodes/block); lane owns cols 4l..4l+3.
// W rows straight from L1/L2 (block-wide lockstep k); register-pipelined 1-ahead W quad.
// f32 accumulate; h2 stored head-major as FP16 (halves gather traffic in k_agg).

template <int K>
__launch_bounds__(256)
__global__ void k_gemm(const float* __restrict__ x, const float* __restrict__ W,
                       const float* __restrict__ a_src, const float* __restrict__ a_dst,
                       __half* __restrict__ h2, float* __restrict__ alsrc, float* __restrict__ aldst) {
    __shared__ float xs[32][K];
    int t = threadIdx.x;
    int wv = t >> 6, lane = t & 63;
    int b = blockIdx.y;
    int node0 = blockIdx.x * 32;
    const float* xb = x + (size_t)b * N_NODES * K;

    // stage 32 node rows (clamp OOB; stores masked in epilogue)
    for (int idx = t; idx < 32 * (K / 4); idx += 256) {
        int r = idx / (K / 4), c4 = idx % (K / 4);
        int n = node0 + r;
        if (n > N_NODES - 1) n = N_NODES - 1;
        *(float4*)&xs[r][c4 * 4] = *(const float4*)(xb + (size_t)n * K + c4 * 4);
    }
    __syncthreads();

    float4 acc[8];
#pragma unroll
    for (int i = 0; i < 8; i++) acc[i] = make_float4(0.f, 0.f, 0.f, 0.f);

    const float* Wl = W + lane * 4;
    float4 w0 = *(const float4*)(Wl + 0 * 256);
    float4 w1 = *(const float4*)(Wl + 1 * 256);
    float4 w2 = *(const float4*)(Wl + 2 * 256);
    float4 w3 = *(const float4*)(Wl + 3 * 256);

    for (int k0 = 0; k0 < K; k0 += 4) {
        float4 n0, n1, n2, n3;
        if (k0 + 4 < K) {
            n0 = *(const float4*)(Wl + (size_t)(k0 + 4) * 256);
            n1 = *(const float4*)(Wl + (size_t)(k0 + 5) * 256);
            n2 = *(const float4*)(Wl + (size_t)(k0 + 6) * 256);
            n3 = *(const float4*)(Wl + (size_t)(k0 + 7) * 256);
        }
#pragma unroll
        for (int i = 0; i < 8; i++) {
            float4 xv = *(float4*)&xs[wv * 8 + i][k0];
            acc[i].x += xv.x * w0.x + xv.y * w1.x + xv.z * w2.x + xv.w * w3.x;
            acc[i].y += xv.x * w0.y + xv.y * w1.y + xv.z * w2.y + xv.w * w3.y;
            acc[i].z += xv.x * w0.z + xv.y * w1.z + xv.z * w2.z + xv.w * w3.z;
            acc[i].w += xv.x * w0.w + xv.y * w1.w + xv.z * w2.w + xv.w * w3.w;
        }
        w0 = n0; w1 = n1; w2 = n2; w3 = n3;
    }

    float4 as4 = *(const float4*)(a_src + lane * 4);
    float4 ad4 = *(const float4*)(a_dst + lane * 4);
    int hd = lane >> 4, cl = lane & 15;
    size_t nb = (size_t)b * N_NODES;
#pragma unroll
    for (int i = 0; i < 8; i++) {
        int n = node0 + wv * 8 + i;
        if (n >= N_NODES) break;
        // head-major fp16 store: row ((b*4+hd)*N + n), 64 halves; lane stores 4 halves (8B)
        __half2 lo = __floats2half2_rn(acc[i].x, acc[i].y);
        __half2 hi = __floats2half2_rn(acc[i].z, acc[i].w);
        uint2 pk = make_uint2(*(unsigned*)&lo, *(unsigned*)&hi);
        *(uint2*)(h2 + (((size_t)(b * 4 + hd) * N_NODES + n) * 64 + cl * 4)) = pk;
        float vs = acc[i].x * as4.x + acc[i].y * as4.y + acc[i].z * as4.z + acc[i].w * as4.w;
        float vd = acc[i].x * ad4.x + acc[i].y * ad4.y + acc[i].z * ad4.z + acc[i].w * ad4.w;
#pragma unroll
        for (int o = 1; o < 16; o <<= 1) {
            vs += __shfl_xor(vs, o);
            vd += __shfl_xor(vd, o);
        }
        if (cl == 0) {
            alsrc[(nb + n) * 4 + hd] = vs;
            aldst[(nb + n) * 4 + hd] = vd;
        }
    }
}

// ---------------- Edge-parallel unnormalized attention: e = exp(leaky(al_src+al_dst)) ----------
// Softmax shift-invariance: logits O(1), no max-subtraction (validated absmax 2.4e-4).
// Pad slots (csr_dst<0) write 0 -> contribute nothing downstream. [b][hd][E_PAD] layout.

__launch_bounds__(256)
__global__ void k_alpha(const float* __restrict__ alsrc, const float* __restrict__ aldst,
                        const int* __restrict__ csr_b, const int* __restrict__ csr_dst,
                        const int* __restrict__ offs, float* __restrict__ alpha) {
    int j = blockIdx.x * 256 + threadIdx.x;
    int e_act = offs[N_NODES];
    if (j >= e_act) return;
    int b = blockIdx.y;
    size_t base = (size_t)b * 4 * E_PAD + j;
    int dst = csr_dst[j];
    if (dst < 0) {
        alpha[base] = 0.f;
        alpha[base + E_PAD] = 0.f;
        alpha[base + (size_t)2 * E_PAD] = 0.f;
        alpha[base + (size_t)3 * E_PAD] = 0.f;
        return;
    }
    int src4 = csr_b[j] >> 5;  // (src*128) -> src*4
    const float* als = alsrc + (size_t)b * N_NODES * 4;
    float4 s4 = *(const float4*)(als + src4);
    float4 d4 = *(const float4*)(aldst + ((size_t)b * N_NODES + dst) * 4);
    float a;
    a = s4.x + d4.x; a = a > 0.f ? a : NEG_SLOPE * a; float e0 = __expf(a);
    a = s4.y + d4.y; a = a > 0.f ? a : NEG_SLOPE * a; float e1 = __expf(a);
    a = s4.z + d4.z; a = a > 0.f ? a : NEG_SLOPE * a; float e2 = __expf(a);
    a = s4.w + d4.w; a = a > 0.f ? a : NEG_SLOPE * a; float e3 = __expf(a);
    alpha[base] = e0;
    alpha[base + E_PAD] = e1;
    alpha[base + (size_t)2 * E_PAD] = e2;
    alpha[base + (size_t)3 * E_PAD] = e3;
}

// ---------------- Gather-aggregate: 16-lane group owns one dst, fp16 rows ----------------
// 16 combos (batch, head) x 625 blocks (16 dsts each), XCD-swizzled -> per-XCD set 1.28 MB.
// r11 post-mortem: MSHR(line-miss)-capacity x latency bound -> halve LINES per row via fp16
// (128 B row = 2 lines; wave gather = 8 lines vs 16). 2-quad depth (r9's best). Lane reads
// 8 B (4 halves), cvt to f32, FMA in f32. No cross-lane fold.

#define QUAD_FMA16(p4, g0, g1, g2, g3)                                                    \
    {                                                                                     \
        float2 f01, f23;                                                                  \
        f01 = __half22float2(*(__half2*)&g0.x); f23 = __half22float2(*(__half2*)&g0.y);   \
        acc.x += p4.x * f01.x; acc.y += p4.x * f01.y; acc.z += p4.x * f23.x; acc.w += p4.x * f23.y; \
        f01 = __half22float2(*(__half2*)&g1.x); f23 = __half22float2(*(__half2*)&g1.y);   \
        acc.x += p4.y * f01.x; acc.y += p4.y * f01.y; acc.z += p4.y * f23.x; acc.w += p4.y * f23.y; \
        f01 = __half22float2(*(__half2*)&g2.x); f23 = __half22float2(*(__half2*)&g2.y);   \
        acc.x += p4.z * f01.x; acc.y += p4.z * f01.y; acc.z += p4.z * f23.x; acc.w += p4.z * f23.y; \
        f01 = __half22float2(*(__half2*)&g3.x); f23 = __half22float2(*(__half2*)&g3.y);   \
        acc.x += p4.w * f01.x; acc.y += p4.w * f01.y; acc.z += p4.w * f23.x; acc.w += p4.w * f23.y; \
        sacc += p4.x + p4.y + p4.z + p4.w;                                                \
    }

__launch_bounds__(256)
__global__ void k_agg(const __half* __restrict__ h2, const float* __restrict__ alpha,
                      const int* __restrict__ offs, const int* __restrict__ csr_b,
                      float* __restrict__ oh) {
    int t = threadIdx.x;
    int bid = blockIdx.x;
    int combo = (bid & 7) + 8 * (bid / 5000);
    int local = (bid >> 3) % 625;
    int b = combo & 3, hd = combo >> 2;
    int wv = t >> 6, lane = t & 63;
    int grp = lane >> 4, cl = lane & 15;
    int dst = local * 16 + wv * 4 + grp;

    const char* hcb = (const char*)(h2 + (size_t)(b * 4 + hd) * N_NODES * 64);
    const float* ec = alpha + (size_t)(b * 4 + hd) * E_PAD;
    int s0 = offs[dst], s1 = offs[dst + 1];
    int cl8 = cl * 8;

    float4 acc = make_float4(0.f, 0.f, 0.f, 0.f);
    float sacc = 0.f;
    int j = s0;
    for (; j + 4 < s1; j += 8) {
        int4 ca = *(const int4*)(csr_b + j);
        int4 cb = *(const int4*)(csr_b + j + 4);
        float4 pa = *(const float4*)(ec + j);
        float4 pb = *(const float4*)(ec + j + 4);
        uint2 a0 = *(const uint2*)(hcb + (unsigned)(ca.x + cl8));
        uint2 a1 = *(const uint2*)(hcb + (unsigned)(ca.y + cl8));
        uint2 a2 = *(const uint2*)(hcb + (unsigned)(ca.z + cl8));
        uint2 a3 = *(const uint2*)(hcb + (unsigned)(ca.w + cl8));
        uint2 b0 = *(const uint2*)(hcb + (unsigned)(cb.x + cl8));
        uint2 b1 = *(const uint2*)(hcb + (unsigned)(cb.y + cl8));
        uint2 b2 = *(const uint2*)(hcb + (unsigned)(cb.z + cl8));
        uint2 b3 = *(const uint2*)(hcb + (unsigned)(cb.w + cl8));
        QUAD_FMA16(pa, a0, a1, a2, a3)
        QUAD_FMA16(pb, b0, b1, b2, b3)
    }
    if (j < s1) {  // one remaining quad
        int4 ca = *(const int4*)(csr_b + j);
        float4 pa = *(const float4*)(ec + j);
        uint2 a0 = *(const uint2*)(hcb + (unsigned)(ca.x + cl8));
        uint2 a1 = *(const uint2*)(hcb + (unsigned)(ca.y + cl8));
        uint2 a2 = *(const uint2*)(hcb + (unsigned)(ca.z + cl8));
        uint2 a3 = *(const uint2*)(hcb + (unsigned)(ca.w + cl8));
        QUAD_FMA16(pa, a0, a1, a2, a3)
    }
    float inv = 1.f / (sacc + 1e-16f);
    float4 r = make_float4(acc.x * inv, acc.y * inv, acc.z * inv, acc.w * inv);
    *(float4*)(oh + ((size_t)(b * 4 + hd) * N_NODES + dst) * 64 + cl * 4) = r;
}

// ---------------- Head mean + bias (+ELU for layer 1): pure streaming ----------------

template <bool LAYER1>
__launch_bounds__(256)
__global__ void k_reduce(const float* __restrict__ oh, const float* __restrict__ bias,
                         float* __restrict__ out) {
    int tid = blockIdx.x * 256 + threadIdx.x;  // B*N*16 threads, one float4 each
    int c4 = (tid & 15) * 4;
    int n = (tid >> 4) % N_NODES;
    int b = tid / (N_NODES * 16);
    size_t base = ((size_t)(b * 4) * N_NODES + n) * 64 + c4;
    float4 s = make_float4(0.f, 0.f, 0.f, 0.f);
#pragma unroll
    for (int hd = 0; hd < 4; hd++) {
        float4 v = *(const float4*)(oh + base + (size_t)hd * N_NODES * 64);
        s.x += v.x; s.y += v.y; s.z += v.z; s.w += v.w;
    }
    float4 b4 = *(const float4*)(bias + c4);
    float ox = s.x * 0.25f + b4.x;
    float oy = s.y * 0.25f + b4.y;
    float oz = s.z * 0.25f + b4.z;
    float ow = s.w * 0.25f + b4.w;
    if (LAYER1) {
        ox = ox > 0.f ? ox : expm1f(ox);
        oy = oy > 0.f ? oy : expm1f(oy);
        oz = oz > 0.f ? oz : expm1f(oz);
        ow = ow > 0.f ? ow : expm1f(ow);
    }
    *(float4*)(out + ((size_t)b * N_NODES + n) * 64 + c4) = make_float4(ox, oy, oz, ow);
}

// ---------------- Launch ----------------

extern "C" void kernel_launch(void* const* d_in, const int* in_sizes, int n_in,
                              void* d_out, int out_size, void* d_ws, size_t ws_size,
                              hipStream_t stream) {
    const float* x = (const float*)d_in[0];
    const int* ei = (const int*)d_in[1];
    const float* W1 = (const float*)d_in[2];
    const float* as1 = (const float*)d_in[3];
    const float* ad1 = (const float*)d_in[4];
    const float* b1 = (const float*)d_in[5];
    const float* W2 = (const float*)d_in[6];
    const float* as2 = (const float*)d_in[7];
    const float* ad2 = (const float*)d_in[8];
    const float* b2 = (const float*)d_in[9];
    float* out = (float*)d_out;

    // workspace layout
    char* p = (char*)d_ws;
    int* deg = (int*)p;            p += sizeof(int) * N_NODES;
    int* offs = (int*)p;           p += sizeof(int) * (N_NODES + 4);
    int* cursor = (int*)p;         p += sizeof(int) * N_NODES;
    int* csr_b = (int*)p;          p += sizeof(int) * E_PAD;
    int* csr_dst = (int*)p;        p += sizeof(int) * E_PAD;
    float* alsrc = (float*)p;      p += sizeof(float) * B_BATCH * N_NODES * 4;
    float* aldst = (float*)p;      p += sizeof(float) * B_BATCH * N_NODES * 4;
    __half* h2 = (__half*)p;       p += sizeof(__half) * (size_t)B_BATCH * N_NODES * 256;
    float* oh = (float*)p;         p += sizeof(float) * (size_t)B_BATCH * N_NODES * 256;
    // alpha and x2 share one region (disjoint liveness), sized max(alpha, x2) = alpha.
    float* alpha = (float*)p;
    float* x2 = (float*)p;         p += sizeof(float) * (size_t)B_BATCH * 4 * E_PAD;

    // CSR build (padded)
    k_deg_init<<<(N_NODES + 255) / 256, 256, 0, stream>>>(deg);
    k_deg_count<<<(E_EDGES + 255) / 256, 256, 0, stream>>>(ei, deg);
    k_scan<<<1, 1024, 0, stream>>>(deg, offs, cursor);
    k_scatter<<<(E_TOT + 255) / 256, 256, 0, stream>>>(ei, cursor, csr_b, csr_dst);
    k_pad<<<(N_NODES * 4 + 255) / 256, 256, 0, stream>>>(cursor, offs, csr_b, csr_dst);

    dim3 gGemm((N_NODES + 31) / 32, B_BATCH);
    dim3 gAlpha((E_PAD + 255) / 256, B_BATCH);
    int gAgg = 16 * 625;   // (batch, head) combos x 625 blocks (16 dsts each), XCD-swizzled
    int gRed = B_BATCH * N_NODES * 16 / 256;

    // Layer 1
    k_gemm<F_IN_C><<<gGemm, 256, 0, stream>>>(x, W1, as1, ad1, h2, alsrc, aldst);
    k_alpha<<<gAlpha, 256, 0, stream>>>(alsrc, aldst, csr_b, csr_dst, offs, alpha);
    k_agg<<<gAgg, 256, 0, stream>>>(h2, alpha, offs, csr_b, oh);
    k_reduce<true><<<gRed, 256, 0, stream>>>(oh, b1, x2);

    // Layer 2
    k_gemm<HID_C><<<gGemm, 256, 0, stream>>>(x2, W2, as2, ad2, h2, alsrc, aldst);
    k_alpha<<<gAlpha, 256, 0, stream>>>(alsrc, aldst, csr_b, csr_dst, offs, alpha);
    k_agg<<<gAgg, 256, 0, stream>>>(h2, alpha, offs, csr_b, oh);
    k_reduce<false><<<gRed, 256, 0, stream>>>(oh, b2, out);
}

// Round 13
// 235.042 us; speedup vs baseline: 1.1501x; 1.0583x over previous
//
#include <hip/hip_runtime.h>
#include <hip/hip_fp16.h>
#include <math.h>

#define N_NODES 10000
#define B_BATCH 4
#define F_IN_C 128
#define HID_C 64
#define HEADS_C 4
#define E_EDGES 160000
#define E_TOT (E_EDGES + N_NODES)
#define E_PAD 200000   // E_TOT + 3*N_NODES upper bound, static stride for alpha
#define NEG_SLOPE 0.2f

typedef _Float16 half8 __attribute__((ext_vector_type(8)));
typedef float f32x4 __attribute__((ext_vector_type(4)));

// ---------------- CSR construction (padded to quad granularity) ----------------

__global__ void k_deg_init(int* __restrict__ deg) {
    int i = blockIdx.x * 256 + threadIdx.x;
    if (i < N_NODES) deg[i] = 1;  // self loop
}

__global__ void k_deg_count(const int* __restrict__ ei, int* __restrict__ deg) {
    int e = blockIdx.x * 256 + threadIdx.x;
    if (e < E_EDGES) atomicAdd(&deg[ei[E_EDGES + e]], 1);
}

// 1024 threads, 10 serial elems/thread, single LDS scan. Offsets use PADDED degrees
// ((deg+3)&~3) so every dst segment is 16B-aligned with quad-multiple length.
__global__ void k_scan(const int* __restrict__ deg, int* __restrict__ offs, int* __restrict__ cursor) {
    __shared__ int lds[1024];
    int t = threadIdx.x;
    int local[10];
    int tot = 0;
#pragma unroll
    for (int j = 0; j < 10; j++) {
        int i = t * 10 + j;
        int v = (i < N_NODES) ? ((deg[i] + 3) & ~3) : 0;
        tot += v;
        local[j] = tot;  // inclusive within chunk
    }
    lds[t] = tot;
    __syncthreads();
    for (int ofs = 1; ofs < 1024; ofs <<= 1) {
        int v = (t >= ofs) ? lds[t - ofs] : 0;
        __syncthreads();
        lds[t] += v;
        __syncthreads();
    }
    int base = lds[t] - tot;  // exclusive prefix of this chunk
#pragma unroll
    for (int j = 0; j < 10; j++) {
        int i = t * 10 + j;
        if (i < N_NODES) {
            offs[i + 1] = base + local[j];
            cursor[i] = (j == 0) ? base : base + local[j - 1];
        }
    }
    if (t == 0) offs[0] = 0;
}

// csr_b holds BYTE offsets (src*128, fp16 rows) for the h-row gather; csr_dst the destination.
__global__ void k_scatter(const int* __restrict__ ei, int* __restrict__ cursor,
                          int* __restrict__ csr_b, int* __restrict__ csr_dst) {
    int e = blockIdx.x * 256 + threadIdx.x;
    if (e < E_TOT) {
        int s, d;
        if (e < E_EDGES) { s = ei[e]; d = ei[E_EDGES + e]; }
        else { s = d = e - E_EDGES; }
        int pos = atomicAdd(&cursor[d], 1);
        csr_b[pos] = s << 7;     // src * 128 bytes (64 halves)
        csr_dst[pos] = d;
    }
}

// Fill pad slots (cursor[d] is the real end after scatter): csr_b=0, csr_dst=-1.
__global__ void k_pad(const int* __restrict__ cursor, const int* __restrict__ offs,
                      int* __restrict__ csr_b, int* __restrict__ csr_dst) {
    int tid = blockIdx.x * 256 + threadIdx.x;
    if (tid >= N_NODES * 4) return;
    int d = tid >> 2, ps = tid & 3;
    int pos = cursor[d] + ps;
    if (pos < offs[d + 1]) { csr_b[pos] = 0; csr_dst[pos] = -1; }
}

// ---------------- Wt_ext build: fp16 col-major [272][K] ----------------
// cols 0..255 = W^T; 256+hd = W @ a_src[hd] (al_src fused into GEMM); 260+hd = W @ a_dst;
// 264..271 = 0 pad. One thread per (nc, k).

template <int K>
__global__ void k_wext(const float* __restrict__ W, const float* __restrict__ asrc,
                       const float* __restrict__ adst, __half* __restrict__ Wt) {
    int tid = blockIdx.x * 256 + threadIdx.x;   // 272*K threads, exact multiple of 256
    int nc = tid / K, k = tid % K;
    float v;
    if (nc < 256) {
        v = W[k * 256 + nc];
    } else if (nc < 260) {
        int hd = nc - 256; v = 0.f;
        for (int c = 0; c < 64; c++) v += W[k * 256 + hd * 64 + c] * asrc[hd * 64 + c];
    } else if (nc < 264) {
        int hd = nc - 260; v = 0.f;
        for (int c = 0; c < 64; c++) v += W[k * 256 + hd * 64 + c] * adst[hd * 64 + c];
    } else {
        v = 0.f;
    }
    Wt[(size_t)nc * K + k] = __float2half(v);
}

// ---------------- MFMA GEMM: h = x@W (fp16 in, f32 accum, fp16 head-major out) ----------------
// mfma_f32_16x16x32_f16. Block = 16 nodes (M-tile), 4 waves; wave w owns head w (4 N-tiles
// = cols w*64..w*64+63); wave 0 additionally the al tile (cols 256..271 -> alsrc/aldst).
// Layouts (cdna4 guide / m89): A: row=lane&15, k=(lane>>4)*8+j. B: col=lane&15, same k.
// C/D: col=lane&15, row=(lane>>4)*4+reg. No LDS, no barriers: A = lane-direct 32 B x read
// (each 32 B chunk of the M-tile read exactly once per wave); B = contiguous 16 B Wt read.

template <int K>
__launch_bounds__(256)
__global__ void k_gemm(const float* __restrict__ x, const __half* __restrict__ Wt,
                       __half* __restrict__ h2, float* __restrict__ alsrc, float* __restrict__ aldst) {
    int t = threadIdx.x;
    int w = t >> 6, lane = t & 63;
    int b = blockIdx.y;
    int node0 = blockIdx.x * 16;           // 625*16 == 10000 exactly
    int col = lane & 15, kblk = lane >> 4;

    const float* xr = x + ((size_t)b * N_NODES + node0 + col) * K + kblk * 8;

    f32x4 acc0 = {0.f, 0.f, 0.f, 0.f};
    f32x4 acc1 = {0.f, 0.f, 0.f, 0.f};
    f32x4 acc2 = {0.f, 0.f, 0.f, 0.f};
    f32x4 acc3 = {0.f, 0.f, 0.f, 0.f};
    f32x4 accal = {0.f, 0.f, 0.f, 0.f};

#pragma unroll
    for (int k0 = 0; k0 < K; k0 += 32) {
        float4 xa = *(const float4*)(xr + k0);
        float4 xc = *(const float4*)(xr + k0 + 4);
        half8 a;
        a[0] = (_Float16)xa.x; a[1] = (_Float16)xa.y; a[2] = (_Float16)xa.z; a[3] = (_Float16)xa.w;
        a[4] = (_Float16)xc.x; a[5] = (_Float16)xc.y; a[6] = (_Float16)xc.z; a[7] = (_Float16)xc.w;
        const __half* wtk = Wt + kblk * 8 + k0;
        half8 b0 = *(const half8*)(wtk + (size_t)((w * 4 + 0) * 16 + col) * K);
        half8 b1 = *(const half8*)(wtk + (size_t)((w * 4 + 1) * 16 + col) * K);
        half8 b2 = *(const half8*)(wtk + (size_t)((w * 4 + 2) * 16 + col) * K);
        half8 b3 = *(const half8*)(wtk + (size_t)((w * 4 + 3) * 16 + col) * K);
        acc0 = __builtin_amdgcn_mfma_f32_16x16x32_f16(a, b0, acc0, 0, 0, 0);
        acc1 = __builtin_amdgcn_mfma_f32_16x16x32_f16(a, b1, acc1, 0, 0, 0);
        acc2 = __builtin_amdgcn_mfma_f32_16x16x32_f16(a, b2, acc2, 0, 0, 0);
        acc3 = __builtin_amdgcn_mfma_f32_16x16x32_f16(a, b3, acc3, 0, 0, 0);
        if (w == 0) {
            half8 bal = *(const half8*)(wtk + (size_t)(256 + col) * K);
            accal = __builtin_amdgcn_mfma_f32_16x16x32_f16(a, bal, accal, 0, 0, 0);
        }
    }

    // h2 stores: head-major fp16 rows of 64; wave w == head w; c = nt*16 + col;
    // node = node0 + kblk*4 + reg.
    {
        __half* dst = h2 + ((size_t)(b * 4 + w) * N_NODES + node0 + kblk * 4) * 64 + col;
#pragma unroll
        for (int r = 0; r < 4; r++) dst[(size_t)r * 64 + 0 * 16] = __float2half(acc0[r]);
#pragma unroll
        for (int r = 0; r < 4; r++) dst[(size_t)r * 64 + 1 * 16] = __float2half(acc1[r]);
#pragma unroll
        for (int r = 0; r < 4; r++) dst[(size_t)r * 64 + 2 * 16] = __float2half(acc2[r]);
#pragma unroll
        for (int r = 0; r < 4; r++) dst[(size_t)r * 64 + 3 * 16] = __float2half(acc3[r]);
    }
    if (w == 0 && col < 8) {
        int node = node0 + kblk * 4;
        size_t nb = (size_t)b * N_NODES;
        if (col < 4) {
            float* d = alsrc + (nb + node) * 4 + col;
#pragma unroll
            for (int r = 0; r < 4; r++) d[r * 4] = accal[r];
        } else {
            float* d = aldst + (nb + node) * 4 + (col - 4);
#pragma unroll
            for (int r = 0; r < 4; r++) d[r * 4] = accal[r];
        }
    }
}

// ---------------- Edge-parallel unnormalized attention: e = exp(leaky(al_src+al_dst)) ----------
// Softmax shift-invariance: logits O(1), no max-subtraction (validated absmax 2.4e-4).
// Pad slots (csr_dst<0) write 0 -> contribute nothing downstream. [b][hd][E_PAD] layout.

__launch_bounds__(256)
__global__ void k_alpha(const float* __restrict__ alsrc, const float* __restrict__ aldst,
                        const int* __restrict__ csr_b, const int* __restrict__ csr_dst,
                        const int* __restrict__ offs, float* __restrict__ alpha) {
    int j = blockIdx.x * 256 + threadIdx.x;
    int e_act = offs[N_NODES];
    if (j >= e_act) return;
    int b = blockIdx.y;
    size_t base = (size_t)b * 4 * E_PAD + j;
    int dst = csr_dst[j];
    if (dst < 0) {
        alpha[base] = 0.f;
        alpha[base + E_PAD] = 0.f;
        alpha[base + (size_t)2 * E_PAD] = 0.f;
        alpha[base + (size_t)3 * E_PAD] = 0.f;
        return;
    }
    int src4 = csr_b[j] >> 5;  // (src*128) -> src*4
    const float* als = alsrc + (size_t)b * N_NODES * 4;
    float4 s4 = *(const float4*)(als + src4);
    float4 d4 = *(const float4*)(aldst + ((size_t)b * N_NODES + dst) * 4);
    float a;
    a = s4.x + d4.x; a = a > 0.f ? a : NEG_SLOPE * a; float e0 = __expf(a);
    a = s4.y + d4.y; a = a > 0.f ? a : NEG_SLOPE * a; float e1 = __expf(a);
    a = s4.z + d4.z; a = a > 0.f ? a : NEG_SLOPE * a; float e2 = __expf(a);
    a = s4.w + d4.w; a = a > 0.f ? a : NEG_SLOPE * a; float e3 = __expf(a);
    alpha[base] = e0;
    alpha[base + E_PAD] = e1;
    alpha[base + (size_t)2 * E_PAD] = e2;
    alpha[base + (size_t)3 * E_PAD] = e3;
}

// ---------------- Gather-aggregate: 16-lane group owns one dst, fp16 rows ----------------
// 16 combos (batch, head) x 625 blocks (16 dsts each), XCD-swizzled -> per-XCD set 1.28 MB.
// fp16 rows (128 B = 2 lines) halve the line-miss demand (r11 MSHR model). 2-quad depth.
// Lane reads 8 B (4 halves), cvt to f32, FMA in f32. No cross-lane fold.

#define QUAD_FMA16(p4, g0, g1, g2, g3)                                                    \
    {                                                                                     \
        float2 f01, f23;                                                                  \
        f01 = __half22float2(*(__half2*)&g0.x); f23 = __half22float2(*(__half2*)&g0.y);   \
        acc.x += p4.x * f01.x; acc.y += p4.x * f01.y; acc.z += p4.x * f23.x; acc.w += p4.x * f23.y; \
        f01 = __half22float2(*(__half2*)&g1.x); f23 = __half22float2(*(__half2*)&g1.y);   \
        acc.x += p4.y * f01.x; acc.y += p4.y * f01.y; acc.z += p4.y * f23.x; acc.w += p4.y * f23.y; \
        f01 = __half22float2(*(__half2*)&g2.x); f23 = __half22float2(*(__half2*)&g2.y);   \
        acc.x += p4.z * f01.x; acc.y += p4.z * f01.y; acc.z += p4.z * f23.x; acc.w += p4.z * f23.y; \
        f01 = __half22float2(*(__half2*)&g3.x); f23 = __half22float2(*(__half2*)&g3.y);   \
        acc.x += p4.w * f01.x; acc.y += p4.w * f01.y; acc.z += p4.w * f23.x; acc.w += p4.w * f23.y; \
        sacc += p4.x + p4.y + p4.z + p4.w;                                                \
    }

__launch_bounds__(256)
__global__ void k_agg(const __half* __restrict__ h2, const float* __restrict__ alpha,
                      const int* __restrict__ offs, const int* __restrict__ csr_b,
                      float* __restrict__ oh) {
    int t = threadIdx.x;
    int bid = blockIdx.x;
    int combo = (bid & 7) + 8 * (bid / 5000);
    int local = (bid >> 3) % 625;
    int b = combo & 3, hd = combo >> 2;
    int wv = t >> 6, lane = t & 63;
    int grp = lane >> 4, cl = lane & 15;
    int dst = local * 16 + wv * 4 + grp;

    const char* hcb = (const char*)(h2 + (size_t)(b * 4 + hd) * N_NODES * 64);
    const float* ec = alpha + (size_t)(b * 4 + hd) * E_PAD;
    int s0 = offs[dst], s1 = offs[dst + 1];
    int cl8 = cl * 8;

    float4 acc = make_float4(0.f, 0.f, 0.f, 0.f);
    float sacc = 0.f;
    int j = s0;
    for (; j + 4 < s1; j += 8) {
        int4 ca = *(const int4*)(csr_b + j);
        int4 cb = *(const int4*)(csr_b + j + 4);
        float4 pa = *(const float4*)(ec + j);
        float4 pb = *(const float4*)(ec + j + 4);
        uint2 a0 = *(const uint2*)(hcb + (unsigned)(ca.x + cl8));
        uint2 a1 = *(const uint2*)(hcb + (unsigned)(ca.y + cl8));
        uint2 a2 = *(const uint2*)(hcb + (unsigned)(ca.z + cl8));
        uint2 a3 = *(const uint2*)(hcb + (unsigned)(ca.w + cl8));
        uint2 b0 = *(const uint2*)(hcb + (unsigned)(cb.x + cl8));
        uint2 b1 = *(const uint2*)(hcb + (unsigned)(cb.y + cl8));
        uint2 b2 = *(const uint2*)(hcb + (unsigned)(cb.z + cl8));
        uint2 b3 = *(const uint2*)(hcb + (unsigned)(cb.w + cl8));
        QUAD_FMA16(pa, a0, a1, a2, a3)
        QUAD_FMA16(pb, b0, b1, b2, b3)
    }
    if (j < s1) {  // one remaining quad
        int4 ca = *(const int4*)(csr_b + j);
        float4 pa = *(const float4*)(ec + j);
        uint2 a0 = *(const uint2*)(hcb + (unsigned)(ca.x + cl8));
        uint2 a1 = *(const uint2*)(hcb + (unsigned)(ca.y + cl8));
        uint2 a2 = *(const uint2*)(hcb + (unsigned)(ca.z + cl8));
        uint2 a3 = *(const uint2*)(hcb + (unsigned)(ca.w + cl8));
        QUAD_FMA16(pa, a0, a1, a2, a3)
    }
    float inv = 1.f / (sacc + 1e-16f);
    float4 r = make_float4(acc.x * inv, acc.y * inv, acc.z * inv, acc.w * inv);
    *(float4*)(oh + ((size_t)(b * 4 + hd) * N_NODES + dst) * 64 + cl * 4) = r;
}

// ---------------- Head mean + bias (+ELU for layer 1): pure streaming ----------------

template <bool LAYER1>
__launch_bounds__(256)
__global__ void k_reduce(const float* __restrict__ oh, const float* __restrict__ bias,
                         float* __restrict__ out) {
    int tid = blockIdx.x * 256 + threadIdx.x;  // B*N*16 threads, one float4 each
    int c4 = (tid & 15) * 4;
    int n = (tid >> 4) % N_NODES;
    int b = tid / (N_NODES * 16);
    size_t base = ((size_t)(b * 4) * N_NODES + n) * 64 + c4;
    float4 s = make_float4(0.f, 0.f, 0.f, 0.f);
#pragma unroll
    for (int hd = 0; hd < 4; hd++) {
        float4 v = *(const float4*)(oh + base + (size_t)hd * N_NODES * 64);
        s.x += v.x; s.y += v.y; s.z += v.z; s.w += v.w;
    }
    float4 b4 = *(const float4*)(bias + c4);
    float ox = s.x * 0.25f + b4.x;
    float oy = s.y * 0.25f + b4.y;
    float oz = s.z * 0.25f + b4.z;
    float ow = s.w * 0.25f + b4.w;
    if (LAYER1) {
        ox = ox > 0.f ? ox : expm1f(ox);
        oy = oy > 0.f ? oy : expm1f(oy);
        oz = oz > 0.f ? oz : expm1f(oz);
        ow = ow > 0.f ? ow : expm1f(ow);
    }
    *(float4*)(out + ((size_t)b * N_NODES + n) * 64 + c4) = make_float4(ox, oy, oz, ow);
}

// ---------------- Launch ----------------

extern "C" void kernel_launch(void* const* d_in, const int* in_sizes, int n_in,
                              void* d_out, int out_size, void* d_ws, size_t ws_size,
                              hipStream_t stream) {
    const float* x = (const float*)d_in[0];
    const int* ei = (const int*)d_in[1];
    const float* W1 = (const float*)d_in[2];
    const float* as1 = (const float*)d_in[3];
    const float* ad1 = (const float*)d_in[4];
    const float* b1 = (const float*)d_in[5];
    const float* W2 = (const float*)d_in[6];
    const float* as2 = (const float*)d_in[7];
    const float* ad2 = (const float*)d_in[8];
    const float* b2 = (const float*)d_in[9];
    float* out = (float*)d_out;

    // workspace layout (all segments 16B-aligned by construction)
    char* p = (char*)d_ws;
    int* deg = (int*)p;            p += sizeof(int) * N_NODES;
    int* offs = (int*)p;           p += sizeof(int) * (N_NODES + 4);
    int* cursor = (int*)p;         p += sizeof(int) * N_NODES;
    int* csr_b = (int*)p;          p += sizeof(int) * E_PAD;
    int* csr_dst = (int*)p;        p += sizeof(int) * E_PAD;
    __half* Wt1 = (__half*)p;      p += sizeof(__half) * 272 * F_IN_C;
    __half* Wt2 = (__half*)p;      p += sizeof(__half) * 272 * HID_C;
    float* alsrc = (float*)p;      p += sizeof(float) * B_BATCH * N_NODES * 4;
    float* aldst = (float*)p;      p += sizeof(float) * B_BATCH * N_NODES * 4;
    __half* h2 = (__half*)p;       p += sizeof(__half) * (size_t)B_BATCH * N_NODES * 256;
    float* oh = (float*)p;         p += sizeof(float) * (size_t)B_BATCH * N_NODES * 256;
    // alpha and x2 share one region (disjoint liveness), sized max(alpha, x2) = alpha.
    float* alpha = (float*)p;
    float* x2 = (float*)p;         p += sizeof(float) * (size_t)B_BATCH * 4 * E_PAD;

    // Wt_ext builds (independent of CSR)
    k_wext<F_IN_C><<<272 * F_IN_C / 256, 256, 0, stream>>>(W1, as1, ad1, Wt1);
    k_wext<HID_C><<<272 * HID_C / 256, 256, 0, stream>>>(W2, as2, ad2, Wt2);

    // CSR build (padded)
    k_deg_init<<<(N_NODES + 255) / 256, 256, 0, stream>>>(deg);
    k_deg_count<<<(E_EDGES + 255) / 256, 256, 0, stream>>>(ei, deg);
    k_scan<<<1, 1024, 0, stream>>>(deg, offs, cursor);
    k_scatter<<<(E_TOT + 255) / 256, 256, 0, stream>>>(ei, cursor, csr_b, csr_dst);
    k_pad<<<(N_NODES * 4 + 255) / 256, 256, 0, stream>>>(cursor, offs, csr_b, csr_dst);

    dim3 gGemm(N_NODES / 16, B_BATCH);
    dim3 gAlpha((E_PAD + 255) / 256, B_BATCH);
    int gAgg = 16 * 625;   // (batch, head) combos x 625 blocks (16 dsts each), XCD-swizzled
    int gRed = B_BATCH * N_NODES * 16 / 256;

    // Layer 1
    k_gemm<F_IN_C><<<gGemm, 256, 0, stream>>>(x, Wt1, h2, alsrc, aldst);
    k_alpha<<<gAlpha, 256, 0, stream>>>(alsrc, aldst, csr_b, csr_dst, offs, alpha);
    k_agg<<<gAgg, 256, 0, stream>>>(h2, alpha, offs, csr_b, oh);
    k_reduce<true><<<gRed, 256, 0, stream>>>(oh, b1, x2);

    // Layer 2
    k_gemm<HID_C><<<gGemm, 256, 0, stream>>>(x2, Wt2, h2, alsrc, aldst);
    k_alpha<<<gAlpha, 256, 0, stream>>>(alsrc, aldst, csr_b, csr_dst, offs, alpha);
    k_agg<<<gAgg, 256, 0, stream>>>(h2, alpha, offs, csr_b, oh);
    k_reduce<false><<<gRed, 256, 0, stream>>>(oh, b2, out);
}

// Round 14
// 220.715 us; speedup vs baseline: 1.2248x; 1.0649x over previous
//
#include <hip/hip_runtime.h>
#include <hip/hip_fp16.h>
#include <math.h>

#define N_NODES 10000
#define B_BATCH 4
#define F_IN_C 128
#define HID_C 64
#define HEADS_C 4
#define E_EDGES 160000
#define E_TOT (E_EDGES + N_NODES)
#define E_PAD 200000   // E_TOT + 3*N_NODES upper bound, static stride for alpha
#define NEG_SLOPE 0.2f

typedef _Float16 half8 __attribute__((ext_vector_type(8)));
typedef float f32x4 __attribute__((ext_vector_type(4)));

// ---------------- CSR construction (padded to quad granularity) ----------------

__global__ void k_deg_init(int* __restrict__ deg) {
    int i = blockIdx.x * 256 + threadIdx.x;
    if (i < N_NODES) deg[i] = 1;  // self loop
}

__global__ void k_deg_count(const int* __restrict__ ei, int* __restrict__ deg) {
    int e = blockIdx.x * 256 + threadIdx.x;
    if (e < E_EDGES) atomicAdd(&deg[ei[E_EDGES + e]], 1);
}

// 1024 threads, 10 serial elems/thread, single LDS scan. Offsets use PADDED degrees
// ((deg+3)&~3) so every dst segment is 16B-aligned with quad-multiple length.
__global__ void k_scan(const int* __restrict__ deg, int* __restrict__ offs, int* __restrict__ cursor) {
    __shared__ int lds[1024];
    int t = threadIdx.x;
    int local[10];
    int tot = 0;
#pragma unroll
    for (int j = 0; j < 10; j++) {
        int i = t * 10 + j;
        int v = (i < N_NODES) ? ((deg[i] + 3) & ~3) : 0;
        tot += v;
        local[j] = tot;  // inclusive within chunk
    }
    lds[t] = tot;
    __syncthreads();
    for (int ofs = 1; ofs < 1024; ofs <<= 1) {
        int v = (t >= ofs) ? lds[t - ofs] : 0;
        __syncthreads();
        lds[t] += v;
        __syncthreads();
    }
    int base = lds[t] - tot;  // exclusive prefix of this chunk
#pragma unroll
    for (int j = 0; j < 10; j++) {
        int i = t * 10 + j;
        if (i < N_NODES) {
            offs[i + 1] = base + local[j];
            cursor[i] = (j == 0) ? base : base + local[j - 1];
        }
    }
    if (t == 0) offs[0] = 0;
}

// csr_b holds BYTE offsets (src*128, fp16 rows) for the h-row gather; csr_dst the destination.
__global__ void k_scatter(const int* __restrict__ ei, int* __restrict__ cursor,
                          int* __restrict__ csr_b, int* __restrict__ csr_dst) {
    int e = blockIdx.x * 256 + threadIdx.x;
    if (e < E_TOT) {
        int s, d;
        if (e < E_EDGES) { s = ei[e]; d = ei[E_EDGES + e]; }
        else { s = d = e - E_EDGES; }
        int pos = atomicAdd(&cursor[d], 1);
        csr_b[pos] = s << 7;     // src * 128 bytes (64 halves)
        csr_dst[pos] = d;
    }
}

// Fill pad slots (cursor[d] is the real end after scatter): csr_b=0, csr_dst=-1.
__global__ void k_pad(const int* __restrict__ cursor, const int* __restrict__ offs,
                      int* __restrict__ csr_b, int* __restrict__ csr_dst) {
    int tid = blockIdx.x * 256 + threadIdx.x;
    if (tid >= N_NODES * 4) return;
    int d = tid >> 2, ps = tid & 3;
    int pos = cursor[d] + ps;
    if (pos < offs[d + 1]) { csr_b[pos] = 0; csr_dst[pos] = -1; }
}

// ---------------- Wt_ext build: fp16 col-major [272][K] ----------------
// cols 0..255 = W^T; 256+hd = W @ a_src[hd] (al_src fused into GEMM); 260+hd = W @ a_dst;
// 264..271 = 0 pad. One thread per (nc, k).

template <int K>
__global__ void k_wext(const float* __restrict__ W, const float* __restrict__ asrc,
                       const float* __restrict__ adst, __half* __restrict__ Wt) {
    int tid = blockIdx.x * 256 + threadIdx.x;   // 272*K threads, exact multiple of 256
    int nc = tid / K, k = tid % K;
    float v;
    if (nc < 256) {
        v = W[k * 256 + nc];
    } else if (nc < 260) {
        int hd = nc - 256; v = 0.f;
        for (int c = 0; c < 64; c++) v += W[k * 256 + hd * 64 + c] * asrc[hd * 64 + c];
    } else if (nc < 264) {
        int hd = nc - 260; v = 0.f;
        for (int c = 0; c < 64; c++) v += W[k * 256 + hd * 64 + c] * adst[hd * 64 + c];
    } else {
        v = 0.f;
    }
    Wt[(size_t)nc * K + k] = __float2half(v);
}

// ---------------- MFMA GEMM: h = x@W (fp16 in, f32 accum, fp16 head-major out) ----------------
// mfma_f32_16x16x32_f16. Block = 16 nodes (M-tile), 4 waves; wave w owns head w (4 N-tiles);
// wave 0 additionally the al tile (cols 256..271 -> alsrc/aldst). No LDS, no barriers.
// A: row=lane&15, k=(lane>>4)*8+j. B: col=lane&15. C/D: col=lane&15, row=(lane>>4)*4+reg.
// XT = float (layer 1, cvt to fp16) or __half (layer 2, direct half8 load).

template <int K, typename XT>
__launch_bounds__(256)
__global__ void k_gemm(const XT* __restrict__ x, const __half* __restrict__ Wt,
                       __half* __restrict__ h2, float* __restrict__ alsrc, float* __restrict__ aldst) {
    int t = threadIdx.x;
    int w = t >> 6, lane = t & 63;
    int b = blockIdx.y;
    int node0 = blockIdx.x * 16;           // 625*16 == 10000 exactly
    int col = lane & 15, kblk = lane >> 4;

    const XT* xr = x + ((size_t)b * N_NODES + node0 + col) * K + kblk * 8;

    f32x4 acc0 = {0.f, 0.f, 0.f, 0.f};
    f32x4 acc1 = {0.f, 0.f, 0.f, 0.f};
    f32x4 acc2 = {0.f, 0.f, 0.f, 0.f};
    f32x4 acc3 = {0.f, 0.f, 0.f, 0.f};
    f32x4 accal = {0.f, 0.f, 0.f, 0.f};

#pragma unroll
    for (int k0 = 0; k0 < K; k0 += 32) {
        half8 a;
        if constexpr (sizeof(XT) == 4) {
            float4 xa = *(const float4*)(xr + k0);
            float4 xc = *(const float4*)(xr + k0 + 4);
            a[0] = (_Float16)xa.x; a[1] = (_Float16)xa.y; a[2] = (_Float16)xa.z; a[3] = (_Float16)xa.w;
            a[4] = (_Float16)xc.x; a[5] = (_Float16)xc.y; a[6] = (_Float16)xc.z; a[7] = (_Float16)xc.w;
        } else {
            a = *(const half8*)(xr + k0);
        }
        const __half* wtk = Wt + kblk * 8 + k0;
        half8 b0 = *(const half8*)(wtk + (size_t)((w * 4 + 0) * 16 + col) * K);
        half8 b1 = *(const half8*)(wtk + (size_t)((w * 4 + 1) * 16 + col) * K);
        half8 b2 = *(const half8*)(wtk + (size_t)((w * 4 + 2) * 16 + col) * K);
        half8 b3 = *(const half8*)(wtk + (size_t)((w * 4 + 3) * 16 + col) * K);
        acc0 = __builtin_amdgcn_mfma_f32_16x16x32_f16(a, b0, acc0, 0, 0, 0);
        acc1 = __builtin_amdgcn_mfma_f32_16x16x32_f16(a, b1, acc1, 0, 0, 0);
        acc2 = __builtin_amdgcn_mfma_f32_16x16x32_f16(a, b2, acc2, 0, 0, 0);
        acc3 = __builtin_amdgcn_mfma_f32_16x16x32_f16(a, b3, acc3, 0, 0, 0);
        if (w == 0) {
            half8 bal = *(const half8*)(wtk + (size_t)(256 + col) * K);
            accal = __builtin_amdgcn_mfma_f32_16x16x32_f16(a, bal, accal, 0, 0, 0);
        }
    }

    // h2 stores: head-major fp16 rows of 64; wave w == head w; c = nt*16 + col;
    // node = node0 + kblk*4 + reg.
    {
        __half* dst = h2 + ((size_t)(b * 4 + w) * N_NODES + node0 + kblk * 4) * 64 + col;
#pragma unroll
        for (int r = 0; r < 4; r++) dst[(size_t)r * 64 + 0 * 16] = __float2half(acc0[r]);
#pragma unroll
        for (int r = 0; r < 4; r++) dst[(size_t)r * 64 + 1 * 16] = __float2half(acc1[r]);
#pragma unroll
        for (int r = 0; r < 4; r++) dst[(size_t)r * 64 + 2 * 16] = __float2half(acc2[r]);
#pragma unroll
        for (int r = 0; r < 4; r++) dst[(size_t)r * 64 + 3 * 16] = __float2half(acc3[r]);
    }
    if (w == 0 && col < 8) {
        int node = node0 + kblk * 4;
        size_t nb = (size_t)b * N_NODES;
        if (col < 4) {
            float* d = alsrc + (nb + node) * 4 + col;
#pragma unroll
            for (int r = 0; r < 4; r++) d[r * 4] = accal[r];
        } else {
            float* d = aldst + (nb + node) * 4 + (col - 4);
#pragma unroll
            for (int r = 0; r < 4; r++) d[r * 4] = accal[r];
        }
    }
}

// ---------------- Edge-parallel unnormalized attention: e = exp(leaky(al_src+al_dst)) ----------
// Softmax shift-invariance: logits O(1), no max-subtraction (validated absmax 2.4e-4).
// Pad slots (csr_dst<0) write 0 -> contribute nothing downstream. [b][hd][E_PAD] layout.

__launch_bounds__(256)
__global__ void k_alpha(const float* __restrict__ alsrc, const float* __restrict__ aldst,
                        const int* __restrict__ csr_b, const int* __restrict__ csr_dst,
                        const int* __restrict__ offs, float* __restrict__ alpha) {
    int j = blockIdx.x * 256 + threadIdx.x;
    int e_act = offs[N_NODES];
    if (j >= e_act) return;
    int b = blockIdx.y;
    size_t base = (size_t)b * 4 * E_PAD + j;
    int dst = csr_dst[j];
    if (dst < 0) {
        alpha[base] = 0.f;
        alpha[base + E_PAD] = 0.f;
        alpha[base + (size_t)2 * E_PAD] = 0.f;
        alpha[base + (size_t)3 * E_PAD] = 0.f;
        return;
    }
    int src4 = csr_b[j] >> 5;  // (src*128) -> src*4
    const float* als = alsrc + (size_t)b * N_NODES * 4;
    float4 s4 = *(const float4*)(als + src4);
    float4 d4 = *(const float4*)(aldst + ((size_t)b * N_NODES + dst) * 4);
    float a;
    a = s4.x + d4.x; a = a > 0.f ? a : NEG_SLOPE * a; float e0 = __expf(a);
    a = s4.y + d4.y; a = a > 0.f ? a : NEG_SLOPE * a; float e1 = __expf(a);
    a = s4.z + d4.z; a = a > 0.f ? a : NEG_SLOPE * a; float e2 = __expf(a);
    a = s4.w + d4.w; a = a > 0.f ? a : NEG_SLOPE * a; float e3 = __expf(a);
    alpha[base] = e0;
    alpha[base + E_PAD] = e1;
    alpha[base + (size_t)2 * E_PAD] = e2;
    alpha[base + (size_t)3 * E_PAD] = e3;
}

// ---------------- Gather-aggregate: software-pipelined quad walk, fp16 rows/output --------------
// 16 combos (batch, head) x 625 blocks (16 dsts each), XCD-swizzled -> per-XCD set 1.28 MB.
// r13 post-mortem: latency-chain bound (csr->gather->FMA serial). Rotating 1-quad pipeline:
// next quad's index/alpha/gather loads issue BEFORE current quad's FMA block. Padded segments
// guarantee len>=4 and len%4==0. Output written as fp16 (halves oh round-trip traffic).

#define QUAD_FMA16(p4, g0, g1, g2, g3)                                                    \
    {                                                                                     \
        float2 f01, f23;                                                                  \
        f01 = __half22float2(*(__half2*)&g0.x); f23 = __half22float2(*(__half2*)&g0.y);   \
        acc.x += p4.x * f01.x; acc.y += p4.x * f01.y; acc.z += p4.x * f23.x; acc.w += p4.x * f23.y; \
        f01 = __half22float2(*(__half2*)&g1.x); f23 = __half22float2(*(__half2*)&g1.y);   \
        acc.x += p4.y * f01.x; acc.y += p4.y * f01.y; acc.z += p4.y * f23.x; acc.w += p4.y * f23.y; \
        f01 = __half22float2(*(__half2*)&g2.x); f23 = __half22float2(*(__half2*)&g2.y);   \
        acc.x += p4.z * f01.x; acc.y += p4.z * f01.y; acc.z += p4.z * f23.x; acc.w += p4.z * f23.y; \
        f01 = __half22float2(*(__half2*)&g3.x); f23 = __half22float2(*(__half2*)&g3.y);   \
        acc.x += p4.w * f01.x; acc.y += p4.w * f01.y; acc.z += p4.w * f23.x; acc.w += p4.w * f23.y; \
        sacc += p4.x + p4.y + p4.z + p4.w;                                                \
    }

__launch_bounds__(256)
__global__ void k_agg(const __half* __restrict__ h2, const float* __restrict__ alpha,
                      const int* __restrict__ offs, const int* __restrict__ csr_b,
                      __half* __restrict__ oh) {
    int t = threadIdx.x;
    int bid = blockIdx.x;
    int combo = (bid & 7) + 8 * (bid / 5000);
    int local = (bid >> 3) % 625;
    int b = combo & 3, hd = combo >> 2;
    int wv = t >> 6, lane = t & 63;
    int grp = lane >> 4, cl = lane & 15;
    int dst = local * 16 + wv * 4 + grp;

    const char* hcb = (const char*)(h2 + (size_t)(b * 4 + hd) * N_NODES * 64);
    const float* ec = alpha + (size_t)(b * 4 + hd) * E_PAD;
    int s0 = offs[dst], s1 = offs[dst + 1];
    int cl8 = cl * 8;

    float4 acc = make_float4(0.f, 0.f, 0.f, 0.f);
    float sacc = 0.f;
    // prologue: first quad (always exists: padded deg >= 4)
    int4 c0 = *(const int4*)(csr_b + s0);
    float4 p0 = *(const float4*)(ec + s0);
    uint2 g0 = *(const uint2*)(hcb + (unsigned)(c0.x + cl8));
    uint2 g1 = *(const uint2*)(hcb + (unsigned)(c0.y + cl8));
    uint2 g2 = *(const uint2*)(hcb + (unsigned)(c0.z + cl8));
    uint2 g3 = *(const uint2*)(hcb + (unsigned)(c0.w + cl8));
    for (int j = s0 + 4; j < s1; j += 4) {
        int4 c1 = *(const int4*)(csr_b + j);
        float4 p1 = *(const float4*)(ec + j);
        uint2 m0 = *(const uint2*)(hcb + (unsigned)(c1.x + cl8));
        uint2 m1 = *(const uint2*)(hcb + (unsigned)(c1.y + cl8));
        uint2 m2 = *(const uint2*)(hcb + (unsigned)(c1.z + cl8));
        uint2 m3 = *(const uint2*)(hcb + (unsigned)(c1.w + cl8));
        QUAD_FMA16(p0, g0, g1, g2, g3)
        g0 = m0; g1 = m1; g2 = m2; g3 = m3; p0 = p1;
    }
    QUAD_FMA16(p0, g0, g1, g2, g3)

    float inv = 1.f / (sacc + 1e-16f);
    __half2 lo = __floats2half2_rn(acc.x * inv, acc.y * inv);
    __half2 hi = __floats2half2_rn(acc.z * inv, acc.w * inv);
    uint2 pk = make_uint2(*(unsigned*)&lo, *(unsigned*)&hi);
    *(uint2*)(oh + ((size_t)(b * 4 + hd) * N_NODES + dst) * 64 + cl * 4) = pk;
}

// ---------------- Head mean + bias (+ELU for layer 1): pure streaming ----------------
// LAYER1 writes fp16 (x2 feeds the fp16 MFMA GEMM directly); layer 2 writes f32 output.

template <bool LAYER1>
__launch_bounds__(256)
__global__ void k_reduce(const __half* __restrict__ oh, const float* __restrict__ bias,
                         void* __restrict__ outv) {
    int tid = blockIdx.x * 256 + threadIdx.x;  // B*N*16 threads, 4 channels each
    int c4 = (tid & 15) * 4;
    int n = (tid >> 4) % N_NODES;
    int b = tid / (N_NODES * 16);
    size_t base = ((size_t)(b * 4) * N_NODES + n) * 64 + c4;
    float4 s = make_float4(0.f, 0.f, 0.f, 0.f);
#pragma unroll
    for (int hd = 0; hd < 4; hd++) {
        uint2 v = *(const uint2*)(oh + base + (size_t)hd * N_NODES * 64);
        float2 f01 = __half22float2(*(__half2*)&v.x);
        float2 f23 = __half22float2(*(__half2*)&v.y);
        s.x += f01.x; s.y += f01.y; s.z += f23.x; s.w += f23.y;
    }
    float4 b4 = *(const float4*)(bias + c4);
    float ox = s.x * 0.25f + b4.x;
    float oy = s.y * 0.25f + b4.y;
    float oz = s.z * 0.25f + b4.z;
    float ow = s.w * 0.25f + b4.w;
    if (LAYER1) {
        ox = ox > 0.f ? ox : expm1f(ox);
        oy = oy > 0.f ? oy : expm1f(oy);
        oz = oz > 0.f ? oz : expm1f(oz);
        ow = ow > 0.f ? ow : expm1f(ow);
        __half2 lo = __floats2half2_rn(ox, oy);
        __half2 hi = __floats2half2_rn(oz, ow);
        uint2 pk = make_uint2(*(unsigned*)&lo, *(unsigned*)&hi);
        *(uint2*)((__half*)outv + ((size_t)b * N_NODES + n) * 64 + c4) = pk;
    } else {
        *(float4*)((float*)outv + ((size_t)b * N_NODES + n) * 64 + c4) = make_float4(ox, oy, oz, ow);
    }
}

// ---------------- Launch ----------------

extern "C" void kernel_launch(void* const* d_in, const int* in_sizes, int n_in,
                              void* d_out, int out_size, void* d_ws, size_t ws_size,
                              hipStream_t stream) {
    const float* x = (const float*)d_in[0];
    const int* ei = (const int*)d_in[1];
    const float* W1 = (const float*)d_in[2];
    const float* as1 = (const float*)d_in[3];
    const float* ad1 = (const float*)d_in[4];
    const float* b1 = (const float*)d_in[5];
    const float* W2 = (const float*)d_in[6];
    const float* as2 = (const float*)d_in[7];
    const float* ad2 = (const float*)d_in[8];
    const float* b2 = (const float*)d_in[9];
    float* out = (float*)d_out;

    // workspace layout (all segments 16B-aligned by construction)
    char* p = (char*)d_ws;
    int* deg = (int*)p;            p += sizeof(int) * N_NODES;
    int* offs = (int*)p;           p += sizeof(int) * (N_NODES + 4);
    int* cursor = (int*)p;         p += sizeof(int) * N_NODES;
    int* csr_b = (int*)p;          p += sizeof(int) * E_PAD;
    int* csr_dst = (int*)p;        p += sizeof(int) * E_PAD;
    __half* Wt1 = (__half*)p;      p += sizeof(__half) * 272 * F_IN_C;
    __half* Wt2 = (__half*)p;      p += sizeof(__half) * 272 * HID_C;
    float* alsrc = (float*)p;      p += sizeof(float) * B_BATCH * N_NODES * 4;
    float* aldst = (float*)p;      p += sizeof(float) * B_BATCH * N_NODES * 4;
    __half* h2 = (__half*)p;       p += sizeof(__half) * (size_t)B_BATCH * N_NODES * 256;
    __half* oh = (__half*)p;       p += sizeof(__half) * (size_t)B_BATCH * N_NODES * 256;
    __half* x2 = (__half*)p;       p += sizeof(__half) * (size_t)B_BATCH * N_NODES * 64;
    p = (char*)(((size_t)p + 15) & ~(size_t)15);
    float* alpha = (float*)p;      p += sizeof(float) * (size_t)B_BATCH * 4 * E_PAD;

    // Wt_ext builds (independent of CSR)
    k_wext<F_IN_C><<<272 * F_IN_C / 256, 256, 0, stream>>>(W1, as1, ad1, Wt1);
    k_wext<HID_C><<<272 * HID_C / 256, 256, 0, stream>>>(W2, as2, ad2, Wt2);

    // CSR build (padded)
    k_deg_init<<<(N_NODES + 255) / 256, 256, 0, stream>>>(deg);
    k_deg_count<<<(E_EDGES + 255) / 256, 256, 0, stream>>>(ei, deg);
    k_scan<<<1, 1024, 0, stream>>>(deg, offs, cursor);
    k_scatter<<<(E_TOT + 255) / 256, 256, 0, stream>>>(ei, cursor, csr_b, csr_dst);
    k_pad<<<(N_NODES * 4 + 255) / 256, 256, 0, stream>>>(cursor, offs, csr_b, csr_dst);

    dim3 gGemm(N_NODES / 16, B_BATCH);
    dim3 gAlpha((E_PAD + 255) / 256, B_BATCH);
    int gAgg = 16 * 625;   // (batch, head) combos x 625 blocks (16 dsts each), XCD-swizzled
    int gRed = B_BATCH * N_NODES * 16 / 256;

    // Layer 1
    k_gemm<F_IN_C, float><<<gGemm, 256, 0, stream>>>(x, Wt1, h2, alsrc, aldst);
    k_alpha<<<gAlpha, 256, 0, stream>>>(alsrc, aldst, csr_b, csr_dst, offs, alpha);
    k_agg<<<gAgg, 256, 0, stream>>>(h2, alpha, offs, csr_b, oh);
    k_reduce<true><<<gRed, 256, 0, stream>>>(oh, b1, x2);

    // Layer 2
    k_gemm<HID_C, __half><<<gGemm, 256, 0, stream>>>(x2, Wt2, h2, alsrc, aldst);
    k_alpha<<<gAlpha, 256, 0, stream>>>(alsrc, aldst, csr_b, csr_dst, offs, alpha);
    k_agg<<<gAgg, 256, 0, stream>>>(h2, alpha, offs, csr_b, oh);
    k_reduce<false><<<gRed, 256, 0, stream>>>(oh, b2, out);
}

// Round 15
// 220.574 us; speedup vs baseline: 1.2256x; 1.0006x over previous
//
#include <hip/hip_runtime.h>
#include <hip/hip_fp16.h>
#include <math.h>

#define N_NODES 10000
#define B_BATCH 4
#define F_IN_C 128
#define HID_C 64
#define HEADS_C 4
#define E_EDGES 160000
#define E_TOT (E_EDGES + N_NODES)
#define E_PAD 200000   // E_TOT + 3*N_NODES upper bound, static stride for alpha
#define NEG_SLOPE 0.2f

typedef _Float16 half8 __attribute__((ext_vector_type(8)));
typedef float f32x4 __attribute__((ext_vector_type(4)));

// ---------------- CSR construction (padded to quad granularity) ----------------

__global__ void k_deg_init(int* __restrict__ deg) {
    int i = blockIdx.x * 256 + threadIdx.x;
    if (i < N_NODES) deg[i] = 1;  // self loop
}

__global__ void k_deg_count(const int* __restrict__ ei, int* __restrict__ deg) {
    int e = blockIdx.x * 256 + threadIdx.x;
    if (e < E_EDGES) atomicAdd(&deg[ei[E_EDGES + e]], 1);
}

// 1024 threads, 10 serial elems/thread, single LDS scan. Offsets use PADDED degrees
// ((deg+3)&~3) so every dst segment is 16B-aligned with quad-multiple length.
__global__ void k_scan(const int* __restrict__ deg, int* __restrict__ offs, int* __restrict__ cursor) {
    __shared__ int lds[1024];
    int t = threadIdx.x;
    int local[10];
    int tot = 0;
#pragma unroll
    for (int j = 0; j < 10; j++) {
        int i = t * 10 + j;
        int v = (i < N_NODES) ? ((deg[i] + 3) & ~3) : 0;
        tot += v;
        local[j] = tot;  // inclusive within chunk
    }
    lds[t] = tot;
    __syncthreads();
    for (int ofs = 1; ofs < 1024; ofs <<= 1) {
        int v = (t >= ofs) ? lds[t - ofs] : 0;
        __syncthreads();
        lds[t] += v;
        __syncthreads();
    }
    int base = lds[t] - tot;  // exclusive prefix of this chunk
#pragma unroll
    for (int j = 0; j < 10; j++) {
        int i = t * 10 + j;
        if (i < N_NODES) {
            offs[i + 1] = base + local[j];
            cursor[i] = (j == 0) ? base : base + local[j - 1];
        }
    }
    if (t == 0) offs[0] = 0;
}

// csr_b holds BYTE offsets (src*128, fp16 rows) for the h-row gather; csr_dst the destination.
__global__ void k_scatter(const int* __restrict__ ei, int* __restrict__ cursor,
                          int* __restrict__ csr_b, int* __restrict__ csr_dst) {
    int e = blockIdx.x * 256 + threadIdx.x;
    if (e < E_TOT) {
        int s, d;
        if (e < E_EDGES) { s = ei[e]; d = ei[E_EDGES + e]; }
        else { s = d = e - E_EDGES; }
        int pos = atomicAdd(&cursor[d], 1);
        csr_b[pos] = s << 7;     // src * 128 bytes (64 halves)
        csr_dst[pos] = d;
    }
}

// Fill pad slots (cursor[d] is the real end after scatter): csr_b=0, csr_dst=-1.
__global__ void k_pad(const int* __restrict__ cursor, const int* __restrict__ offs,
                      int* __restrict__ csr_b, int* __restrict__ csr_dst) {
    int tid = blockIdx.x * 256 + threadIdx.x;
    if (tid >= N_NODES * 4) return;
    int d = tid >> 2, ps = tid & 3;
    int pos = cursor[d] + ps;
    if (pos < offs[d + 1]) { csr_b[pos] = 0; csr_dst[pos] = -1; }
}

// ---------------- Wt_ext build: fp16 col-major [272][K] ----------------
// cols 0..255 = W^T; 256+hd = W @ a_src[hd] (al_src fused into GEMM); 260+hd = W @ a_dst;
// 264..271 = 0 pad. One thread per (nc, k).

template <int K>
__global__ void k_wext(const float* __restrict__ W, const float* __restrict__ asrc,
                       const float* __restrict__ adst, __half* __restrict__ Wt) {
    int tid = blockIdx.x * 256 + threadIdx.x;   // 272*K threads, exact multiple of 256
    int nc = tid / K, k = tid % K;
    float v;
    if (nc < 256) {
        v = W[k * 256 + nc];
    } else if (nc < 260) {
        int hd = nc - 256; v = 0.f;
        for (int c = 0; c < 64; c++) v += W[k * 256 + hd * 64 + c] * asrc[hd * 64 + c];
    } else if (nc < 264) {
        int hd = nc - 260; v = 0.f;
        for (int c = 0; c < 64; c++) v += W[k * 256 + hd * 64 + c] * adst[hd * 64 + c];
    } else {
        v = 0.f;
    }
    Wt[(size_t)nc * K + k] = __float2half(v);
}

// ---------------- MFMA GEMM: h = x@W (fp16 in, f32 accum, fp16 head-major out) ----------------
// mfma_f32_16x16x32_f16. Block = 16 nodes (M-tile), 4 waves; wave w owns head w (4 N-tiles);
// wave 0 additionally the al tile (cols 256..271 -> alsrc/aldst). No LDS, no barriers.
// A: row=lane&15, k=(lane>>4)*8+j. B: col=lane&15. C/D: col=lane&15, row=(lane>>4)*4+reg.
// XT = float (layer 1, cvt to fp16) or __half (layer 2, direct half8 load).

template <int K, typename XT>
__launch_bounds__(256)
__global__ void k_gemm(const XT* __restrict__ x, const __half* __restrict__ Wt,
                       __half* __restrict__ h2, float* __restrict__ alsrc, float* __restrict__ aldst) {
    int t = threadIdx.x;
    int w = t >> 6, lane = t & 63;
    int b = blockIdx.y;
    int node0 = blockIdx.x * 16;           // 625*16 == 10000 exactly
    int col = lane & 15, kblk = lane >> 4;

    const XT* xr = x + ((size_t)b * N_NODES + node0 + col) * K + kblk * 8;

    f32x4 acc0 = {0.f, 0.f, 0.f, 0.f};
    f32x4 acc1 = {0.f, 0.f, 0.f, 0.f};
    f32x4 acc2 = {0.f, 0.f, 0.f, 0.f};
    f32x4 acc3 = {0.f, 0.f, 0.f, 0.f};
    f32x4 accal = {0.f, 0.f, 0.f, 0.f};

#pragma unroll
    for (int k0 = 0; k0 < K; k0 += 32) {
        half8 a;
        if constexpr (sizeof(XT) == 4) {
            float4 xa = *(const float4*)(xr + k0);
            float4 xc = *(const float4*)(xr + k0 + 4);
            a[0] = (_Float16)xa.x; a[1] = (_Float16)xa.y; a[2] = (_Float16)xa.z; a[3] = (_Float16)xa.w;
            a[4] = (_Float16)xc.x; a[5] = (_Float16)xc.y; a[6] = (_Float16)xc.z; a[7] = (_Float16)xc.w;
        } else {
            a = *(const half8*)(xr + k0);
        }
        const __half* wtk = Wt + kblk * 8 + k0;
        half8 b0 = *(const half8*)(wtk + (size_t)((w * 4 + 0) * 16 + col) * K);
        half8 b1 = *(const half8*)(wtk + (size_t)((w * 4 + 1) * 16 + col) * K);
        half8 b2 = *(const half8*)(wtk + (size_t)((w * 4 + 2) * 16 + col) * K);
        half8 b3 = *(const half8*)(wtk + (size_t)((w * 4 + 3) * 16 + col) * K);
        acc0 = __builtin_amdgcn_mfma_f32_16x16x32_f16(a, b0, acc0, 0, 0, 0);
        acc1 = __builtin_amdgcn_mfma_f32_16x16x32_f16(a, b1, acc1, 0, 0, 0);
        acc2 = __builtin_amdgcn_mfma_f32_16x16x32_f16(a, b2, acc2, 0, 0, 0);
        acc3 = __builtin_amdgcn_mfma_f32_16x16x32_f16(a, b3, acc3, 0, 0, 0);
        if (w == 0) {
            half8 bal = *(const half8*)(wtk + (size_t)(256 + col) * K);
            accal = __builtin_amdgcn_mfma_f32_16x16x32_f16(a, bal, accal, 0, 0, 0);
        }
    }

    // h2 stores: head-major fp16 rows of 64; wave w == head w; c = nt*16 + col;
    // node = node0 + kblk*4 + reg.
    {
        __half* dst = h2 + ((size_t)(b * 4 + w) * N_NODES + node0 + kblk * 4) * 64 + col;
#pragma unroll
        for (int r = 0; r < 4; r++) dst[(size_t)r * 64 + 0 * 16] = __float2half(acc0[r]);
#pragma unroll
        for (int r = 0; r < 4; r++) dst[(size_t)r * 64 + 1 * 16] = __float2half(acc1[r]);
#pragma unroll
        for (int r = 0; r < 4; r++) dst[(size_t)r * 64 + 2 * 16] = __float2half(acc2[r]);
#pragma unroll
        for (int r = 0; r < 4; r++) dst[(size_t)r * 64 + 3 * 16] = __float2half(acc3[r]);
    }
    if (w == 0 && col < 8) {
        int node = node0 + kblk * 4;
        size_t nb = (size_t)b * N_NODES;
        if (col < 4) {
            float* d = alsrc + (nb + node) * 4 + col;
#pragma unroll
            for (int r = 0; r < 4; r++) d[r * 4] = accal[r];
        } else {
            float* d = aldst + (nb + node) * 4 + (col - 4);
#pragma unroll
            for (int r = 0; r < 4; r++) d[r * 4] = accal[r];
        }
    }
}

// ---------------- Edge-parallel unnormalized attention: e = exp(leaky(al_src+al_dst)) ----------
// Softmax shift-invariance: logits O(1), no max-subtraction (validated absmax 2.4e-4).
// Pad slots (csr_dst<0) write 0 -> contribute nothing downstream. [b][hd][E_PAD] layout.

__launch_bounds__(256)
__global__ void k_alpha(const float* __restrict__ alsrc, const float* __restrict__ aldst,
                        const int* __restrict__ csr_b, const int* __restrict__ csr_dst,
                        const int* __restrict__ offs, float* __restrict__ alpha) {
    int j = blockIdx.x * 256 + threadIdx.x;
    int e_act = offs[N_NODES];
    if (j >= e_act) return;
    int b = blockIdx.y;
    size_t base = (size_t)b * 4 * E_PAD + j;
    int dst = csr_dst[j];
    if (dst < 0) {
        alpha[base] = 0.f;
        alpha[base + E_PAD] = 0.f;
        alpha[base + (size_t)2 * E_PAD] = 0.f;
        alpha[base + (size_t)3 * E_PAD] = 0.f;
        return;
    }
    int src4 = csr_b[j] >> 5;  // (src*128) -> src*4
    const float* als = alsrc + (size_t)b * N_NODES * 4;
    float4 s4 = *(const float4*)(als + src4);
    float4 d4 = *(const float4*)(aldst + ((size_t)b * N_NODES + dst) * 4);
    float a;
    a = s4.x + d4.x; a = a > 0.f ? a : NEG_SLOPE * a; float e0 = __expf(a);
    a = s4.y + d4.y; a = a > 0.f ? a : NEG_SLOPE * a; float e1 = __expf(a);
    a = s4.z + d4.z; a = a > 0.f ? a : NEG_SLOPE * a; float e2 = __expf(a);
    a = s4.w + d4.w; a = a > 0.f ? a : NEG_SLOPE * a; float e3 = __expf(a);
    alpha[base] = e0;
    alpha[base + E_PAD] = e1;
    alpha[base + (size_t)2 * E_PAD] = e2;
    alpha[base + (size_t)3 * E_PAD] = e3;
}

// ---------------- Gather-aggregate: depth-2 software pipeline, fp16 rows/output ----------------
// 16 combos (batch, head) x 625 blocks (16 dsts each), XCD-swizzled -> per-XCD set 1.28 MB.
// r14 post-mortem: ~470 cyc/iter = one exposed L2 round-trip; the index load fed its gathers
// IN the same iteration. Depth-2 rotation: index/alpha for quad k+2 load now (clamped addr,
// branchless); gathers for quad k+1 issue now; FMA consumes quad k. No same-iteration deps.

#define QUAD_FMA16(p4, g0, g1, g2, g3)                                                    \
    {                                                                                     \
        float2 f01, f23;                                                                  \
        f01 = __half22float2(*(__half2*)&g0.x); f23 = __half22float2(*(__half2*)&g0.y);   \
        acc.x += p4.x * f01.x; acc.y += p4.x * f01.y; acc.z += p4.x * f23.x; acc.w += p4.x * f23.y; \
        f01 = __half22float2(*(__half2*)&g1.x); f23 = __half22float2(*(__half2*)&g1.y);   \
        acc.x += p4.y * f01.x; acc.y += p4.y * f01.y; acc.z += p4.y * f23.x; acc.w += p4.y * f23.y; \
        f01 = __half22float2(*(__half2*)&g2.x); f23 = __half22float2(*(__half2*)&g2.y);   \
        acc.x += p4.z * f01.x; acc.y += p4.z * f01.y; acc.z += p4.z * f23.x; acc.w += p4.z * f23.y; \
        f01 = __half22float2(*(__half2*)&g3.x); f23 = __half22float2(*(__half2*)&g3.y);   \
        acc.x += p4.w * f01.x; acc.y += p4.w * f01.y; acc.z += p4.w * f23.x; acc.w += p4.w * f23.y; \
        sacc += p4.x + p4.y + p4.z + p4.w;                                                \
    }

__launch_bounds__(256)
__global__ void k_agg(const __half* __restrict__ h2, const float* __restrict__ alpha,
                      const int* __restrict__ offs, const int* __restrict__ csr_b,
                      __half* __restrict__ oh) {
    int t = threadIdx.x;
    int bid = blockIdx.x;
    int combo = (bid & 7) + 8 * (bid / 5000);
    int local = (bid >> 3) % 625;
    int b = combo & 3, hd = combo >> 2;
    int wv = t >> 6, lane = t & 63;
    int grp = lane >> 4, cl = lane & 15;
    int dst = local * 16 + wv * 4 + grp;

    const char* hcb = (const char*)(h2 + (size_t)(b * 4 + hd) * N_NODES * 64);
    const float* ec = alpha + (size_t)(b * 4 + hd) * E_PAD;
    int s0 = offs[dst], s1 = offs[dst + 1];
    int cl8 = cl * 8;

    float4 acc = make_float4(0.f, 0.f, 0.f, 0.f);
    float sacc = 0.f;
    // prologue: quad 0 fully staged (padded deg >= 4 guaranteed)
    int4 c_cur = *(const int4*)(csr_b + s0);
    float4 p_cur = *(const float4*)(ec + s0);
    uint2 g0 = *(const uint2*)(hcb + (unsigned)(c_cur.x + cl8));
    uint2 g1 = *(const uint2*)(hcb + (unsigned)(c_cur.y + cl8));
    uint2 g2 = *(const uint2*)(hcb + (unsigned)(c_cur.z + cl8));
    uint2 g3 = *(const uint2*)(hcb + (unsigned)(c_cur.w + cl8));
    // quad 1 index/alpha (clamped: always a valid quad address)
    int jn = (s0 + 4 < s1) ? s0 + 4 : s0;
    int4 c_nxt = *(const int4*)(csr_b + jn);
    float4 p_nxt = *(const float4*)(ec + jn);

    for (int j = s0 + 4; j < s1; j += 4) {
        // gathers for quad (k+1) -- index loaded a full iteration ago
        uint2 m0 = *(const uint2*)(hcb + (unsigned)(c_nxt.x + cl8));
        uint2 m1 = *(const uint2*)(hcb + (unsigned)(c_nxt.y + cl8));
        uint2 m2 = *(const uint2*)(hcb + (unsigned)(c_nxt.z + cl8));
        uint2 m3 = *(const uint2*)(hcb + (unsigned)(c_nxt.w + cl8));
        // index/alpha for quad (k+2), clamped (branchless, uniform arithmetic)
        int j2 = (j + 4 < s1) ? j + 4 : j;
        int4 c_tmp = *(const int4*)(csr_b + j2);
        float4 p_tmp = *(const float4*)(ec + j2);
        // consume quad k
        QUAD_FMA16(p_cur, g0, g1, g2, g3)
        g0 = m0; g1 = m1; g2 = m2; g3 = m3;
        p_cur = p_nxt;
        c_nxt = c_tmp; p_nxt = p_tmp;
    }
    QUAD_FMA16(p_cur, g0, g1, g2, g3)

    float inv = 1.f / (sacc + 1e-16f);
    __half2 lo = __floats2half2_rn(acc.x * inv, acc.y * inv);
    __half2 hi = __floats2half2_rn(acc.z * inv, acc.w * inv);
    uint2 pk = make_uint2(*(unsigned*)&lo, *(unsigned*)&hi);
    *(uint2*)(oh + ((size_t)(b * 4 + hd) * N_NODES + dst) * 64 + cl * 4) = pk;
}

// ---------------- Head mean + bias (+ELU for layer 1): pure streaming ----------------
// LAYER1 writes fp16 (x2 feeds the fp16 MFMA GEMM directly); layer 2 writes f32 output.

template <bool LAYER1>
__launch_bounds__(256)
__global__ void k_reduce(const __half* __restrict__ oh, const float* __restrict__ bias,
                         void* __restrict__ outv) {
    int tid = blockIdx.x * 256 + threadIdx.x;  // B*N*16 threads, 4 channels each
    int c4 = (tid & 15) * 4;
    int n = (tid >> 4) % N_NODES;
    int b = tid / (N_NODES * 16);
    size_t base = ((size_t)(b * 4) * N_NODES + n) * 64 + c4;
    float4 s = make_float4(0.f, 0.f, 0.f, 0.f);
#pragma unroll
    for (int hd = 0; hd < 4; hd++) {
        uint2 v = *(const uint2*)(oh + base + (size_t)hd * N_NODES * 64);
        float2 f01 = __half22float2(*(__half2*)&v.x);
        float2 f23 = __half22float2(*(__half2*)&v.y);
        s.x += f01.x; s.y += f01.y; s.z += f23.x; s.w += f23.y;
    }
    float4 b4 = *(const float4*)(bias + c4);
    float ox = s.x * 0.25f + b4.x;
    float oy = s.y * 0.25f + b4.y;
    float oz = s.z * 0.25f + b4.z;
    float ow = s.w * 0.25f + b4.w;
    if (LAYER1) {
        ox = ox > 0.f ? ox : expm1f(ox);
        oy = oy > 0.f ? oy : expm1f(oy);
        oz = oz > 0.f ? oz : expm1f(oz);
        ow = ow > 0.f ? ow : expm1f(ow);
        __half2 lo = __floats2half2_rn(ox, oy);
        __half2 hi = __floats2half2_rn(oz, ow);
        uint2 pk = make_uint2(*(unsigned*)&lo, *(unsigned*)&hi);
        *(uint2*)((__half*)outv + ((size_t)b * N_NODES + n) * 64 + c4) = pk;
    } else {
        *(float4*)((float*)outv + ((size_t)b * N_NODES + n) * 64 + c4) = make_float4(ox, oy, oz, ow);
    }
}

// ---------------- Launch ----------------

extern "C" void kernel_launch(void* const* d_in, const int* in_sizes, int n_in,
                              void* d_out, int out_size, void* d_ws, size_t ws_size,
                              hipStream_t stream) {
    const float* x = (const float*)d_in[0];
    const int* ei = (const int*)d_in[1];
    const float* W1 = (const float*)d_in[2];
    const float* as1 = (const float*)d_in[3];
    const float* ad1 = (const float*)d_in[4];
    const float* b1 = (const float*)d_in[5];
    const float* W2 = (const float*)d_in[6];
    const float* as2 = (const float*)d_in[7];
    const float* ad2 = (const float*)d_in[8];
    const float* b2 = (const float*)d_in[9];
    float* out = (float*)d_out;

    // workspace layout (all segments 16B-aligned by construction)
    char* p = (char*)d_ws;
    int* deg = (int*)p;            p += sizeof(int) * N_NODES;
    int* offs = (int*)p;           p += sizeof(int) * (N_NODES + 4);
    int* cursor = (int*)p;         p += sizeof(int) * N_NODES;
    int* csr_b = (int*)p;          p += sizeof(int) * E_PAD;
    int* csr_dst = (int*)p;        p += sizeof(int) * E_PAD;
    __half* Wt1 = (__half*)p;      p += sizeof(__half) * 272 * F_IN_C;
    __half* Wt2 = (__half*)p;      p += sizeof(__half) * 272 * HID_C;
    float* alsrc = (float*)p;      p += sizeof(float) * B_BATCH * N_NODES * 4;
    float* aldst = (float*)p;      p += sizeof(float) * B_BATCH * N_NODES * 4;
    __half* h2 = (__half*)p;       p += sizeof(__half) * (size_t)B_BATCH * N_NODES * 256;
    __half* oh = (__half*)p;       p += sizeof(__half) * (size_t)B_BATCH * N_NODES * 256;
    __half* x2 = (__half*)p;       p += sizeof(__half) * (size_t)B_BATCH * N_NODES * 64;
    p = (char*)(((size_t)p + 15) & ~(size_t)15);
    float* alpha = (float*)p;      p += sizeof(float) * (size_t)B_BATCH * 4 * E_PAD;

    // Wt_ext builds (independent of CSR)
    k_wext<F_IN_C><<<272 * F_IN_C / 256, 256, 0, stream>>>(W1, as1, ad1, Wt1);
    k_wext<HID_C><<<272 * HID_C / 256, 256, 0, stream>>>(W2, as2, ad2, Wt2);

    // CSR build (padded)
    k_deg_init<<<(N_NODES + 255) / 256, 256, 0, stream>>>(deg);
    k_deg_count<<<(E_EDGES + 255) / 256, 256, 0, stream>>>(ei, deg);
    k_scan<<<1, 1024, 0, stream>>>(deg, offs, cursor);
    k_scatter<<<(E_TOT + 255) / 256, 256, 0, stream>>>(ei, cursor, csr_b, csr_dst);
    k_pad<<<(N_NODES * 4 + 255) / 256, 256, 0, stream>>>(cursor, offs, csr_b, csr_dst);

    dim3 gGemm(N_NODES / 16, B_BATCH);
    dim3 gAlpha((E_PAD + 255) / 256, B_BATCH);
    int gAgg = 16 * 625;   // (batch, head) combos x 625 blocks (16 dsts each), XCD-swizzled
    int gRed = B_BATCH * N_NODES * 16 / 256;

    // Layer 1
    k_gemm<F_IN_C, float><<<gGemm, 256, 0, stream>>>(x, Wt1, h2, alsrc, aldst);
    k_alpha<<<gAlpha, 256, 0, stream>>>(alsrc, aldst, csr_b, csr_dst, offs, alpha);
    k_agg<<<gAgg, 256, 0, stream>>>(h2, alpha, offs, csr_b, oh);
    k_reduce<true><<<gRed, 256, 0, stream>>>(oh, b1, x2);

    // Layer 2
    k_gemm<HID_C, __half><<<gGemm, 256, 0, stream>>>(x2, Wt2, h2, alsrc, aldst);
    k_alpha<<<gAlpha, 256, 0, stream>>>(alsrc, aldst, csr_b, csr_dst, offs, alpha);
    k_agg<<<gAgg, 256, 0, stream>>>(h2, alpha, offs, csr_b, oh);
    k_reduce<false><<<gRed, 256, 0, stream>>>(oh, b2, out);
}

// Round 16
// 207.604 us; speedup vs baseline: 1.3021x; 1.0625x over previous
//
#include <hip/hip_runtime.h>
#include <hip/hip_fp16.h>
#include <math.h>

#define N_NODES 10000
#define B_BATCH 4
#define F_IN_C 128
#define HID_C 64
#define HEADS_C 4
#define E_EDGES 160000
#define E_TOT (E_EDGES + N_NODES)
#define E_PAD 200000   // E_TOT + 3*N_NODES upper bound, static stride for alpha
#define NEG_SLOPE 0.2f

typedef _Float16 half8 __attribute__((ext_vector_type(8)));
typedef float f32x4 __attribute__((ext_vector_type(4)));

// ---------------- Setup: Wt_ext builds (both layers) + deg_init fused ----------------
// Wt_ext: fp16 col-major [272][K]; cols 0..255 = W^T; 256+hd = W@a_src[hd]; 260+hd = W@a_dst;
// 264..271 = 0. Block ranges: [0,136) wext1(K=128), [136,204) wext2(K=64), [204,244) deg_init.

__device__ void wext_body(const float* __restrict__ W, const float* __restrict__ asrc,
                          const float* __restrict__ adst, __half* __restrict__ Wt,
                          int tid, int K) {
    int nc = tid / K, k = tid % K;
    float v;
    if (nc < 256) {
        v = W[k * 256 + nc];
    } else if (nc < 260) {
        int hd = nc - 256; v = 0.f;
        for (int c = 0; c < 64; c++) v += W[k * 256 + hd * 64 + c] * asrc[hd * 64 + c];
    } else if (nc < 264) {
        int hd = nc - 260; v = 0.f;
        for (int c = 0; c < 64; c++) v += W[k * 256 + hd * 64 + c] * adst[hd * 64 + c];
    } else {
        v = 0.f;
    }
    Wt[(size_t)nc * K + k] = __float2half(v);
}

__global__ void k_setup(const float* __restrict__ W1, const float* __restrict__ as1,
                        const float* __restrict__ ad1, const float* __restrict__ W2,
                        const float* __restrict__ as2, const float* __restrict__ ad2,
                        __half* __restrict__ Wt1, __half* __restrict__ Wt2,
                        int* __restrict__ deg) {
    int blk = blockIdx.x;
    if (blk < 136) {
        wext_body(W1, as1, ad1, Wt1, blk * 256 + threadIdx.x, F_IN_C);
    } else if (blk < 204) {
        wext_body(W2, as2, ad2, Wt2, (blk - 136) * 256 + threadIdx.x, HID_C);
    } else {
        int i = (blk - 204) * 256 + threadIdx.x;
        if (i < N_NODES) deg[i] = 1;  // self loop
    }
}

// ---------------- CSR construction (padded to quad granularity) ----------------

__global__ void k_deg_count(const int* __restrict__ ei, int* __restrict__ deg) {
    int e = blockIdx.x * 256 + threadIdx.x;
    if (e < E_EDGES) atomicAdd(&deg[ei[E_EDGES + e]], 1);
}

// 1024 threads, 10 serial elems/thread, single LDS scan. Offsets use PADDED degrees
// ((deg+3)&~3) so every dst segment is 16B-aligned with quad-multiple length.
__global__ void k_scan(const int* __restrict__ deg, int* __restrict__ offs, int* __restrict__ cursor) {
    __shared__ int lds[1024];
    int t = threadIdx.x;
    int local[10];
    int tot = 0;
#pragma unroll
    for (int j = 0; j < 10; j++) {
        int i = t * 10 + j;
        int v = (i < N_NODES) ? ((deg[i] + 3) & ~3) : 0;
        tot += v;
        local[j] = tot;  // inclusive within chunk
    }
    lds[t] = tot;
    __syncthreads();
    for (int ofs = 1; ofs < 1024; ofs <<= 1) {
        int v = (t >= ofs) ? lds[t - ofs] : 0;
        __syncthreads();
        lds[t] += v;
        __syncthreads();
    }
    int base = lds[t] - tot;  // exclusive prefix of this chunk
#pragma unroll
    for (int j = 0; j < 10; j++) {
        int i = t * 10 + j;
        if (i < N_NODES) {
            offs[i + 1] = base + local[j];
            cursor[i] = (j == 0) ? base : base + local[j - 1];
        }
    }
    if (t == 0) offs[0] = 0;
}

// csr_b holds BYTE offsets (src*128, fp16 rows) for the h-row gather; csr_dst the destination.
__global__ void k_scatter(const int* __restrict__ ei, int* __restrict__ cursor,
                          int* __restrict__ csr_b, int* __restrict__ csr_dst) {
    int e = blockIdx.x * 256 + threadIdx.x;
    if (e < E_TOT) {
        int s, d;
        if (e < E_EDGES) { s = ei[e]; d = ei[E_EDGES + e]; }
        else { s = d = e - E_EDGES; }
        int pos = atomicAdd(&cursor[d], 1);
        csr_b[pos] = s << 7;     // src * 128 bytes (64 halves)
        csr_dst[pos] = d;
    }
}

// Fill pad slots (cursor[d] is the real end after scatter): csr_b=0, csr_dst=-1.
__global__ void k_pad(const int* __restrict__ cursor, const int* __restrict__ offs,
                      int* __restrict__ csr_b, int* __restrict__ csr_dst) {
    int tid = blockIdx.x * 256 + threadIdx.x;
    if (tid >= N_NODES * 4) return;
    int d = tid >> 2, ps = tid & 3;
    int pos = cursor[d] + ps;
    if (pos < offs[d + 1]) { csr_b[pos] = 0; csr_dst[pos] = -1; }
}

// ---------------- MFMA GEMM: h = x@W (fp16 in, f32 accum, fp16 head-major out) ----------------
// mfma_f32_16x16x32_f16. Block = 16 nodes (M-tile), 4 waves; wave w owns head w (4 N-tiles);
// wave 0 additionally the al tile (cols 256..271 -> alsrc/aldst). No LDS, no barriers.
// A: row=lane&15, k=(lane>>4)*8+j. B: col=lane&15. C/D: col=lane&15, row=(lane>>4)*4+reg.
// XT = float (layer 1, cvt to fp16) or __half (layer 2, direct half8 load).

template <int K, typename XT>
__launch_bounds__(256)
__global__ void k_gemm(const XT* __restrict__ x, const __half* __restrict__ Wt,
                       __half* __restrict__ h2, float* __restrict__ alsrc, float* __restrict__ aldst) {
    int t = threadIdx.x;
    int w = t >> 6, lane = t & 63;
    int b = blockIdx.y;
    int node0 = blockIdx.x * 16;           // 625*16 == 10000 exactly
    int col = lane & 15, kblk = lane >> 4;

    const XT* xr = x + ((size_t)b * N_NODES + node0 + col) * K + kblk * 8;

    f32x4 acc0 = {0.f, 0.f, 0.f, 0.f};
    f32x4 acc1 = {0.f, 0.f, 0.f, 0.f};
    f32x4 acc2 = {0.f, 0.f, 0.f, 0.f};
    f32x4 acc3 = {0.f, 0.f, 0.f, 0.f};
    f32x4 accal = {0.f, 0.f, 0.f, 0.f};

#pragma unroll
    for (int k0 = 0; k0 < K; k0 += 32) {
        half8 a;
        if constexpr (sizeof(XT) == 4) {
            float4 xa = *(const float4*)(xr + k0);
            float4 xc = *(const float4*)(xr + k0 + 4);
            a[0] = (_Float16)xa.x; a[1] = (_Float16)xa.y; a[2] = (_Float16)xa.z; a[3] = (_Float16)xa.w;
            a[4] = (_Float16)xc.x; a[5] = (_Float16)xc.y; a[6] = (_Float16)xc.z; a[7] = (_Float16)xc.w;
        } else {
            a = *(const half8*)(xr + k0);
        }
        const __half* wtk = Wt + kblk * 8 + k0;
        half8 b0 = *(const half8*)(wtk + (size_t)((w * 4 + 0) * 16 + col) * K);
        half8 b1 = *(const half8*)(wtk + (size_t)((w * 4 + 1) * 16 + col) * K);
        half8 b2 = *(const half8*)(wtk + (size_t)((w * 4 + 2) * 16 + col) * K);
        half8 b3 = *(const half8*)(wtk + (size_t)((w * 4 + 3) * 16 + col) * K);
        acc0 = __builtin_amdgcn_mfma_f32_16x16x32_f16(a, b0, acc0, 0, 0, 0);
        acc1 = __builtin_amdgcn_mfma_f32_16x16x32_f16(a, b1, acc1, 0, 0, 0);
        acc2 = __builtin_amdgcn_mfma_f32_16x16x32_f16(a, b2, acc2, 0, 0, 0);
        acc3 = __builtin_amdgcn_mfma_f32_16x16x32_f16(a, b3, acc3, 0, 0, 0);
        if (w == 0) {
            half8 bal = *(const half8*)(wtk + (size_t)(256 + col) * K);
            accal = __builtin_amdgcn_mfma_f32_16x16x32_f16(a, bal, accal, 0, 0, 0);
        }
    }

    {
        __half* dst = h2 + ((size_t)(b * 4 + w) * N_NODES + node0 + kblk * 4) * 64 + col;
#pragma unroll
        for (int r = 0; r < 4; r++) dst[(size_t)r * 64 + 0 * 16] = __float2half(acc0[r]);
#pragma unroll
        for (int r = 0; r < 4; r++) dst[(size_t)r * 64 + 1 * 16] = __float2half(acc1[r]);
#pragma unroll
        for (int r = 0; r < 4; r++) dst[(size_t)r * 64 + 2 * 16] = __float2half(acc2[r]);
#pragma unroll
        for (int r = 0; r < 4; r++) dst[(size_t)r * 64 + 3 * 16] = __float2half(acc3[r]);
    }
    if (w == 0 && col < 8) {
        int node = node0 + kblk * 4;
        size_t nb = (size_t)b * N_NODES;
        if (col < 4) {
            float* d = alsrc + (nb + node) * 4 + col;
#pragma unroll
            for (int r = 0; r < 4; r++) d[r * 4] = accal[r];
        } else {
            float* d = aldst + (nb + node) * 4 + (col - 4);
#pragma unroll
            for (int r = 0; r < 4; r++) d[r * 4] = accal[r];
        }
    }
}

// ---------------- Edge-parallel unnormalized attention: e = exp(leaky(al_src+al_dst)) ----------
// Softmax shift-invariance: logits O(1), no max-subtraction (validated absmax 2.4e-4).
// Pad slots (csr_dst<0) write 0 -> contribute nothing downstream. [b][hd][E_PAD] layout.

__launch_bounds__(256)
__global__ void k_alpha(const float* __restrict__ alsrc, const float* __restrict__ aldst,
                        const int* __restrict__ csr_b, const int* __restrict__ csr_dst,
                        const int* __restrict__ offs, float* __restrict__ alpha) {
    int j = blockIdx.x * 256 + threadIdx.x;
    int e_act = offs[N_NODES];
    if (j >= e_act) return;
    int b = blockIdx.y;
    size_t base = (size_t)b * 4 * E_PAD + j;
    int dst = csr_dst[j];
    if (dst < 0) {
        alpha[base] = 0.f;
        alpha[base + E_PAD] = 0.f;
        alpha[base + (size_t)2 * E_PAD] = 0.f;
        alpha[base + (size_t)3 * E_PAD] = 0.f;
        return;
    }
    int src4 = csr_b[j] >> 5;  // (src*128) -> src*4
    const float* als = alsrc + (size_t)b * N_NODES * 4;
    float4 s4 = *(const float4*)(als + src4);
    float4 d4 = *(const float4*)(aldst + ((size_t)b * N_NODES + dst) * 4);
    float a;
    a = s4.x + d4.x; a = a > 0.f ? a : NEG_SLOPE * a; float e0 = __expf(a);
    a = s4.y + d4.y; a = a > 0.f ? a : NEG_SLOPE * a; float e1 = __expf(a);
    a = s4.z + d4.z; a = a > 0.f ? a : NEG_SLOPE * a; float e2 = __expf(a);
    a = s4.w + d4.w; a = a > 0.f ? a : NEG_SLOPE * a; float e3 = __expf(a);
    alpha[base] = e0;
    alpha[base + E_PAD] = e1;
    alpha[base + (size_t)2 * E_PAD] = e2;
    alpha[base + (size_t)3 * E_PAD] = e3;
}

// ---------------- 4-head fused gather-aggregate + head-mean epilogue ----------------
// One WAVE per dst covering ALL 4 heads: lane = (hd = l>>4, cl = l&15). Per quad: wave-uniform
// int4 idx (scalar), per-head alpha float4 (4 broadcast lines), 4 gathers whose per-lane
// address adds the head-slice offset. Edge walks: 16 -> 4 per layer; loop = OWN quad count
// (no max-of-4 divergence); idx/bounds scalarize. Epilogue: 1/sacc, 2x shfl_xor head fold,
// bias + (ELU|identity), direct x2/out store -- oh buffer and k_reduce eliminated.
// Grid 4x2500 blocks (4 dsts/block); batch pinned to 2 XCDs (slice 5.1 MB, ~78% L2).

#define QUAD_FMA16(p4, g0, g1, g2, g3)                                                    \
    {                                                                                     \
        float2 f01, f23;                                                                  \
        f01 = __half22float2(*(__half2*)&g0.x); f23 = __half22float2(*(__half2*)&g0.y);   \
        acc.x += p4.x * f01.x; acc.y += p4.x * f01.y; acc.z += p4.x * f23.x; acc.w += p4.x * f23.y; \
        f01 = __half22float2(*(__half2*)&g1.x); f23 = __half22float2(*(__half2*)&g1.y);   \
        acc.x += p4.y * f01.x; acc.y += p4.y * f01.y; acc.z += p4.y * f23.x; acc.w += p4.y * f23.y; \
        f01 = __half22float2(*(__half2*)&g2.x); f23 = __half22float2(*(__half2*)&g2.y);   \
        acc.x += p4.z * f01.x; acc.y += p4.z * f01.y; acc.z += p4.z * f23.x; acc.w += p4.z * f23.y; \
        f01 = __half22float2(*(__half2*)&g3.x); f23 = __half22float2(*(__half2*)&g3.y);   \
        acc.x += p4.w * f01.x; acc.y += p4.w * f01.y; acc.z += p4.w * f23.x; acc.w += p4.w * f23.y; \
        sacc += p4.x + p4.y + p4.z + p4.w;                                                \
    }

template <bool LAYER1>
__launch_bounds__(256)
__global__ void k_agg(const __half* __restrict__ h2, const float* __restrict__ alpha,
                      const int* __restrict__ offs, const int* __restrict__ csr_b,
                      const float* __restrict__ bias, void* __restrict__ outv) {
    int t = threadIdx.x;
    int bid = blockIdx.x;
    int xcd = bid & 7;
    int b = xcd >> 1;                       // batch -> 2 XCDs (slice 5.1 MB over 2 L2s)
    int local = (bid >> 3) * 2 + (xcd & 1); // 0..2499
    int wv = t >> 6, lane = t & 63;
    int hd = lane >> 4, cl = lane & 15;
    int dst = local * 4 + wv;

    const char* hcb = (const char*)(h2 + (size_t)(b * 4 + hd) * N_NODES * 64);
    const float* ec = alpha + (size_t)(b * 4 + hd) * E_PAD;
    int s0 = offs[dst], s1 = offs[dst + 1];
    int cl8 = cl * 8;

    float4 acc = make_float4(0.f, 0.f, 0.f, 0.f);
    float sacc = 0.f;
    // depth-2 pipeline (r15 structure); padded deg >= 4 guaranteed
    int4 c_cur = *(const int4*)(csr_b + s0);
    float4 p_cur = *(const float4*)(ec + s0);
    uint2 g0 = *(const uint2*)(hcb + (unsigned)(c_cur.x + cl8));
    uint2 g1 = *(const uint2*)(hcb + (unsigned)(c_cur.y + cl8));
    uint2 g2 = *(const uint2*)(hcb + (unsigned)(c_cur.z + cl8));
    uint2 g3 = *(const uint2*)(hcb + (unsigned)(c_cur.w + cl8));
    int jn = (s0 + 4 < s1) ? s0 + 4 : s0;
    int4 c_nxt = *(const int4*)(csr_b + jn);
    float4 p_nxt = *(const float4*)(ec + jn);

    for (int j = s0 + 4; j < s1; j += 4) {
        uint2 m0 = *(const uint2*)(hcb + (unsigned)(c_nxt.x + cl8));
        uint2 m1 = *(const uint2*)(hcb + (unsigned)(c_nxt.y + cl8));
        uint2 m2 = *(const uint2*)(hcb + (unsigned)(c_nxt.z + cl8));
        uint2 m3 = *(const uint2*)(hcb + (unsigned)(c_nxt.w + cl8));
        int j2 = (j + 4 < s1) ? j + 4 : j;
        int4 c_tmp = *(const int4*)(csr_b + j2);
        float4 p_tmp = *(const float4*)(ec + j2);
        QUAD_FMA16(p_cur, g0, g1, g2, g3)
        g0 = m0; g1 = m1; g2 = m2; g3 = m3;
        p_cur = p_nxt;
        c_nxt = c_tmp; p_nxt = p_tmp;
    }
    QUAD_FMA16(p_cur, g0, g1, g2, g3)

    // per-head normalize, then fold heads (lanes cl, cl+16, cl+32, cl+48 share channel)
    float inv = 1.f / (sacc + 1e-16f);
    float4 v = make_float4(acc.x * inv, acc.y * inv, acc.z * inv, acc.w * inv);
#pragma unroll
    for (int o = 16; o < 64; o <<= 1) {
        v.x += __shfl_xor(v.x, o);
        v.y += __shfl_xor(v.y, o);
        v.z += __shfl_xor(v.z, o);
        v.w += __shfl_xor(v.w, o);
    }
    if (lane < 16) {
        float4 b4 = *(const float4*)(bias + cl * 4);
        float ox = v.x * 0.25f + b4.x;
        float oy = v.y * 0.25f + b4.y;
        float oz = v.z * 0.25f + b4.z;
        float ow = v.w * 0.25f + b4.w;
        if (LAYER1) {
            ox = ox > 0.f ? ox : expm1f(ox);
            oy = oy > 0.f ? oy : expm1f(oy);
            oz = oz > 0.f ? oz : expm1f(oz);
            ow = ow > 0.f ? ow : expm1f(ow);
            __half2 lo = __floats2half2_rn(ox, oy);
            __half2 hi = __floats2half2_rn(oz, ow);
            uint2 pk = make_uint2(*(unsigned*)&lo, *(unsigned*)&hi);
            *(uint2*)((__half*)outv + ((size_t)b * N_NODES + dst) * 64 + cl * 4) = pk;
        } else {
            *(float4*)((float*)outv + ((size_t)b * N_NODES + dst) * 64 + cl * 4) =
                make_float4(ox, oy, oz, ow);
        }
    }
}

// ---------------- Launch ----------------

extern "C" void kernel_launch(void* const* d_in, const int* in_sizes, int n_in,
                              void* d_out, int out_size, void* d_ws, size_t ws_size,
                              hipStream_t stream) {
    const float* x = (const float*)d_in[0];
    const int* ei = (const int*)d_in[1];
    const float* W1 = (const float*)d_in[2];
    const float* as1 = (const float*)d_in[3];
    const float* ad1 = (const float*)d_in[4];
    const float* b1 = (const float*)d_in[5];
    const float* W2 = (const float*)d_in[6];
    const float* as2 = (const float*)d_in[7];
    const float* ad2 = (const float*)d_in[8];
    const float* b2 = (const float*)d_in[9];
    float* out = (float*)d_out;

    // workspace layout (all segments 16B-aligned by construction)
    char* p = (char*)d_ws;
    int* deg = (int*)p;            p += sizeof(int) * N_NODES;
    int* offs = (int*)p;           p += sizeof(int) * (N_NODES + 4);
    int* cursor = (int*)p;         p += sizeof(int) * N_NODES;
    int* csr_b = (int*)p;          p += sizeof(int) * E_PAD;
    int* csr_dst = (int*)p;        p += sizeof(int) * E_PAD;
    __half* Wt1 = (__half*)p;      p += sizeof(__half) * 272 * F_IN_C;
    __half* Wt2 = (__half*)p;      p += sizeof(__half) * 272 * HID_C;
    float* alsrc = (float*)p;      p += sizeof(float) * B_BATCH * N_NODES * 4;
    float* aldst = (float*)p;      p += sizeof(float) * B_BATCH * N_NODES * 4;
    __half* h2 = (__half*)p;       p += sizeof(__half) * (size_t)B_BATCH * N_NODES * 256;
    __half* x2 = (__half*)p;       p += sizeof(__half) * (size_t)B_BATCH * N_NODES * 64;
    p = (char*)(((size_t)p + 15) & ~(size_t)15);
    float* alpha = (float*)p;      p += sizeof(float) * (size_t)B_BATCH * 4 * E_PAD;

    // setup: wext1 + wext2 + deg_init (independent, fused into one dispatch)
    k_setup<<<244, 256, 0, stream>>>(W1, as1, ad1, W2, as2, ad2, Wt1, Wt2, deg);

    // CSR build (padded)
    k_deg_count<<<(E_EDGES + 255) / 256, 256, 0, stream>>>(ei, deg);
    k_scan<<<1, 1024, 0, stream>>>(deg, offs, cursor);
    k_scatter<<<(E_TOT + 255) / 256, 256, 0, stream>>>(ei, cursor, csr_b, csr_dst);
    k_pad<<<(N_NODES * 4 + 255) / 256, 256, 0, stream>>>(cursor, offs, csr_b, csr_dst);

    dim3 gGemm(N_NODES / 16, B_BATCH);
    dim3 gAlpha((E_PAD + 255) / 256, B_BATCH);
    int gAgg = B_BATCH * 2500;   // 4 dsts/block; batch = (bid&7)>>1 -> 2 XCDs per batch

    // Layer 1
    k_gemm<F_IN_C, float><<<gGemm, 256, 0, stream>>>(x, Wt1, h2, alsrc, aldst);
    k_alpha<<<gAlpha, 256, 0, stream>>>(alsrc, aldst, csr_b, csr_dst, offs, alpha);
    k_agg<true><<<gAgg, 256, 0, stream>>>(h2, alpha, offs, csr_b, b1, x2);

    // Layer 2
    k_gemm<HID_C, __half><<<gGemm, 256, 0, stream>>>(x2, Wt2, h2, alsrc, aldst);
    k_alpha<<<gAlpha, 256, 0, stream>>>(alsrc, aldst, csr_b, csr_dst, offs, alpha);
    k_agg<false><<<gAgg, 256, 0, stream>>>(h2, alpha, offs, csr_b, b2, out);
}

// Round 17
// 204.800 us; speedup vs baseline: 1.3200x; 1.0137x over previous
//
#include <hip/hip_runtime.h>
#include <hip/hip_fp16.h>
#include <math.h>

#define N_NODES 10000
#define B_BATCH 4
#define F_IN_C 128
#define HID_C 64
#define HEADS_C 4
#define E_EDGES 160000
#define E_TOT (E_EDGES + N_NODES)
#define E_OCT 240000   // E_TOT + 7*N_NODES upper bound (oct-padded), static stride for alpha
#define NEG_SLOPE 0.2f

typedef _Float16 half8 __attribute__((ext_vector_type(8)));
typedef float f32x4 __attribute__((ext_vector_type(4)));

// ---------------- Setup: Wt_ext builds (both layers) + deg_init fused ----------------

__device__ void wext_body(const float* __restrict__ W, const float* __restrict__ asrc,
                          const float* __restrict__ adst, __half* __restrict__ Wt,
                          int tid, int K) {
    int nc = tid / K, k = tid % K;
    float v;
    if (nc < 256) {
        v = W[k * 256 + nc];
    } else if (nc < 260) {
        int hd = nc - 256; v = 0.f;
        for (int c = 0; c < 64; c++) v += W[k * 256 + hd * 64 + c] * asrc[hd * 64 + c];
    } else if (nc < 264) {
        int hd = nc - 260; v = 0.f;
        for (int c = 0; c < 64; c++) v += W[k * 256 + hd * 64 + c] * adst[hd * 64 + c];
    } else {
        v = 0.f;
    }
    Wt[(size_t)nc * K + k] = __float2half(v);
}

__global__ void k_setup(const float* __restrict__ W1, const float* __restrict__ as1,
                        const float* __restrict__ ad1, const float* __restrict__ W2,
                        const float* __restrict__ as2, const float* __restrict__ ad2,
                        __half* __restrict__ Wt1, __half* __restrict__ Wt2,
                        int* __restrict__ deg) {
    int blk = blockIdx.x;
    if (blk < 136) {
        wext_body(W1, as1, ad1, Wt1, blk * 256 + threadIdx.x, F_IN_C);
    } else if (blk < 204) {
        wext_body(W2, as2, ad2, Wt2, (blk - 136) * 256 + threadIdx.x, HID_C);
    } else {
        int i = (blk - 204) * 256 + threadIdx.x;
        if (i < N_NODES) deg[i] = 1;  // self loop
    }
}

// ---------------- CSR construction (padded to OCT granularity) ----------------

__global__ void k_deg_count(const int* __restrict__ ei, int* __restrict__ deg) {
    int e = blockIdx.x * 256 + threadIdx.x;
    if (e < E_EDGES) atomicAdd(&deg[ei[E_EDGES + e]], 1);
}

// Offsets use PADDED degrees ((deg+7)&~7): every segment is a multiple of 8, len >= 8.
__global__ void k_scan(const int* __restrict__ deg, int* __restrict__ offs, int* __restrict__ cursor) {
    __shared__ int lds[1024];
    int t = threadIdx.x;
    int local[10];
    int tot = 0;
#pragma unroll
    for (int j = 0; j < 10; j++) {
        int i = t * 10 + j;
        int v = (i < N_NODES) ? ((deg[i] + 7) & ~7) : 0;
        tot += v;
        local[j] = tot;  // inclusive within chunk
    }
    lds[t] = tot;
    __syncthreads();
    for (int ofs = 1; ofs < 1024; ofs <<= 1) {
        int v = (t >= ofs) ? lds[t - ofs] : 0;
        __syncthreads();
        lds[t] += v;
        __syncthreads();
    }
    int base = lds[t] - tot;  // exclusive prefix of this chunk
#pragma unroll
    for (int j = 0; j < 10; j++) {
        int i = t * 10 + j;
        if (i < N_NODES) {
            offs[i + 1] = base + local[j];
            cursor[i] = (j == 0) ? base : base + local[j - 1];
        }
    }
    if (t == 0) offs[0] = 0;
}

// csr_b holds BYTE offsets (src*512: node-major fp16 rows of 256) for the h gather.
__global__ void k_scatter(const int* __restrict__ ei, int* __restrict__ cursor,
                          int* __restrict__ csr_b, int* __restrict__ csr_dst) {
    int e = blockIdx.x * 256 + threadIdx.x;
    if (e < E_TOT) {
        int s, d;
        if (e < E_EDGES) { s = ei[e]; d = ei[E_EDGES + e]; }
        else { s = d = e - E_EDGES; }
        int pos = atomicAdd(&cursor[d], 1);
        csr_b[pos] = s << 9;     // src * 512 bytes (256 halves, all 4 heads)
        csr_dst[pos] = d;
    }
}

// Fill pad slots (up to 7 per dst): csr_b=0, csr_dst=-1.
__global__ void k_pad(const int* __restrict__ cursor, const int* __restrict__ offs,
                      int* __restrict__ csr_b, int* __restrict__ csr_dst) {
    int tid = blockIdx.x * 256 + threadIdx.x;
    if (tid >= N_NODES * 8) return;
    int d = tid >> 3, ps = tid & 7;
    int pos = cursor[d] + ps;
    if (pos < offs[d + 1]) { csr_b[pos] = 0; csr_dst[pos] = -1; }
}

// ---------------- MFMA GEMM: h = x@W (fp16 in, f32 accum, fp16 NODE-major out) ----------------
// mfma_f32_16x16x32_f16. Block = 16 nodes, 4 waves; wave w owns head w; wave 0 also al tile.
// h2 layout now [b][n][hd*64+ch] so the gather reads one contiguous 512 B row per src.

template <int K, typename XT>
__launch_bounds__(256)
__global__ void k_gemm(const XT* __restrict__ x, const __half* __restrict__ Wt,
                       __half* __restrict__ h2, float* __restrict__ alsrc, float* __restrict__ aldst) {
    int t = threadIdx.x;
    int w = t >> 6, lane = t & 63;
    int b = blockIdx.y;
    int node0 = blockIdx.x * 16;           // 625*16 == 10000 exactly
    int col = lane & 15, kblk = lane >> 4;

    const XT* xr = x + ((size_t)b * N_NODES + node0 + col) * K + kblk * 8;

    f32x4 acc0 = {0.f, 0.f, 0.f, 0.f};
    f32x4 acc1 = {0.f, 0.f, 0.f, 0.f};
    f32x4 acc2 = {0.f, 0.f, 0.f, 0.f};
    f32x4 acc3 = {0.f, 0.f, 0.f, 0.f};
    f32x4 accal = {0.f, 0.f, 0.f, 0.f};

#pragma unroll
    for (int k0 = 0; k0 < K; k0 += 32) {
        half8 a;
        if constexpr (sizeof(XT) == 4) {
            float4 xa = *(const float4*)(xr + k0);
            float4 xc = *(const float4*)(xr + k0 + 4);
            a[0] = (_Float16)xa.x; a[1] = (_Float16)xa.y; a[2] = (_Float16)xa.z; a[3] = (_Float16)xa.w;
            a[4] = (_Float16)xc.x; a[5] = (_Float16)xc.y; a[6] = (_Float16)xc.z; a[7] = (_Float16)xc.w;
        } else {
            a = *(const half8*)(xr + k0);
        }
        const __half* wtk = Wt + kblk * 8 + k0;
        half8 b0 = *(const half8*)(wtk + (size_t)((w * 4 + 0) * 16 + col) * K);
        half8 b1 = *(const half8*)(wtk + (size_t)((w * 4 + 1) * 16 + col) * K);
        half8 b2 = *(const half8*)(wtk + (size_t)((w * 4 + 2) * 16 + col) * K);
        half8 b3 = *(const half8*)(wtk + (size_t)((w * 4 + 3) * 16 + col) * K);
        acc0 = __builtin_amdgcn_mfma_f32_16x16x32_f16(a, b0, acc0, 0, 0, 0);
        acc1 = __builtin_amdgcn_mfma_f32_16x16x32_f16(a, b1, acc1, 0, 0, 0);
        acc2 = __builtin_amdgcn_mfma_f32_16x16x32_f16(a, b2, acc2, 0, 0, 0);
        acc3 = __builtin_amdgcn_mfma_f32_16x16x32_f16(a, b3, acc3, 0, 0, 0);
        if (w == 0) {
            half8 bal = *(const half8*)(wtk + (size_t)(256 + col) * K);
            accal = __builtin_amdgcn_mfma_f32_16x16x32_f16(a, bal, accal, 0, 0, 0);
        }
    }

    // node-major store: h2[(b*N + node)*256 + w*64 + nt*16 + col], node = node0+kblk*4+r
    {
        __half* dst = h2 + ((size_t)b * N_NODES + node0 + kblk * 4) * 256 + w * 64 + col;
#pragma unroll
        for (int r = 0; r < 4; r++) dst[(size_t)r * 256 + 0 * 16] = __float2half(acc0[r]);
#pragma unroll
        for (int r = 0; r < 4; r++) dst[(size_t)r * 256 + 1 * 16] = __float2half(acc1[r]);
#pragma unroll
        for (int r = 0; r < 4; r++) dst[(size_t)r * 256 + 2 * 16] = __float2half(acc2[r]);
#pragma unroll
        for (int r = 0; r < 4; r++) dst[(size_t)r * 256 + 3 * 16] = __float2half(acc3[r]);
    }
    if (w == 0 && col < 8) {
        int node = node0 + kblk * 4;
        size_t nb = (size_t)b * N_NODES;
        if (col < 4) {
            float* d = alsrc + (nb + node) * 4 + col;
#pragma unroll
            for (int r = 0; r < 4; r++) d[r * 4] = accal[r];
        } else {
            float* d = aldst + (nb + node) * 4 + (col - 4);
#pragma unroll
            for (int r = 0; r < 4; r++) d[r * 4] = accal[r];
        }
    }
}

// ---------------- Edge-parallel unnormalized attention: e = exp(leaky(al_src+al_dst)) ----------

__launch_bounds__(256)
__global__ void k_alpha(const float* __restrict__ alsrc, const float* __restrict__ aldst,
                        const int* __restrict__ csr_b, const int* __restrict__ csr_dst,
                        const int* __restrict__ offs, float* __restrict__ alpha) {
    int j = blockIdx.x * 256 + threadIdx.x;
    int e_act = offs[N_NODES];
    if (j >= e_act) return;
    int b = blockIdx.y;
    size_t base = (size_t)b * 4 * E_OCT + j;
    int dst = csr_dst[j];
    if (dst < 0) {
        alpha[base] = 0.f;
        alpha[base + E_OCT] = 0.f;
        alpha[base + (size_t)2 * E_OCT] = 0.f;
        alpha[base + (size_t)3 * E_OCT] = 0.f;
        return;
    }
    int src4 = csr_b[j] >> 7;  // (src*512) -> src*4
    const float* als = alsrc + (size_t)b * N_NODES * 4;
    float4 s4 = *(const float4*)(als + src4);
    float4 d4 = *(const float4*)(aldst + ((size_t)b * N_NODES + dst) * 4);
    float a;
    a = s4.x + d4.x; a = a > 0.f ? a : NEG_SLOPE * a; float e0 = __expf(a);
    a = s4.y + d4.y; a = a > 0.f ? a : NEG_SLOPE * a; float e1 = __expf(a);
    a = s4.z + d4.z; a = a > 0.f ? a : NEG_SLOPE * a; float e2 = __expf(a);
    a = s4.w + d4.w; a = a > 0.f ? a : NEG_SLOPE * a; float e3 = __expf(a);
    alpha[base] = e0;
    alpha[base + E_OCT] = e1;
    alpha[base + (size_t)2 * E_OCT] = e2;
    alpha[base + (size_t)3 * E_OCT] = e3;
}

// ---------------- 4-head fused gather-aggregate, oct-wide depth-2 pipeline ----------------
// One wave per dst, lane = (hd = l>>4, cl = l&15). Node-major h2: each gather instruction
// reads one contiguous 512 B src row (64 lanes x 8 B). Oct-granular segments -> uniform
// 8-src iterations; 8 gathers in flight during each 32-FMA block (L3-latency regime).

#define QUAD_FMA16(p4, g0, g1, g2, g3)                                                    \
    {                                                                                     \
        float2 f01, f23;                                                                  \
        f01 = __half22float2(*(__half2*)&g0.x); f23 = __half22float2(*(__half2*)&g0.y);   \
        acc.x += p4.x * f01.x; acc.y += p4.x * f01.y; acc.z += p4.x * f23.x; acc.w += p4.x * f23.y; \
        f01 = __half22float2(*(__half2*)&g1.x); f23 = __half22float2(*(__half2*)&g1.y);   \
        acc.x += p4.y * f01.x; acc.y += p4.y * f01.y; acc.z += p4.y * f23.x; acc.w += p4.y * f23.y; \
        f01 = __half22float2(*(__half2*)&g2.x); f23 = __half22float2(*(__half2*)&g2.y);   \
        acc.x += p4.z * f01.x; acc.y += p4.z * f01.y; acc.z += p4.z * f23.x; acc.w += p4.z * f23.y; \
        f01 = __half22float2(*(__half2*)&g3.x); f23 = __half22float2(*(__half2*)&g3.y);   \
        acc.x += p4.w * f01.x; acc.y += p4.w * f01.y; acc.z += p4.w * f23.x; acc.w += p4.w * f23.y; \
        sacc += p4.x + p4.y + p4.z + p4.w;                                                \
    }

template <bool LAYER1>
__launch_bounds__(256)
__global__ void k_agg(const __half* __restrict__ h2, const float* __restrict__ alpha,
                      const int* __restrict__ offs, const int* __restrict__ csr_b,
                      const float* __restrict__ bias, void* __restrict__ outv) {
    int t = threadIdx.x;
    int bid = blockIdx.x;
    int xcd = bid & 7;
    int b = xcd >> 1;
    int local = (bid >> 3) * 2 + (xcd & 1); // 0..2499
    int wv = t >> 6, lane = t & 63;
    int hd = lane >> 4, cl = lane & 15;
    int dst = local * 4 + wv;

    const char* hcb = (const char*)(h2 + (size_t)b * N_NODES * 256);
    const float* ec = alpha + (size_t)(b * 4 + hd) * E_OCT;
    int s0 = offs[dst], s1 = offs[dst + 1];
    int laneoff = (hd << 7) | (cl << 3);    // head slice (128 B) + chan quad (8 B)

    float4 acc = make_float4(0.f, 0.f, 0.f, 0.f);
    float sacc = 0.f;
    // prologue: oct 0 fully staged (padded len >= 8 guaranteed)
    int4 cA = *(const int4*)(csr_b + s0);
    int4 cB = *(const int4*)(csr_b + s0 + 4);
    float4 pA = *(const float4*)(ec + s0);
    float4 pB = *(const float4*)(ec + s0 + 4);
    uint2 g0 = *(const uint2*)(hcb + (unsigned)(cA.x + laneoff));
    uint2 g1 = *(const uint2*)(hcb + (unsigned)(cA.y + laneoff));
    uint2 g2 = *(const uint2*)(hcb + (unsigned)(cA.z + laneoff));
    uint2 g3 = *(const uint2*)(hcb + (unsigned)(cA.w + laneoff));
    uint2 g4 = *(const uint2*)(hcb + (unsigned)(cB.x + laneoff));
    uint2 g5 = *(const uint2*)(hcb + (unsigned)(cB.y + laneoff));
    uint2 g6 = *(const uint2*)(hcb + (unsigned)(cB.z + laneoff));
    uint2 g7 = *(const uint2*)(hcb + (unsigned)(cB.w + laneoff));
    // oct 1 indices/alphas (clamped)
    int jn = (s0 + 8 < s1) ? s0 + 8 : s0;
    int4 cA2 = *(const int4*)(csr_b + jn);
    int4 cB2 = *(const int4*)(csr_b + jn + 4);
    float4 pA2 = *(const float4*)(ec + jn);
    float4 pB2 = *(const float4*)(ec + jn + 4);

    for (int j = s0 + 8; j < s1; j += 8) {
        // gathers for oct (k+1) -- indices loaded a full iteration ago
        uint2 m0 = *(const uint2*)(hcb + (unsigned)(cA2.x + laneoff));
        uint2 m1 = *(const uint2*)(hcb + (unsigned)(cA2.y + laneoff));
        uint2 m2 = *(const uint2*)(hcb + (unsigned)(cA2.z + laneoff));
        uint2 m3 = *(const uint2*)(hcb + (unsigned)(cA2.w + laneoff));
        uint2 m4 = *(const uint2*)(hcb + (unsigned)(cB2.x + laneoff));
        uint2 m5 = *(const uint2*)(hcb + (unsigned)(cB2.y + laneoff));
        uint2 m6 = *(const uint2*)(hcb + (unsigned)(cB2.z + laneoff));
        uint2 m7 = *(const uint2*)(hcb + (unsigned)(cB2.w + laneoff));
        // indices/alphas for oct (k+2), clamped
        int j2 = (j + 8 < s1) ? j + 8 : j;
        int4 cA3 = *(const int4*)(csr_b + j2);
        int4 cB3 = *(const int4*)(csr_b + j2 + 4);
        float4 pA3 = *(const float4*)(ec + j2);
        float4 pB3 = *(const float4*)(ec + j2 + 4);
        // consume oct k
        QUAD_FMA16(pA, g0, g1, g2, g3)
        QUAD_FMA16(pB, g4, g5, g6, g7)
        g0 = m0; g1 = m1; g2 = m2; g3 = m3;
        g4 = m4; g5 = m5; g6 = m6; g7 = m7;
        pA = pA2; pB = pB2;
        cA2 = cA3; cB2 = cB3; pA2 = pA3; pB2 = pB3;
    }
    QUAD_FMA16(pA, g0, g1, g2, g3)
    QUAD_FMA16(pB, g4, g5, g6, g7)

    // per-head normalize, then fold heads (lanes cl, cl+16, cl+32, cl+48 share channel)
    float inv = 1.f / (sacc + 1e-16f);
    float4 v = make_float4(acc.x * inv, acc.y * inv, acc.z * inv, acc.w * inv);
#pragma unroll
    for (int o = 16; o < 64; o <<= 1) {
        v.x += __shfl_xor(v.x, o);
        v.y += __shfl_xor(v.y, o);
        v.z += __shfl_xor(v.z, o);
        v.w += __shfl_xor(v.w, o);
    }
    if (lane < 16) {
        float4 b4 = *(const float4*)(bias + cl * 4);
        float ox = v.x * 0.25f + b4.x;
        float oy = v.y * 0.25f + b4.y;
        float oz = v.z * 0.25f + b4.z;
        float ow = v.w * 0.25f + b4.w;
        if (LAYER1) {
            ox = ox > 0.f ? ox : expm1f(ox);
            oy = oy > 0.f ? oy : expm1f(oy);
            oz = oz > 0.f ? oz : expm1f(oz);
            ow = ow > 0.f ? ow : expm1f(ow);
            __half2 lo = __floats2half2_rn(ox, oy);
            __half2 hi = __floats2half2_rn(oz, ow);
            uint2 pk = make_uint2(*(unsigned*)&lo, *(unsigned*)&hi);
            *(uint2*)((__half*)outv + ((size_t)b * N_NODES + dst) * 64 + cl * 4) = pk;
        } else {
            *(float4*)((float*)outv + ((size_t)b * N_NODES + dst) * 64 + cl * 4) =
                make_float4(ox, oy, oz, ow);
        }
    }
}

// ---------------- Launch ----------------

extern "C" void kernel_launch(void* const* d_in, const int* in_sizes, int n_in,
                              void* d_out, int out_size, void* d_ws, size_t ws_size,
                              hipStream_t stream) {
    const float* x = (const float*)d_in[0];
    const int* ei = (const int*)d_in[1];
    const float* W1 = (const float*)d_in[2];
    const float* as1 = (const float*)d_in[3];
    const float* ad1 = (const float*)d_in[4];
    const float* b1 = (const float*)d_in[5];
    const float* W2 = (const float*)d_in[6];
    const float* as2 = (const float*)d_in[7];
    const float* ad2 = (const float*)d_in[8];
    const float* b2 = (const float*)d_in[9];
    float* out = (float*)d_out;

    // workspace layout (all segments 16B-aligned by construction)
    char* p = (char*)d_ws;
    int* deg = (int*)p;            p += sizeof(int) * N_NODES;
    int* offs = (int*)p;           p += sizeof(int) * (N_NODES + 4);
    int* cursor = (int*)p;         p += sizeof(int) * N_NODES;
    int* csr_b = (int*)p;          p += sizeof(int) * E_OCT;
    int* csr_dst = (int*)p;        p += sizeof(int) * E_OCT;
    __half* Wt1 = (__half*)p;      p += sizeof(__half) * 272 * F_IN_C;
    __half* Wt2 = (__half*)p;      p += sizeof(__half) * 272 * HID_C;
    float* alsrc = (float*)p;      p += sizeof(float) * B_BATCH * N_NODES * 4;
    float* aldst = (float*)p;      p += sizeof(float) * B_BATCH * N_NODES * 4;
    __half* h2 = (__half*)p;       p += sizeof(__half) * (size_t)B_BATCH * N_NODES * 256;
    __half* x2 = (__half*)p;       p += sizeof(__half) * (size_t)B_BATCH * N_NODES * 64;
    p = (char*)(((size_t)p + 15) & ~(size_t)15);
    float* alpha = (float*)p;      p += sizeof(float) * (size_t)B_BATCH * 4 * E_OCT;

    // setup: wext1 + wext2 + deg_init (independent, fused into one dispatch)
    k_setup<<<244, 256, 0, stream>>>(W1, as1, ad1, W2, as2, ad2, Wt1, Wt2, deg);

    // CSR build (oct-padded)
    k_deg_count<<<(E_EDGES + 255) / 256, 256, 0, stream>>>(ei, deg);
    k_scan<<<1, 1024, 0, stream>>>(deg, offs, cursor);
    k_scatter<<<(E_TOT + 255) / 256, 256, 0, stream>>>(ei, cursor, csr_b, csr_dst);
    k_pad<<<(N_NODES * 8 + 255) / 256, 256, 0, stream>>>(cursor, offs, csr_b, csr_dst);

    dim3 gGemm(N_NODES / 16, B_BATCH);
    dim3 gAlpha((E_OCT + 255) / 256, B_BATCH);
    int gAgg = B_BATCH * 2500;   // 4 dsts/block

    // Layer 1
    k_gemm<F_IN_C, float><<<gGemm, 256, 0, stream>>>(x, Wt1, h2, alsrc, aldst);
    k_alpha<<<gAlpha, 256, 0, stream>>>(alsrc, aldst, csr_b, csr_dst, offs, alpha);
    k_agg<true><<<gAgg, 256, 0, stream>>>(h2, alpha, offs, csr_b, b1, x2);

    // Layer 2
    k_gemm<HID_C, __half><<<gGemm, 256, 0, stream>>>(x2, Wt2, h2, alsrc, aldst);
    k_alpha<<<gAlpha, 256, 0, stream>>>(alsrc, aldst, csr_b, csr_dst, offs, alpha);
    k_agg<false><<<gAgg, 256, 0, stream>>>(h2, alpha, offs, csr_b, b2, out);
}

// Round 18
// 199.670 us; speedup vs baseline: 1.3539x; 1.0257x over previous
//
#include <hip/hip_runtime.h>
#include <hip/hip_fp16.h>
#include <math.h>

#define N_NODES 10000
#define B_BATCH 4
#define F_IN_C 128
#define HID_C 64
#define E_EDGES 160000
#define E_TOT (E_EDGES + N_NODES)
#define E_OCT 240000   // E_TOT + 7*N_NODES upper bound (oct-padded)
#define NEG_SLOPE 0.2f
#define SN (N_NODES + 8)   // alsrc/aldst node stride per batch (row N = dummy, -1e30)
#define SH (N_NODES + 8)   // h2 rows per batch (row N = dummy, zeros)

typedef _Float16 half8 __attribute__((ext_vector_type(8)));
typedef float f32x4 __attribute__((ext_vector_type(4)));

// ---------------- Wt_ext: fp16 col-major [272][K]; 256+hd=W@a_src, 260+hd=W@a_dst ----------------

__device__ void wext_body(const float* __restrict__ W, const float* __restrict__ asrc,
                          const float* __restrict__ adst, __half* __restrict__ Wt,
                          int tid, int K) {
    int nc = tid / K, k = tid % K;
    float v;
    if (nc < 256) {
        v = W[k * 256 + nc];
    } else if (nc < 260) {
        int hd = nc - 256; v = 0.f;
        for (int c = 0; c < 64; c++) v += W[k * 256 + hd * 64 + c] * asrc[hd * 64 + c];
    } else if (nc < 264) {
        int hd = nc - 260; v = 0.f;
        for (int c = 0; c < 64; c++) v += W[k * 256 + hd * 64 + c] * adst[hd * 64 + c];
    } else {
        v = 0.f;
    }
    Wt[(size_t)nc * K + k] = __float2half(v);
}

// ---------------- Mega-setup: wext1 | wext2 | csr sentinel-fill | dummy rows | deg_count --------
// deg pre-zeroed by hipMemsetAsync. Pads never touched by scatter keep the dummy sentinel
// (csr_b = N<<9), whose alsrc row is -1e30 -> e = exp(-inf) = 0 -> zero contribution.

__global__ void k_setup(const float* __restrict__ W1, const float* __restrict__ as1,
                        const float* __restrict__ ad1, const float* __restrict__ W2,
                        const float* __restrict__ as2, const float* __restrict__ ad2,
                        __half* __restrict__ Wt1, __half* __restrict__ Wt2,
                        int* __restrict__ csr_b, __half* __restrict__ h2,
                        float* __restrict__ alsrc, int* __restrict__ deg,
                        const int* __restrict__ ei) {
    int blk = blockIdx.x, t = threadIdx.x;
    if (blk < 136) {
        wext_body(W1, as1, ad1, Wt1, blk * 256 + t, F_IN_C);
    } else if (blk < 204) {
        wext_body(W2, as2, ad2, Wt2, (blk - 136) * 256 + t, HID_C);
    } else if (blk < 1142) {
        int i = (blk - 204) * 256 + t;
        if (i < E_OCT) csr_b[i] = N_NODES << 9;   // dummy sentinel
    } else if (blk == 1142) {
        for (int i = t; i < 4 * 256; i += 256) {   // dummy h2 rows = 0
            int b = i >> 8, c = i & 255;
            h2[((size_t)b * SH + N_NODES) * 256 + c] = __float2half(0.f);
        }
        if (t < 16) {                              // dummy alsrc = -1e30
            int b = t >> 2, q = t & 3;
            alsrc[((size_t)b * SN + N_NODES) * 4 + q] = -1e30f;
        }
    } else {
        int e = (blk - 1143) * 256 + t;
        if (e < E_EDGES) atomicAdd(&deg[ei[E_EDGES + e]], 1);
    }
}

// ---------------- MFMA GEMM body: h = x@W (fp16 in, f32 accum, node-major fp16 out) ------------

template <int K, typename XT>
__device__ void gemm_body(const XT* __restrict__ x, const __half* __restrict__ Wt,
                          __half* __restrict__ h2, float* __restrict__ alsrc,
                          float* __restrict__ aldst, int b, int tile) {
    int t = threadIdx.x;
    int w = t >> 6, lane = t & 63;
    int node0 = tile * 16;
    int col = lane & 15, kblk = lane >> 4;

    const XT* xr = x + ((size_t)b * N_NODES + node0 + col) * K + kblk * 8;

    f32x4 acc0 = {0.f, 0.f, 0.f, 0.f};
    f32x4 acc1 = {0.f, 0.f, 0.f, 0.f};
    f32x4 acc2 = {0.f, 0.f, 0.f, 0.f};
    f32x4 acc3 = {0.f, 0.f, 0.f, 0.f};
    f32x4 accal = {0.f, 0.f, 0.f, 0.f};

#pragma unroll
    for (int k0 = 0; k0 < K; k0 += 32) {
        half8 a;
        if constexpr (sizeof(XT) == 4) {
            float4 xa = *(const float4*)(xr + k0);
            float4 xc = *(const float4*)(xr + k0 + 4);
            a[0] = (_Float16)xa.x; a[1] = (_Float16)xa.y; a[2] = (_Float16)xa.z; a[3] = (_Float16)xa.w;
            a[4] = (_Float16)xc.x; a[5] = (_Float16)xc.y; a[6] = (_Float16)xc.z; a[7] = (_Float16)xc.w;
        } else {
            a = *(const half8*)(xr + k0);
        }
        const __half* wtk = Wt + kblk * 8 + k0;
        half8 b0 = *(const half8*)(wtk + (size_t)((w * 4 + 0) * 16 + col) * K);
        half8 b1 = *(const half8*)(wtk + (size_t)((w * 4 + 1) * 16 + col) * K);
        half8 b2 = *(const half8*)(wtk + (size_t)((w * 4 + 2) * 16 + col) * K);
        half8 b3 = *(const half8*)(wtk + (size_t)((w * 4 + 3) * 16 + col) * K);
        acc0 = __builtin_amdgcn_mfma_f32_16x16x32_f16(a, b0, acc0, 0, 0, 0);
        acc1 = __builtin_amdgcn_mfma_f32_16x16x32_f16(a, b1, acc1, 0, 0, 0);
        acc2 = __builtin_amdgcn_mfma_f32_16x16x32_f16(a, b2, acc2, 0, 0, 0);
        acc3 = __builtin_amdgcn_mfma_f32_16x16x32_f16(a, b3, acc3, 0, 0, 0);
        if (w == 0) {
            half8 bal = *(const half8*)(wtk + (size_t)(256 + col) * K);
            accal = __builtin_amdgcn_mfma_f32_16x16x32_f16(a, bal, accal, 0, 0, 0);
        }
    }

    {   // node-major store: h2[(b*SH + node)*256 + w*64 + nt*16 + col]
        __half* dst = h2 + ((size_t)b * SH + node0 + kblk * 4) * 256 + w * 64 + col;
#pragma unroll
        for (int r = 0; r < 4; r++) dst[(size_t)r * 256 + 0 * 16] = __float2half(acc0[r]);
#pragma unroll
        for (int r = 0; r < 4; r++) dst[(size_t)r * 256 + 1 * 16] = __float2half(acc1[r]);
#pragma unroll
        for (int r = 0; r < 4; r++) dst[(size_t)r * 256 + 2 * 16] = __float2half(acc2[r]);
#pragma unroll
        for (int r = 0; r < 4; r++) dst[(size_t)r * 256 + 3 * 16] = __float2half(acc3[r]);
    }
    if (w == 0 && col < 8) {
        int node = node0 + kblk * 4;
        if (col < 4) {
            float* d = alsrc + ((size_t)b * SN + node) * 4 + col;
#pragma unroll
            for (int r = 0; r < 4; r++) d[r * 4] = accal[r];
        } else {
            float* d = aldst + ((size_t)b * SN + node) * 4 + (col - 4);
#pragma unroll
            for (int r = 0; r < 4; r++) d[r * 4] = accal[r];
        }
    }
}

// ---------------- Scan (256 threads, two-pass; +1 self-loop, oct-pad) ----------------

__device__ void scan_body(const int* __restrict__ deg, int* __restrict__ offs,
                          int* __restrict__ cursor) {
    __shared__ int lds[256];
    int t = threadIdx.x;
    int i0 = t * 40;
    int tot = 0;
    for (int j = 0; j < 40; j++) {
        int i = i0 + j;
        if (i < N_NODES) tot += (deg[i] + 8) & ~7;   // (deg+1 self-loop +7) & ~7
    }
    lds[t] = tot;
    __syncthreads();
    for (int ofs = 1; ofs < 256; ofs <<= 1) {
        int v = (t >= ofs) ? lds[t - ofs] : 0;
        __syncthreads();
        lds[t] += v;
        __syncthreads();
    }
    int run = lds[t] - tot;
    for (int j = 0; j < 40; j++) {
        int i = i0 + j;
        if (i < N_NODES) {
            cursor[i] = run;
            run += (deg[i] + 8) & ~7;
            offs[i + 1] = run;
        }
    }
    if (t == 0) offs[0] = 0;
}

// ---------------- Fused dispatch: gemm1 (blocks 0..2499) || scan (block 2500) ----------------

__launch_bounds__(256)
__global__ void k_gemm1_scan(const float* __restrict__ x, const __half* __restrict__ Wt,
                             __half* __restrict__ h2, float* __restrict__ alsrc,
                             float* __restrict__ aldst, const int* __restrict__ deg,
                             int* __restrict__ offs, int* __restrict__ cursor) {
    int bid = blockIdx.x;
    if (bid == 2500) { scan_body(deg, offs, cursor); return; }
    gemm_body<F_IN_C, float>(x, Wt, h2, alsrc, aldst, bid / 625, bid % 625);
}

__launch_bounds__(256)
__global__ void k_gemm2(const __half* __restrict__ x2, const __half* __restrict__ Wt,
                        __half* __restrict__ h2, float* __restrict__ alsrc,
                        float* __restrict__ aldst) {
    gemm_body<HID_C, __half>(x2, Wt, h2, alsrc, aldst, blockIdx.y, blockIdx.x);
}

// ---------------- Scatter: real edges overwrite sentinel fill ----------------

__global__ void k_scatter(const int* __restrict__ ei, int* __restrict__ cursor,
                          int* __restrict__ csr_b) {
    int e = blockIdx.x * 256 + threadIdx.x;
    if (e < E_TOT) {
        int s, d;
        if (e < E_EDGES) { s = ei[e]; d = ei[E_EDGES + e]; }
        else { s = d = e - E_EDGES; }
        int pos = atomicAdd(&cursor[d], 1);
        csr_b[pos] = s << 9;     // src * 512 bytes (node-major fp16 row)
    }
}

// ---------------- 4-head fused gather-aggregate, in-loop alpha, oct depth-2 pipeline ----------
// One wave per dst; lane = (hd = l>>4, cl = l&15). Per edge: e = exp(leaky(alsrc+aldst))
// computed in-register (alsrc = broadcast L2-hit load; pads hit the -1e30 dummy -> e = 0).
// Node-major h2: 8 contiguous-512B gathers in flight; head-mean epilogue writes x2/out.

#define EDGE_FMA(av, g)                                                                   \
    {                                                                                     \
        float e = av + ad_h; e = e > 0.f ? e : NEG_SLOPE * e; e = __expf(e);              \
        float2 f01 = __half22float2(*(__half2*)&g.x);                                     \
        float2 f23 = __half22float2(*(__half2*)&g.y);                                     \
        acc.x += e * f01.x; acc.y += e * f01.y; acc.z += e * f23.x; acc.w += e * f23.y;   \
        sacc += e;                                                                        \
    }

template <bool LAYER1>
__launch_bounds__(256)
__global__ void k_agg(const __half* __restrict__ h2, const float* __restrict__ alsrc,
                      const float* __restrict__ aldst, const int* __restrict__ offs,
                      const int* __restrict__ csr_b, const float* __restrict__ bias,
                      void* __restrict__ outv) {
    int t = threadIdx.x;
    int bid = blockIdx.x;
    int xcd = bid & 7;
    int b = xcd >> 1;
    int local = (bid >> 3) * 2 + (xcd & 1); // 0..2499
    int wv = t >> 6, lane = t & 63;
    int hd = lane >> 4, cl = lane & 15;
    int dst = local * 4 + wv;

    const char* hcb = (const char*)(h2 + (size_t)b * SH * 256);
    const float* als = alsrc + (size_t)b * SN * 4 + hd;   // +hd folded into base
    float ad_h = aldst[((size_t)b * SN + dst) * 4 + hd];
    int s0 = offs[dst], s1 = offs[dst + 1];
    int laneoff = (hd << 7) | (cl << 3);    // head slice (128 B) + chan quad (8 B)

    float4 acc = make_float4(0.f, 0.f, 0.f, 0.f);
    float sacc = 0.f;
    // prologue: oct 0 fully staged (padded len >= 8)
    int4 cA = *(const int4*)(csr_b + s0);
    int4 cB = *(const int4*)(csr_b + s0 + 4);
    uint2 g0 = *(const uint2*)(hcb + (unsigned)(cA.x + laneoff));
    uint2 g1 = *(const uint2*)(hcb + (unsigned)(cA.y + laneoff));
    uint2 g2 = *(const uint2*)(hcb + (unsigned)(cA.z + laneoff));
    uint2 g3 = *(const uint2*)(hcb + (unsigned)(cA.w + laneoff));
    uint2 g4 = *(const uint2*)(hcb + (unsigned)(cB.x + laneoff));
    uint2 g5 = *(const uint2*)(hcb + (unsigned)(cB.y + laneoff));
    uint2 g6 = *(const uint2*)(hcb + (unsigned)(cB.z + laneoff));
    uint2 g7 = *(const uint2*)(hcb + (unsigned)(cB.w + laneoff));
    float a0 = als[cA.x >> 7], a1 = als[cA.y >> 7], a2 = als[cA.z >> 7], a3 = als[cA.w >> 7];
    float a4 = als[cB.x >> 7], a5 = als[cB.y >> 7], a6 = als[cB.z >> 7], a7 = als[cB.w >> 7];
    // oct 1 indices (clamped)
    int jn = (s0 + 8 < s1) ? s0 + 8 : s0;
    int4 cA2 = *(const int4*)(csr_b + jn);
    int4 cB2 = *(const int4*)(csr_b + jn + 4);

    for (int j = s0 + 8; j < s1; j += 8) {
        // gathers + alsrc for oct (k+1) -- indices loaded a full iteration ago
        uint2 m0 = *(const uint2*)(hcb + (unsigned)(cA2.x + laneoff));
        uint2 m1 = *(const uint2*)(hcb + (unsigned)(cA2.y + laneoff));
        uint2 m2 = *(const uint2*)(hcb + (unsigned)(cA2.z + laneoff));
        uint2 m3 = *(const uint2*)(hcb + (unsigned)(cA2.w + laneoff));
        uint2 m4 = *(const uint2*)(hcb + (unsigned)(cB2.x + laneoff));
        uint2 m5 = *(const uint2*)(hcb + (unsigned)(cB2.y + laneoff));
        uint2 m6 = *(const uint2*)(hcb + (unsigned)(cB2.z + laneoff));
        uint2 m7 = *(const uint2*)(hcb + (unsigned)(cB2.w + laneoff));
        float v0 = als[cA2.x >> 7], v1 = als[cA2.y >> 7], v2 = als[cA2.z >> 7], v3 = als[cA2.w >> 7];
        float v4 = als[cB2.x >> 7], v5 = als[cB2.y >> 7], v6 = als[cB2.z >> 7], v7 = als[cB2.w >> 7];
        // indices for oct (k+2), clamped
        int j2 = (j + 8 < s1) ? j + 8 : j;
        int4 cA3 = *(const int4*)(csr_b + j2);
        int4 cB3 = *(const int4*)(csr_b + j2 + 4);
        // consume oct k
        EDGE_FMA(a0, g0) EDGE_FMA(a1, g1) EDGE_FMA(a2, g2) EDGE_FMA(a3, g3)
        EDGE_FMA(a4, g4) EDGE_FMA(a5, g5) EDGE_FMA(a6, g6) EDGE_FMA(a7, g7)
        g0 = m0; g1 = m1; g2 = m2; g3 = m3; g4 = m4; g5 = m5; g6 = m6; g7 = m7;
        a0 = v0; a1 = v1; a2 = v2; a3 = v3; a4 = v4; a5 = v5; a6 = v6; a7 = v7;
        cA2 = cA3; cB2 = cB3;
    }
    EDGE_FMA(a0, g0) EDGE_FMA(a1, g1) EDGE_FMA(a2, g2) EDGE_FMA(a3, g3)
    EDGE_FMA(a4, g4) EDGE_FMA(a5, g5) EDGE_FMA(a6, g6) EDGE_FMA(a7, g7)

    // per-head normalize, then fold heads (lanes cl, cl+16, cl+32, cl+48 share channel)
    float inv = 1.f / (sacc + 1e-16f);
    float4 v = make_float4(acc.x * inv, acc.y * inv, acc.z * inv, acc.w * inv);
#pragma unroll
    for (int o = 16; o < 64; o <<= 1) {
        v.x += __shfl_xor(v.x, o);
        v.y += __shfl_xor(v.y, o);
        v.z += __shfl_xor(v.z, o);
        v.w += __shfl_xor(v.w, o);
    }
    if (lane < 16) {
        float4 b4 = *(const float4*)(bias + cl * 4);
        float ox = v.x * 0.25f + b4.x;
        float oy = v.y * 0.25f + b4.y;
        float oz = v.z * 0.25f + b4.z;
        float ow = v.w * 0.25f + b4.w;
        if (LAYER1) {
            ox = ox > 0.f ? ox : expm1f(ox);
            oy = oy > 0.f ? oy : expm1f(oy);
            oz = oz > 0.f ? oz : expm1f(oz);
            ow = ow > 0.f ? ow : expm1f(ow);
            __half2 lo = __floats2half2_rn(ox, oy);
            __half2 hi = __floats2half2_rn(oz, ow);
            uint2 pk = make_uint2(*(unsigned*)&lo, *(unsigned*)&hi);
            *(uint2*)((__half*)outv + ((size_t)b * N_NODES + dst) * 64 + cl * 4) = pk;
        } else {
            *(float4*)((float*)outv + ((size_t)b * N_NODES + dst) * 64 + cl * 4) =
                make_float4(ox, oy, oz, ow);
        }
    }
}

// ---------------- Launch: 7 dispatches + 1 memset ----------------

extern "C" void kernel_launch(void* const* d_in, const int* in_sizes, int n_in,
                              void* d_out, int out_size, void* d_ws, size_t ws_size,
                              hipStream_t stream) {
    const float* x = (const float*)d_in[0];
    const int* ei = (const int*)d_in[1];
    const float* W1 = (const float*)d_in[2];
    const float* as1 = (const float*)d_in[3];
    const float* ad1 = (const float*)d_in[4];
    const float* b1 = (const float*)d_in[5];
    const float* W2 = (const float*)d_in[6];
    const float* as2 = (const float*)d_in[7];
    const float* ad2 = (const float*)d_in[8];
    const float* b2 = (const float*)d_in[9];
    float* out = (float*)d_out;

    // workspace layout (all segments 16B-aligned by construction)
    char* p = (char*)d_ws;
    int* deg = (int*)p;            p += sizeof(int) * N_NODES;
    int* offs = (int*)p;           p += sizeof(int) * (N_NODES + 4);
    int* cursor = (int*)p;         p += sizeof(int) * N_NODES;
    int* csr_b = (int*)p;          p += sizeof(int) * E_OCT;
    __half* Wt1 = (__half*)p;      p += sizeof(__half) * 272 * F_IN_C;
    __half* Wt2 = (__half*)p;      p += sizeof(__half) * 272 * HID_C;
    float* alsrc = (float*)p;      p += sizeof(float) * B_BATCH * SN * 4;
    float* aldst = (float*)p;      p += sizeof(float) * B_BATCH * SN * 4;
    __half* h2 = (__half*)p;       p += sizeof(__half) * (size_t)B_BATCH * SH * 256;
    __half* x2 = (__half*)p;       p += sizeof(__half) * (size_t)B_BATCH * N_NODES * 64;

    hipMemsetAsync(deg, 0, sizeof(int) * N_NODES, stream);

    // D1: wext1 | wext2 | csr sentinel fill | dummy rows | deg_count
    k_setup<<<1768, 256, 0, stream>>>(W1, as1, ad1, W2, as2, ad2, Wt1, Wt2,
                                      csr_b, h2, alsrc, deg, ei);
    // D2: gemm layer 1 (2500 blocks) || scan (block 2500)
    k_gemm1_scan<<<2501, 256, 0, stream>>>(x, Wt1, h2, alsrc, aldst, deg, offs, cursor);
    // D3: scatter (overwrites sentinel fill with real edges)
    k_scatter<<<(E_TOT + 255) / 256, 256, 0, stream>>>(ei, cursor, csr_b);
    // D4: layer-1 aggregate (alpha in-loop) -> x2 (fp16)
    k_agg<true><<<B_BATCH * 2500, 256, 0, stream>>>(h2, alsrc, aldst, offs, csr_b, b1, x2);
    // D5: gemm layer 2
    k_gemm2<<<dim3(625, B_BATCH), 256, 0, stream>>>(x2, Wt2, h2, alsrc, aldst);
    // D6: layer-2 aggregate -> out (f32)
    k_agg<false><<<B_BATCH * 2500, 256, 0, stream>>>(h2, alsrc, aldst, offs, csr_b, b2, out);
}

// Round 19
// 180.274 us; speedup vs baseline: 1.4996x; 1.1076x over previous
//
#include <hip/hip_runtime.h>
#include <hip/hip_fp16.h>
#include <math.h>

#define N_NODES 10000
#define N_PAD 10240    // deg array padded for int4 scan reads
#define B_BATCH 4
#define F_IN_C 128
#define HID_C 64
#define E_EDGES 160000
#define E_TOT (E_EDGES + N_NODES)
#define E_OCT 240000   // E_TOT + 7*N_NODES upper bound (oct-padded)
#define NEG_SLOPE 0.2f
#define SN (N_NODES + 8)   // alsrc/aldst node stride per batch (row N = dummy, -1e30)
#define SH (N_NODES + 8)   // h2 rows per batch (row N = dummy, zeros)

typedef _Float16 half8 __attribute__((ext_vector_type(8)));
typedef float f32x4 __attribute__((ext_vector_type(4)));

// ---------------- Wt_ext: fp16 col-major [272][K]; 256+hd=W@a_src, 260+hd=W@a_dst ----------------

__device__ void wext_body(const float* __restrict__ W, const float* __restrict__ asrc,
                          const float* __restrict__ adst, __half* __restrict__ Wt,
                          int tid, int K) {
    int nc = tid / K, k = tid % K;
    float v;
    if (nc < 256) {
        v = W[k * 256 + nc];
    } else if (nc < 260) {
        int hd = nc - 256; v = 0.f;
        for (int c = 0; c < 64; c++) v += W[k * 256 + hd * 64 + c] * asrc[hd * 64 + c];
    } else if (nc < 264) {
        int hd = nc - 260; v = 0.f;
        for (int c = 0; c < 64; c++) v += W[k * 256 + hd * 64 + c] * adst[hd * 64 + c];
    } else {
        v = 0.f;
    }
    Wt[(size_t)nc * K + k] = __float2half(v);
}

// ---------------- Mega-setup: wext1 | wext2 | csr sentinel-fill | dummy rows | deg_count --------
// deg pre-zeroed by hipMemsetAsync (N_PAD entries). Pads never touched by scatter keep the
// dummy sentinel (csr_b = N<<9) whose alsrc row is -1e30 -> e = 0 -> zero contribution.

__global__ void k_setup(const float* __restrict__ W1, const float* __restrict__ as1,
                        const float* __restrict__ ad1, const float* __restrict__ W2,
                        const float* __restrict__ as2, const float* __restrict__ ad2,
                        __half* __restrict__ Wt1, __half* __restrict__ Wt2,
                        int* __restrict__ csr_b, __half* __restrict__ h2,
                        float* __restrict__ alsrc, int* __restrict__ deg,
                        const int* __restrict__ ei) {
    int blk = blockIdx.x, t = threadIdx.x;
    if (blk < 136) {
        wext_body(W1, as1, ad1, Wt1, blk * 256 + t, F_IN_C);
    } else if (blk < 204) {
        wext_body(W2, as2, ad2, Wt2, (blk - 136) * 256 + t, HID_C);
    } else if (blk < 1142) {
        int i = (blk - 204) * 256 + t;
        if (i < E_OCT) csr_b[i] = N_NODES << 9;   // dummy sentinel
    } else if (blk == 1142) {
        for (int i = t; i < 4 * 256; i += 256) {   // dummy h2 rows = 0
            int b = i >> 8, c = i & 255;
            h2[((size_t)b * SH + N_NODES) * 256 + c] = __float2half(0.f);
        }
        if (t < 16) {                              // dummy alsrc = -1e30
            int b = t >> 2, q = t & 3;
            alsrc[((size_t)b * SN + N_NODES) * 4 + q] = -1e30f;
        }
    } else {
        int e = (blk - 1143) * 256 + t;
        if (e < E_EDGES) atomicAdd(&deg[ei[E_EDGES + e]], 1);
    }
}

// ---------------- MFMA GEMM body: h = x@W (fp16 in, f32 accum, node-major fp16 out) ------------

template <int K, typename XT>
__device__ void gemm_body(const XT* __restrict__ x, const __half* __restrict__ Wt,
                          __half* __restrict__ h2, float* __restrict__ alsrc,
                          float* __restrict__ aldst, int b, int tile) {
    int t = threadIdx.x;
    int w = t >> 6, lane = t & 63;
    int node0 = tile * 16;
    int col = lane & 15, kblk = lane >> 4;

    const XT* xr = x + ((size_t)b * N_NODES + node0 + col) * K + kblk * 8;

    f32x4 acc0 = {0.f, 0.f, 0.f, 0.f};
    f32x4 acc1 = {0.f, 0.f, 0.f, 0.f};
    f32x4 acc2 = {0.f, 0.f, 0.f, 0.f};
    f32x4 acc3 = {0.f, 0.f, 0.f, 0.f};
    f32x4 accal = {0.f, 0.f, 0.f, 0.f};

#pragma unroll
    for (int k0 = 0; k0 < K; k0 += 32) {
        half8 a;
        if constexpr (sizeof(XT) == 4) {
            float4 xa = *(const float4*)(xr + k0);
            float4 xc = *(const float4*)(xr + k0 + 4);
            a[0] = (_Float16)xa.x; a[1] = (_Float16)xa.y; a[2] = (_Float16)xa.z; a[3] = (_Float16)xa.w;
            a[4] = (_Float16)xc.x; a[5] = (_Float16)xc.y; a[6] = (_Float16)xc.z; a[7] = (_Float16)xc.w;
        } else {
            a = *(const half8*)(xr + k0);
        }
        const __half* wtk = Wt + kblk * 8 + k0;
        half8 b0 = *(const half8*)(wtk + (size_t)((w * 4 + 0) * 16 + col) * K);
        half8 b1 = *(const half8*)(wtk + (size_t)((w * 4 + 1) * 16 + col) * K);
        half8 b2 = *(const half8*)(wtk + (size_t)((w * 4 + 2) * 16 + col) * K);
        half8 b3 = *(const half8*)(wtk + (size_t)((w * 4 + 3) * 16 + col) * K);
        acc0 = __builtin_amdgcn_mfma_f32_16x16x32_f16(a, b0, acc0, 0, 0, 0);
        acc1 = __builtin_amdgcn_mfma_f32_16x16x32_f16(a, b1, acc1, 0, 0, 0);
        acc2 = __builtin_amdgcn_mfma_f32_16x16x32_f16(a, b2, acc2, 0, 0, 0);
        acc3 = __builtin_amdgcn_mfma_f32_16x16x32_f16(a, b3, acc3, 0, 0, 0);
        if (w == 0) {
            half8 bal = *(const half8*)(wtk + (size_t)(256 + col) * K);
            accal = __builtin_amdgcn_mfma_f32_16x16x32_f16(a, bal, accal, 0, 0, 0);
        }
    }

    {   // node-major store: h2[(b*SH + node)*256 + w*64 + nt*16 + col]
        __half* dst = h2 + ((size_t)b * SH + node0 + kblk * 4) * 256 + w * 64 + col;
#pragma unroll
        for (int r = 0; r < 4; r++) dst[(size_t)r * 256 + 0 * 16] = __float2half(acc0[r]);
#pragma unroll
        for (int r = 0; r < 4; r++) dst[(size_t)r * 256 + 1 * 16] = __float2half(acc1[r]);
#pragma unroll
        for (int r = 0; r < 4; r++) dst[(size_t)r * 256 + 2 * 16] = __float2half(acc2[r]);
#pragma unroll
        for (int r = 0; r < 4; r++) dst[(size_t)r * 256 + 3 * 16] = __float2half(acc3[r]);
    }
    if (w == 0 && col < 8) {
        int node = node0 + kblk * 4;
        if (col < 4) {
            float* d = alsrc + ((size_t)b * SN + node) * 4 + col;
#pragma unroll
            for (int r = 0; r < 4; r++) d[r * 4] = accal[r];
        } else {
            float* d = aldst + ((size_t)b * SN + node) * 4 + (col - 4);
#pragma unroll
            for (int r = 0; r < 4; r++) d[r * 4] = accal[r];
        }
    }
}

// ---------------- Scan (256 threads; int4-vectorized loads, fully pipelined) ----------------
// r18 post-mortem: scalar 160B-strided deg loads made the scan block a 55 us straggler.
// 10x int4 independent loads/thread (deg padded to N_PAD, zeros round to 8, masked writes).

__device__ void scan_body(const int* __restrict__ deg, int* __restrict__ offs,
                          int* __restrict__ cursor) {
    __shared__ int lds[256];
    int t = threadIdx.x;
    int i0 = t * 40;
    int v[40];
#pragma unroll
    for (int q = 0; q < 10; q++) {
        int4 d4 = *(const int4*)(deg + i0 + q * 4);
        v[q * 4 + 0] = (d4.x + 8) & ~7;   // (deg + 1 self-loop + 7) & ~7
        v[q * 4 + 1] = (d4.y + 8) & ~7;
        v[q * 4 + 2] = (d4.z + 8) & ~7;
        v[q * 4 + 3] = (d4.w + 8) & ~7;
    }
    int tot = 0;
#pragma unroll
    for (int j = 0; j < 40; j++) tot += v[j];
    lds[t] = tot;
    __syncthreads();
    for (int ofs = 1; ofs < 256; ofs <<= 1) {
        int w = (t >= ofs) ? lds[t - ofs] : 0;
        __syncthreads();
        lds[t] += w;
        __syncthreads();
    }
    int run = lds[t] - tot;
#pragma unroll
    for (int j = 0; j < 40; j++) {
        int i = i0 + j;
        if (i < N_NODES) {
            cursor[i] = run;
            offs[i + 1] = run + v[j];
        }
        run += v[j];
    }
    if (t == 0) offs[0] = 0;
}

// ---------------- Fused dispatch: scan (block 0) || gemm1 (blocks 1..2500) ----------------

__launch_bounds__(256)
__global__ void k_gemm1_scan(const float* __restrict__ x, const __half* __restrict__ Wt,
                             __half* __restrict__ h2, float* __restrict__ alsrc,
                             float* __restrict__ aldst, const int* __restrict__ deg,
                             int* __restrict__ offs, int* __restrict__ cursor) {
    int bid = blockIdx.x;
    if (bid == 0) { scan_body(deg, offs, cursor); return; }
    gemm_body<F_IN_C, float>(x, Wt, h2, alsrc, aldst, (bid - 1) / 625, (bid - 1) % 625);
}

__launch_bounds__(256)
__global__ void k_gemm2(const __half* __restrict__ x2, const __half* __restrict__ Wt,
                        __half* __restrict__ h2, float* __restrict__ alsrc,
                        float* __restrict__ aldst) {
    gemm_body<HID_C, __half>(x2, Wt, h2, alsrc, aldst, blockIdx.y, blockIdx.x);
}

// ---------------- Scatter: real edges overwrite sentinel fill ----------------

__global__ void k_scatter(const int* __restrict__ ei, int* __restrict__ cursor,
                          int* __restrict__ csr_b) {
    int e = blockIdx.x * 256 + threadIdx.x;
    if (e < E_TOT) {
        int s, d;
        if (e < E_EDGES) { s = ei[e]; d = ei[E_EDGES + e]; }
        else { s = d = e - E_EDGES; }
        int pos = atomicAdd(&cursor[d], 1);
        csr_b[pos] = s << 9;     // src * 512 bytes (node-major fp16 row)
    }
}

// ---------------- 4-head fused gather-aggregate, in-loop alpha, oct depth-2 pipeline ----------

#define EDGE_FMA(av, g)                                                                   \
    {                                                                                     \
        float e = av + ad_h; e = e > 0.f ? e : NEG_SLOPE * e; e = __expf(e);              \
        float2 f01 = __half22float2(*(__half2*)&g.x);                                     \
        float2 f23 = __half22float2(*(__half2*)&g.y);                                     \
        acc.x += e * f01.x; acc.y += e * f01.y; acc.z += e * f23.x; acc.w += e * f23.y;   \
        sacc += e;                                                                        \
    }

template <bool LAYER1>
__launch_bounds__(256)
__global__ void k_agg(const __half* __restrict__ h2, const float* __restrict__ alsrc,
                      const float* __restrict__ aldst, const int* __restrict__ offs,
                      const int* __restrict__ csr_b, const float* __restrict__ bias,
                      void* __restrict__ outv) {
    int t = threadIdx.x;
    int bid = blockIdx.x;
    int xcd = bid & 7;
    int b = xcd >> 1;
    int local = (bid >> 3) * 2 + (xcd & 1); // 0..2499
    int wv = t >> 6, lane = t & 63;
    int hd = lane >> 4, cl = lane & 15;
    int dst = local * 4 + wv;

    const char* hcb = (const char*)(h2 + (size_t)b * SH * 256);
    const float* als = alsrc + (size_t)b * SN * 4 + hd;   // +hd folded into base
    float ad_h = aldst[((size_t)b * SN + dst) * 4 + hd];
    int s0 = offs[dst], s1 = offs[dst + 1];
    int laneoff = (hd << 7) | (cl << 3);    // head slice (128 B) + chan quad (8 B)

    float4 acc = make_float4(0.f, 0.f, 0.f, 0.f);
    float sacc = 0.f;
    // prologue: oct 0 fully staged (padded len >= 8)
    int4 cA = *(const int4*)(csr_b + s0);
    int4 cB = *(const int4*)(csr_b + s0 + 4);
    uint2 g0 = *(const uint2*)(hcb + (unsigned)(cA.x + laneoff));
    uint2 g1 = *(const uint2*)(hcb + (unsigned)(cA.y + laneoff));
    uint2 g2 = *(const uint2*)(hcb + (unsigned)(cA.z + laneoff));
    uint2 g3 = *(const uint2*)(hcb + (unsigned)(cA.w + laneoff));
    uint2 g4 = *(const uint2*)(hcb + (unsigned)(cB.x + laneoff));
    uint2 g5 = *(const uint2*)(hcb + (unsigned)(cB.y + laneoff));
    uint2 g6 = *(const uint2*)(hcb + (unsigned)(cB.z + laneoff));
    uint2 g7 = *(const uint2*)(hcb + (unsigned)(cB.w + laneoff));
    float a0 = als[cA.x >> 7], a1 = als[cA.y >> 7], a2 = als[cA.z >> 7], a3 = als[cA.w >> 7];
    float a4 = als[cB.x >> 7], a5 = als[cB.y >> 7], a6 = als[cB.z >> 7], a7 = als[cB.w >> 7];
    // oct 1 indices (clamped)
    int jn = (s0 + 8 < s1) ? s0 + 8 : s0;
    int4 cA2 = *(const int4*)(csr_b + jn);
    int4 cB2 = *(const int4*)(csr_b + jn + 4);

    for (int j = s0 + 8; j < s1; j += 8) {
        uint2 m0 = *(const uint2*)(hcb + (unsigned)(cA2.x + laneoff));
        uint2 m1 = *(const uint2*)(hcb + (unsigned)(cA2.y + laneoff));
        uint2 m2 = *(const uint2*)(hcb + (unsigned)(cA2.z + laneoff));
        uint2 m3 = *(const uint2*)(hcb + (unsigned)(cA2.w + laneoff));
        uint2 m4 = *(const uint2*)(hcb + (unsigned)(cB2.x + laneoff));
        uint2 m5 = *(const uint2*)(hcb + (unsigned)(cB2.y + laneoff));
        uint2 m6 = *(const uint2*)(hcb + (unsigned)(cB2.z + laneoff));
        uint2 m7 = *(const uint2*)(hcb + (unsigned)(cB2.w + laneoff));
        float v0 = als[cA2.x >> 7], v1 = als[cA2.y >> 7], v2 = als[cA2.z >> 7], v3 = als[cA2.w >> 7];
        float v4 = als[cB2.x >> 7], v5 = als[cB2.y >> 7], v6 = als[cB2.z >> 7], v7 = als[cB2.w >> 7];
        int j2 = (j + 8 < s1) ? j + 8 : j;
        int4 cA3 = *(const int4*)(csr_b + j2);
        int4 cB3 = *(const int4*)(csr_b + j2 + 4);
        EDGE_FMA(a0, g0) EDGE_FMA(a1, g1) EDGE_FMA(a2, g2) EDGE_FMA(a3, g3)
        EDGE_FMA(a4, g4) EDGE_FMA(a5, g5) EDGE_FMA(a6, g6) EDGE_FMA(a7, g7)
        g0 = m0; g1 = m1; g2 = m2; g3 = m3; g4 = m4; g5 = m5; g6 = m6; g7 = m7;
        a0 = v0; a1 = v1; a2 = v2; a3 = v3; a4 = v4; a5 = v5; a6 = v6; a7 = v7;
        cA2 = cA3; cB2 = cB3;
    }
    EDGE_FMA(a0, g0) EDGE_FMA(a1, g1) EDGE_FMA(a2, g2) EDGE_FMA(a3, g3)
    EDGE_FMA(a4, g4) EDGE_FMA(a5, g5) EDGE_FMA(a6, g6) EDGE_FMA(a7, g7)

    // per-head normalize, then fold heads (lanes cl, cl+16, cl+32, cl+48 share channel)
    float inv = 1.f / (sacc + 1e-16f);
    float4 v = make_float4(acc.x * inv, acc.y * inv, acc.z * inv, acc.w * inv);
#pragma unroll
    for (int o = 16; o < 64; o <<= 1) {
        v.x += __shfl_xor(v.x, o);
        v.y += __shfl_xor(v.y, o);
        v.z += __shfl_xor(v.z, o);
        v.w += __shfl_xor(v.w, o);
    }
    if (lane < 16) {
        float4 b4 = *(const float4*)(bias + cl * 4);
        float ox = v.x * 0.25f + b4.x;
        float oy = v.y * 0.25f + b4.y;
        float oz = v.z * 0.25f + b4.z;
        float ow = v.w * 0.25f + b4.w;
        if (LAYER1) {
            ox = ox > 0.f ? ox : expm1f(ox);
            oy = oy > 0.f ? oy : expm1f(oy);
            oz = oz > 0.f ? oz : expm1f(oz);
            ow = ow > 0.f ? ow : expm1f(ow);
            __half2 lo = __floats2half2_rn(ox, oy);
            __half2 hi = __floats2half2_rn(oz, ow);
            uint2 pk = make_uint2(*(unsigned*)&lo, *(unsigned*)&hi);
            *(uint2*)((__half*)outv + ((size_t)b * N_NODES + dst) * 64 + cl * 4) = pk;
        } else {
            *(float4*)((float*)outv + ((size_t)b * N_NODES + dst) * 64 + cl * 4) =
                make_float4(ox, oy, oz, ow);
        }
    }
}

// ---------------- Launch: 6 dispatches + 1 memset ----------------

extern "C" void kernel_launch(void* const* d_in, const int* in_sizes, int n_in,
                              void* d_out, int out_size, void* d_ws, size_t ws_size,
                              hipStream_t stream) {
    const float* x = (const float*)d_in[0];
    const int* ei = (const int*)d_in[1];
    const float* W1 = (const float*)d_in[2];
    const float* as1 = (const float*)d_in[3];
    const float* ad1 = (const float*)d_in[4];
    const float* b1 = (const float*)d_in[5];
    const float* W2 = (const float*)d_in[6];
    const float* as2 = (const float*)d_in[7];
    const float* ad2 = (const float*)d_in[8];
    const float* b2 = (const float*)d_in[9];
    float* out = (float*)d_out;

    // workspace layout (all segments 16B-aligned by construction)
    char* p = (char*)d_ws;
    int* deg = (int*)p;            p += sizeof(int) * N_PAD;
    int* offs = (int*)p;           p += sizeof(int) * (N_NODES + 4);
    int* cursor = (int*)p;         p += sizeof(int) * N_NODES;
    int* csr_b = (int*)p;          p += sizeof(int) * E_OCT;
    __half* Wt1 = (__half*)p;      p += sizeof(__half) * 272 * F_IN_C;
    __half* Wt2 = (__half*)p;      p += sizeof(__half) * 272 * HID_C;
    float* alsrc = (float*)p;      p += sizeof(float) * B_BATCH * SN * 4;
    float* aldst = (float*)p;      p += sizeof(float) * B_BATCH * SN * 4;
    __half* h2 = (__half*)p;       p += sizeof(__half) * (size_t)B_BATCH * SH * 256;
    __half* x2 = (__half*)p;       p += sizeof(__half) * (size_t)B_BATCH * N_NODES * 64;

    hipMemsetAsync(deg, 0, sizeof(int) * N_PAD, stream);

    // D1: wext1 | wext2 | csr sentinel fill | dummy rows | deg_count
    k_setup<<<1768, 256, 0, stream>>>(W1, as1, ad1, W2, as2, ad2, Wt1, Wt2,
                                      csr_b, h2, alsrc, deg, ei);
    // D2: scan (block 0, int4-vectorized) || gemm layer 1 (blocks 1..2500)
    k_gemm1_scan<<<2501, 256, 0, stream>>>(x, Wt1, h2, alsrc, aldst, deg, offs, cursor);
    // D3: scatter (overwrites sentinel fill with real edges)
    k_scatter<<<(E_TOT + 255) / 256, 256, 0, stream>>>(ei, cursor, csr_b);
    // D4: layer-1 aggregate (alpha in-loop) -> x2 (fp16)
    k_agg<true><<<B_BATCH * 2500, 256, 0, stream>>>(h2, alsrc, aldst, offs, csr_b, b1, x2);
    // D5: gemm layer 2
    k_gemm2<<<dim3(625, B_BATCH), 256, 0, stream>>>(x2, Wt2, h2, alsrc, aldst);
    // D6: layer-2 aggregate -> out (f32)
    k_agg<false><<<B_BATCH * 2500, 256, 0, stream>>>(h2, alsrc, aldst, offs, csr_b, b2, out);
}

// Round 20
// 179.338 us; speedup vs baseline: 1.5074x; 1.0052x over previous
//
#include <hip/hip_runtime.h>
#include <hip/hip_fp16.h>
#include <math.h>

#define N_NODES 10000
#define N_PAD 10240    // deg array padded for int4 scan reads
#define B_BATCH 4
#define F_IN_C 128
#define HID_C 64
#define E_EDGES 160000
#define E_TOT (E_EDGES + N_NODES)
#define E_OCT 240000   // E_TOT + 7*N_NODES upper bound (oct-padded)
#define NEG_SLOPE 0.2f
#define LOG2E 1.44269504f
#define SN (N_NODES + 8)   // alsrc/aldst node stride per batch (row N = dummy, -1e30)
#define SH (N_NODES + 8)   // h2 rows per batch (row N = dummy, zeros)

typedef _Float16 half8 __attribute__((ext_vector_type(8)));
typedef float f32x4 __attribute__((ext_vector_type(4)));

// ---------------- Wt_ext: fp16 col-major [272][K]; 256+hd=W@a_src, 260+hd=W@a_dst --------------
// al columns pre-scaled by log2(e): leaky is positively homogeneous, so
// exp(leaky(s+d)) == exp2(leaky(s'+d')) with s',d' scaled -- saves the per-edge mul in k_agg.

__device__ void wext_body(const float* __restrict__ W, const float* __restrict__ asrc,
                          const float* __restrict__ adst, __half* __restrict__ Wt,
                          int tid, int K) {
    int nc = tid / K, k = tid % K;
    float v;
    if (nc < 256) {
        v = W[k * 256 + nc];
    } else if (nc < 260) {
        int hd = nc - 256; v = 0.f;
        for (int c = 0; c < 64; c++) v += W[k * 256 + hd * 64 + c] * asrc[hd * 64 + c];
        v *= LOG2E;
    } else if (nc < 264) {
        int hd = nc - 260; v = 0.f;
        for (int c = 0; c < 64; c++) v += W[k * 256 + hd * 64 + c] * adst[hd * 64 + c];
        v *= LOG2E;
    } else {
        v = 0.f;
    }
    Wt[(size_t)nc * K + k] = __float2half(v);
}

// ---------------- Mega-setup: wext1 | wext2 | csr sentinel-fill | dummy rows | deg_count --------

__global__ void k_setup(const float* __restrict__ W1, const float* __restrict__ as1,
                        const float* __restrict__ ad1, const float* __restrict__ W2,
                        const float* __restrict__ as2, const float* __restrict__ ad2,
                        __half* __restrict__ Wt1, __half* __restrict__ Wt2,
                        int* __restrict__ csr_b, __half* __restrict__ h2,
                        float* __restrict__ alsrc, int* __restrict__ deg,
                        const int* __restrict__ ei) {
    int blk = blockIdx.x, t = threadIdx.x;
    if (blk < 136) {
        wext_body(W1, as1, ad1, Wt1, blk * 256 + t, F_IN_C);
    } else if (blk < 204) {
        wext_body(W2, as2, ad2, Wt2, (blk - 136) * 256 + t, HID_C);
    } else if (blk < 1142) {
        int i = (blk - 204) * 256 + t;
        if (i < E_OCT) csr_b[i] = N_NODES << 9;   // dummy sentinel
    } else if (blk == 1142) {
        for (int i = t; i < 4 * 256; i += 256) {   // dummy h2 rows = 0
            int b = i >> 8, c = i & 255;
            h2[((size_t)b * SH + N_NODES) * 256 + c] = __float2half(0.f);
        }
        if (t < 16) {                              // dummy alsrc = -1e30
            int b = t >> 2, q = t & 3;
            alsrc[((size_t)b * SN + N_NODES) * 4 + q] = -1e30f;
        }
    } else {
        int e = (blk - 1143) * 256 + t;
        if (e < E_EDGES) atomicAdd(&deg[ei[E_EDGES + e]], 1);
    }
}

// ---------------- MFMA GEMM body: h = x@W (fp16 in, f32 accum, node-major fp16 out) ------------

template <int K, typename XT>
__device__ void gemm_body(const XT* __restrict__ x, const __half* __restrict__ Wt,
                          __half* __restrict__ h2, float* __restrict__ alsrc,
                          float* __restrict__ aldst, int b, int tile) {
    int t = threadIdx.x;
    int w = t >> 6, lane = t & 63;
    int node0 = tile * 16;
    int col = lane & 15, kblk = lane >> 4;

    const XT* xr = x + ((size_t)b * N_NODES + node0 + col) * K + kblk * 8;

    f32x4 acc0 = {0.f, 0.f, 0.f, 0.f};
    f32x4 acc1 = {0.f, 0.f, 0.f, 0.f};
    f32x4 acc2 = {0.f, 0.f, 0.f, 0.f};
    f32x4 acc3 = {0.f, 0.f, 0.f, 0.f};
    f32x4 accal = {0.f, 0.f, 0.f, 0.f};

#pragma unroll
    for (int k0 = 0; k0 < K; k0 += 32) {
        half8 a;
        if constexpr (sizeof(XT) == 4) {
            float4 xa = *(const float4*)(xr + k0);
            float4 xc = *(const float4*)(xr + k0 + 4);
            a[0] = (_Float16)xa.x; a[1] = (_Float16)xa.y; a[2] = (_Float16)xa.z; a[3] = (_Float16)xa.w;
            a[4] = (_Float16)xc.x; a[5] = (_Float16)xc.y; a[6] = (_Float16)xc.z; a[7] = (_Float16)xc.w;
        } else {
            a = *(const half8*)(xr + k0);
        }
        const __half* wtk = Wt + kblk * 8 + k0;
        half8 b0 = *(const half8*)(wtk + (size_t)((w * 4 + 0) * 16 + col) * K);
        half8 b1 = *(const half8*)(wtk + (size_t)((w * 4 + 1) * 16 + col) * K);
        half8 b2 = *(const half8*)(wtk + (size_t)((w * 4 + 2) * 16 + col) * K);
        half8 b3 = *(const half8*)(wtk + (size_t)((w * 4 + 3) * 16 + col) * K);
        acc0 = __builtin_amdgcn_mfma_f32_16x16x32_f16(a, b0, acc0, 0, 0, 0);
        acc1 = __builtin_amdgcn_mfma_f32_16x16x32_f16(a, b1, acc1, 0, 0, 0);
        acc2 = __builtin_amdgcn_mfma_f32_16x16x32_f16(a, b2, acc2, 0, 0, 0);
        acc3 = __builtin_amdgcn_mfma_f32_16x16x32_f16(a, b3, acc3, 0, 0, 0);
        if (w == 0) {
            half8 bal = *(const half8*)(wtk + (size_t)(256 + col) * K);
            accal = __builtin_amdgcn_mfma_f32_16x16x32_f16(a, bal, accal, 0, 0, 0);
        }
    }

    {   // node-major store: h2[(b*SH + node)*256 + w*64 + nt*16 + col]
        __half* dst = h2 + ((size_t)b * SH + node0 + kblk * 4) * 256 + w * 64 + col;
#pragma unroll
        for (int r = 0; r < 4; r++) dst[(size_t)r * 256 + 0 * 16] = __float2half(acc0[r]);
#pragma unroll
        for (int r = 0; r < 4; r++) dst[(size_t)r * 256 + 1 * 16] = __float2half(acc1[r]);
#pragma unroll
        for (int r = 0; r < 4; r++) dst[(size_t)r * 256 + 2 * 16] = __float2half(acc2[r]);
#pragma unroll
        for (int r = 0; r < 4; r++) dst[(size_t)r * 256 + 3 * 16] = __float2half(acc3[r]);
    }
    if (w == 0 && col < 8) {
        int node = node0 + kblk * 4;
        if (col < 4) {
            float* d = alsrc + ((size_t)b * SN + node) * 4 + col;
#pragma unroll
            for (int r = 0; r < 4; r++) d[r * 4] = accal[r];
        } else {
            float* d = aldst + ((size_t)b * SN + node) * 4 + (col - 4);
#pragma unroll
            for (int r = 0; r < 4; r++) d[r * 4] = accal[r];
        }
    }
}

// ---------------- Scan (256 threads; int4-vectorized loads, fully pipelined) ----------------

__device__ void scan_body(const int* __restrict__ deg, int* __restrict__ offs,
                          int* __restrict__ cursor) {
    __shared__ int lds[256];
    int t = threadIdx.x;
    int i0 = t * 40;
    int v[40];
#pragma unroll
    for (int q = 0; q < 10; q++) {
        int4 d4 = *(const int4*)(deg + i0 + q * 4);
        v[q * 4 + 0] = (d4.x + 8) & ~7;   // (deg + 1 self-loop + 7) & ~7
        v[q * 4 + 1] = (d4.y + 8) & ~7;
        v[q * 4 + 2] = (d4.z + 8) & ~7;
        v[q * 4 + 3] = (d4.w + 8) & ~7;
    }
    int tot = 0;
#pragma unroll
    for (int j = 0; j < 40; j++) tot += v[j];
    lds[t] = tot;
    __syncthreads();
    for (int ofs = 1; ofs < 256; ofs <<= 1) {
        int w = (t >= ofs) ? lds[t - ofs] : 0;
        __syncthreads();
        lds[t] += w;
        __syncthreads();
    }
    int run = lds[t] - tot;
#pragma unroll
    for (int j = 0; j < 40; j++) {
        int i = i0 + j;
        if (i < N_NODES) {
            cursor[i] = run;
            offs[i + 1] = run + v[j];
        }
        run += v[j];
    }
    if (t == 0) offs[0] = 0;
}

// ---------------- Fused dispatch: scan (block 0) || gemm1 (blocks 1..2500) ----------------

__launch_bounds__(256)
__global__ void k_gemm1_scan(const float* __restrict__ x, const __half* __restrict__ Wt,
                             __half* __restrict__ h2, float* __restrict__ alsrc,
                             float* __restrict__ aldst, const int* __restrict__ deg,
                             int* __restrict__ offs, int* __restrict__ cursor) {
    int bid = blockIdx.x;
    if (bid == 0) { scan_body(deg, offs, cursor); return; }
    gemm_body<F_IN_C, float>(x, Wt, h2, alsrc, aldst, (bid - 1) / 625, (bid - 1) % 625);
}

__launch_bounds__(256)
__global__ void k_gemm2(const __half* __restrict__ x2, const __half* __restrict__ Wt,
                        __half* __restrict__ h2, float* __restrict__ alsrc,
                        float* __restrict__ aldst) {
    gemm_body<HID_C, __half>(x2, Wt, h2, alsrc, aldst, blockIdx.y, blockIdx.x);
}

// ---------------- Scatter: real edges overwrite sentinel fill ----------------

__global__ void k_scatter(const int* __restrict__ ei, int* __restrict__ cursor,
                          int* __restrict__ csr_b) {
    int e = blockIdx.x * 256 + threadIdx.x;
    if (e < E_TOT) {
        int s, d;
        if (e < E_EDGES) { s = ei[e]; d = ei[E_EDGES + e]; }
        else { s = d = e - E_EDGES; }
        int pos = atomicAdd(&cursor[d], 1);
        csr_b[pos] = s << 9;     // src * 512 bytes (node-major fp16 row)
    }
}

// ---------------- 4-head fused gather-aggregate, in-loop alpha, oct depth-2 pipeline ----------
// r19 post-mortem: VALUBusy 74% -> issue-bound. Two VALU cuts: (1) v_fma_mix_f32 consumes the
// gathered fp16 directly (kills 4 cvt/edge); (2) al pre-scaled by log2e -> raw v_exp_f32
// (2^x) without the per-edge mul. Asm is register-only, deps fully in constraints.

#define EDGE_FMA(av, g)                                                                   \
    {                                                                                     \
        float v_ = av + ad_h;                                                             \
        v_ = fmaxf(v_, NEG_SLOPE * v_);                                                   \
        float e_;                                                                         \
        asm("v_exp_f32 %0, %1" : "=v"(e_) : "v"(v_));                                     \
        asm("v_fma_mix_f32 %0, %1, %2, %0 op_sel:[0,0,0] op_sel_hi:[1,0,0]"               \
            : "+v"(acc.x) : "v"(g.x), "v"(e_));                                           \
        asm("v_fma_mix_f32 %0, %1, %2, %0 op_sel:[1,0,0] op_sel_hi:[1,0,0]"               \
            : "+v"(acc.y) : "v"(g.x), "v"(e_));                                           \
        asm("v_fma_mix_f32 %0, %1, %2, %0 op_sel:[0,0,0] op_sel_hi:[1,0,0]"               \
            : "+v"(acc.z) : "v"(g.y), "v"(e_));                                           \
        asm("v_fma_mix_f32 %0, %1, %2, %0 op_sel:[1,0,0] op_sel_hi:[1,0,0]"               \
            : "+v"(acc.w) : "v"(g.y), "v"(e_));                                           \
        sacc += e_;                                                                       \
    }

template <bool LAYER1>
__launch_bounds__(256)
__global__ void k_agg(const __half* __restrict__ h2, const float* __restrict__ alsrc,
                      const float* __restrict__ aldst, const int* __restrict__ offs,
                      const int* __restrict__ csr_b, const float* __restrict__ bias,
                      void* __restrict__ outv) {
    int t = threadIdx.x;
    int bid = blockIdx.x;
    int xcd = bid & 7;
    int b = xcd >> 1;
    int local = (bid >> 3) * 2 + (xcd & 1); // 0..2499
    int wv = t >> 6, lane = t & 63;
    int hd = lane >> 4, cl = lane & 15;
    int dst = local * 4 + wv;

    const char* hcb = (const char*)(h2 + (size_t)b * SH * 256);
    const float* als = alsrc + (size_t)b * SN * 4 + hd;   // +hd folded into base
    float ad_h = aldst[((size_t)b * SN + dst) * 4 + hd];
    int s0 = offs[dst], s1 = offs[dst + 1];
    int laneoff = (hd << 7) | (cl << 3);    // head slice (128 B) + chan quad (8 B)

    float4 acc = make_float4(0.f, 0.f, 0.f, 0.f);
    float sacc = 0.f;
    // prologue: oct 0 fully staged (padded len >= 8)
    int4 cA = *(const int4*)(csr_b + s0);
    int4 cB = *(const int4*)(csr_b + s0 + 4);
    uint2 g0 = *(const uint2*)(hcb + (unsigned)(cA.x + laneoff));
    uint2 g1 = *(const uint2*)(hcb + (unsigned)(cA.y + laneoff));
    uint2 g2 = *(const uint2*)(hcb + (unsigned)(cA.z + laneoff));
    uint2 g3 = *(const uint2*)(hcb + (unsigned)(cA.w + laneoff));
    uint2 g4 = *(const uint2*)(hcb + (unsigned)(cB.x + laneoff));
    uint2 g5 = *(const uint2*)(hcb + (unsigned)(cB.y + laneoff));
    uint2 g6 = *(const uint2*)(hcb + (unsigned)(cB.z + laneoff));
    uint2 g7 = *(const uint2*)(hcb + (unsigned)(cB.w + laneoff));
    float a0 = als[cA.x >> 7], a1 = als[cA.y >> 7], a2 = als[cA.z >> 7], a3 = als[cA.w >> 7];
    float a4 = als[cB.x >> 7], a5 = als[cB.y >> 7], a6 = als[cB.z >> 7], a7 = als[cB.w >> 7];
    // oct 1 indices (clamped)
    int jn = (s0 + 8 < s1) ? s0 + 8 : s0;
    int4 cA2 = *(const int4*)(csr_b + jn);
    int4 cB2 = *(const int4*)(csr_b + jn + 4);

    for (int j = s0 + 8; j < s1; j += 8) {
        uint2 m0 = *(const uint2*)(hcb + (unsigned)(cA2.x + laneoff));
        uint2 m1 = *(const uint2*)(hcb + (unsigned)(cA2.y + laneoff));
        uint2 m2 = *(const uint2*)(hcb + (unsigned)(cA2.z + laneoff));
        uint2 m3 = *(const uint2*)(hcb + (unsigned)(cA2.w + laneoff));
        uint2 m4 = *(const uint2*)(hcb + (unsigned)(cB2.x + laneoff));
        uint2 m5 = *(const uint2*)(hcb + (unsigned)(cB2.y + laneoff));
        uint2 m6 = *(const uint2*)(hcb + (unsigned)(cB2.z + laneoff));
        uint2 m7 = *(const uint2*)(hcb + (unsigned)(cB2.w + laneoff));
        float v0 = als[cA2.x >> 7], v1 = als[cA2.y >> 7], v2 = als[cA2.z >> 7], v3 = als[cA2.w >> 7];
        float v4 = als[cB2.x >> 7], v5 = als[cB2.y >> 7], v6 = als[cB2.z >> 7], v7 = als[cB2.w >> 7];
        int j2 = (j + 8 < s1) ? j + 8 : j;
        int4 cA3 = *(const int4*)(csr_b + j2);
        int4 cB3 = *(const int4*)(csr_b + j2 + 4);
        EDGE_FMA(a0, g0) EDGE_FMA(a1, g1) EDGE_FMA(a2, g2) EDGE_FMA(a3, g3)
        EDGE_FMA(a4, g4) EDGE_FMA(a5, g5) EDGE_FMA(a6, g6) EDGE_FMA(a7, g7)
        g0 = m0; g1 = m1; g2 = m2; g3 = m3; g4 = m4; g5 = m5; g6 = m6; g7 = m7;
        a0 = v0; a1 = v1; a2 = v2; a3 = v3; a4 = v4; a5 = v5; a6 = v6; a7 = v7;
        cA2 = cA3; cB2 = cB3;
    }
    EDGE_FMA(a0, g0) EDGE_FMA(a1, g1) EDGE_FMA(a2, g2) EDGE_FMA(a3, g3)
    EDGE_FMA(a4, g4) EDGE_FMA(a5, g5) EDGE_FMA(a6, g6) EDGE_FMA(a7, g7)

    // per-head normalize, then fold heads (lanes cl, cl+16, cl+32, cl+48 share channel)
    float inv = 1.f / (sacc + 1e-16f);
    float4 v = make_float4(acc.x * inv, acc.y * inv, acc.z * inv, acc.w * inv);
#pragma unroll
    for (int o = 16; o < 64; o <<= 1) {
        v.x += __shfl_xor(v.x, o);
        v.y += __shfl_xor(v.y, o);
        v.z += __shfl_xor(v.z, o);
        v.w += __shfl_xor(v.w, o);
    }
    if (lane < 16) {
        float4 b4 = *(const float4*)(bias + cl * 4);
        float ox = v.x * 0.25f + b4.x;
        float oy = v.y * 0.25f + b4.y;
        float oz = v.z * 0.25f + b4.z;
        float ow = v.w * 0.25f + b4.w;
        if (LAYER1) {
            ox = ox > 0.f ? ox : expm1f(ox);
            oy = oy > 0.f ? oy : expm1f(oy);
            oz = oz > 0.f ? oz : expm1f(oz);
            ow = ow > 0.f ? ow : expm1f(ow);
            __half2 lo = __floats2half2_rn(ox, oy);
            __half2 hi = __floats2half2_rn(oz, ow);
            uint2 pk = make_uint2(*(unsigned*)&lo, *(unsigned*)&hi);
            *(uint2*)((__half*)outv + ((size_t)b * N_NODES + dst) * 64 + cl * 4) = pk;
        } else {
            *(float4*)((float*)outv + ((size_t)b * N_NODES + dst) * 64 + cl * 4) =
                make_float4(ox, oy, oz, ow);
        }
    }
}

// ---------------- Launch: 6 dispatches + 1 memset ----------------

extern "C" void kernel_launch(void* const* d_in, const int* in_sizes, int n_in,
                              void* d_out, int out_size, void* d_ws, size_t ws_size,
                              hipStream_t stream) {
    const float* x = (const float*)d_in[0];
    const int* ei = (const int*)d_in[1];
    const float* W1 = (const float*)d_in[2];
    const float* as1 = (const float*)d_in[3];
    const float* ad1 = (const float*)d_in[4];
    const float* b1 = (const float*)d_in[5];
    const float* W2 = (const float*)d_in[6];
    const float* as2 = (const float*)d_in[7];
    const float* ad2 = (const float*)d_in[8];
    const float* b2 = (const float*)d_in[9];
    float* out = (float*)d_out;

    // workspace layout (all segments 16B-aligned by construction)
    char* p = (char*)d_ws;
    int* deg = (int*)p;            p += sizeof(int) * N_PAD;
    int* offs = (int*)p;           p += sizeof(int) * (N_NODES + 4);
    int* cursor = (int*)p;         p += sizeof(int) * N_NODES;
    int* csr_b = (int*)p;          p += sizeof(int) * E_OCT;
    __half* Wt1 = (__half*)p;      p += sizeof(__half) * 272 * F_IN_C;
    __half* Wt2 = (__half*)p;      p += sizeof(__half) * 272 * HID_C;
    float* alsrc = (float*)p;      p += sizeof(float) * B_BATCH * SN * 4;
    float* aldst = (float*)p;      p += sizeof(float) * B_BATCH * SN * 4;
    __half* h2 = (__half*)p;       p += sizeof(__half) * (size_t)B_BATCH * SH * 256;
    __half* x2 = (__half*)p;       p += sizeof(__half) * (size_t)B_BATCH * N_NODES * 64;

    hipMemsetAsync(deg, 0, sizeof(int) * N_PAD, stream);

    // D1: wext1 | wext2 | csr sentinel fill | dummy rows | deg_count
    k_setup<<<1768, 256, 0, stream>>>(W1, as1, ad1, W2, as2, ad2, Wt1, Wt2,
                                      csr_b, h2, alsrc, deg, ei);
    // D2: scan (block 0, int4-vectorized) || gemm layer 1 (blocks 1..2500)
    k_gemm1_scan<<<2501, 256, 0, stream>>>(x, Wt1, h2, alsrc, aldst, deg, offs, cursor);
    // D3: scatter (overwrites sentinel fill with real edges)
    k_scatter<<<(E_TOT + 255) / 256, 256, 0, stream>>>(ei, cursor, csr_b);
    // D4: layer-1 aggregate (alpha in-loop) -> x2 (fp16)
    k_agg<true><<<B_BATCH * 2500, 256, 0, stream>>>(h2, alsrc, aldst, offs, csr_b, b1, x2);
    // D5: gemm layer 2
    k_gemm2<<<dim3(625, B_BATCH), 256, 0, stream>>>(x2, Wt2, h2, alsrc, aldst);
    // D6: layer-2 aggregate -> out (f32)
    k_agg<false><<<B_BATCH * 2500, 256, 0, stream>>>(h2, alsrc, aldst, offs, csr_b, b2, out);
}